// Round 2
// baseline (918.261 us; speedup 1.0000x reference)
//
#include <hip/hip_runtime.h>
#include <math.h>

#define N_ENT 100000
#define N_USR 50000
#define N_EDGE 1000000
#define CDIM 64
#define TEMPC 0.2f

__device__ __forceinline__ float waveReduceSum(float x) {
#pragma unroll
  for (int d = 32; d > 0; d >>= 1) x += __shfl_xor(x, d);
  return x;
}
__device__ __forceinline__ float waveReduceMax(float x) {
#pragma unroll
  for (int d = 32; d > 0; d >>= 1) x = fmaxf(x, __shfl_xor(x, d));
  return x;
}
__device__ __forceinline__ int waveReduceSumI(int x) {
#pragma unroll
  for (int d = 32; d > 0; d >>= 1) x += __shfl_xor(x, d);
  return x;
}

// ---------------- CSR build ----------------
__global__ void k_count(const int* __restrict__ head, const int* __restrict__ uir,
                        int* __restrict__ cnt_h, int* __restrict__ cnt_u) {
  int i = blockIdx.x * blockDim.x + threadIdx.x;
  if (i < N_EDGE) {
    atomicAdd(&cnt_h[head[i]], 1);
    atomicAdd(&cnt_u[uir[i]], 1);
  }
}

__global__ void k_scan_reduce(const int* __restrict__ cnt, int n, int* __restrict__ bsum) {
  int b = blockIdx.x, tid = threadIdx.x;
  int i0 = b * 1024 + tid * 4;
  int s = 0;
#pragma unroll
  for (int k = 0; k < 4; ++k)
    if (i0 + k < n) s += cnt[i0 + k];
  s = waveReduceSumI(s);
  __shared__ int l[4];
  int lane = tid & 63, wid = tid >> 6;
  if (lane == 0) l[wid] = s;
  __syncthreads();
  if (tid == 0) bsum[b] = l[0] + l[1] + l[2] + l[3];
}

__global__ void k_scan_tops(int* bsA, int nA, int* bsB, int nB,
                            int* ptrA, int NA, int* ptrB, int NB, int total) {
  if (threadIdx.x == 0) {
    int a = 0;
    for (int i = 0; i < nA; ++i) { int t = bsA[i]; bsA[i] = a; a += t; }
    ptrA[NA] = total;
  }
  if (threadIdx.x == 1) {
    int a = 0;
    for (int i = 0; i < nB; ++i) { int t = bsB[i]; bsB[i] = a; a += t; }
    ptrB[NB] = total;
  }
}

__global__ void k_scan_final(int* __restrict__ cnt, int n, const int* __restrict__ bsum,
                             int* __restrict__ ptr, int* __restrict__ cur) {
  int b = blockIdx.x, tid = threadIdx.x;
  int i0 = b * 1024 + tid * 4;
  int c[4];
  int s = 0;
  int loc[4];
#pragma unroll
  for (int k = 0; k < 4; ++k) {
    c[k] = (i0 + k < n) ? cnt[i0 + k] : 0;
    loc[k] = s;
    s += c[k];
  }
  int lane = tid & 63, wid = tid >> 6;
  int x = s;
#pragma unroll
  for (int d = 1; d < 64; d <<= 1) {
    int y = __shfl_up(x, d);
    if (lane >= d) x += y;
  }
  __shared__ int l[4];
  if (lane == 63) l[wid] = x;
  __syncthreads();
  if (tid == 0) {
    int a = 0;
    for (int w = 0; w < 4; ++w) { int t = l[w]; l[w] = a; a += t; }
  }
  __syncthreads();
  int excl = x - s + l[wid] + bsum[b];
#pragma unroll
  for (int k = 0; k < 4; ++k) {
    if (i0 + k < n) {
      int v = excl + loc[k];
      ptr[i0 + k] = v;
      cur[i0 + k] = v;
    }
  }
}

__global__ void k_build(const int* __restrict__ head, const int* __restrict__ tail,
                        const int* __restrict__ etype,
                        const int* __restrict__ uir, const int* __restrict__ uic,
                        const float* __restrict__ uival,
                        int* __restrict__ cur_h, int* __restrict__ cur_u,
                        int* __restrict__ packed, int* __restrict__ col_s,
                        float* __restrict__ val_s) {
  int i = blockIdx.x * blockDim.x + threadIdx.x;
  if (i < N_EDGE) {
    int h = head[i];
    int p = atomicAdd(&cur_h[h], 1);
    packed[p] = (tail[i] & 0xFFFFF) | ((etype[i] - 1) << 20);
    int u = uir[i];
    int q = atomicAdd(&cur_u[u], 1);
    col_s[q] = uic[i];
    val_s[q] = uival[i];
  }
}

// ---------------- tiny precompute: V = (W W^T) w_r, wsq, disen_w, cor ----------------
__global__ void k_prep(const float* __restrict__ weight, const float* __restrict__ kgW,
                       const float* __restrict__ disen,
                       float* __restrict__ V, float* __restrict__ wsq,
                       float* __restrict__ dw, float* __restrict__ cor_out) {
  __shared__ float M[64 * 64];
  __shared__ float sm[4 * 9];
  int tid = threadIdx.x;
  for (int e = tid; e < 64 * 64; e += 256) {
    int i = e >> 6, j = e & 63;
    float s = 0.f;
    for (int k = 0; k < 64; ++k) s += kgW[i * 64 + k] * kgW[j * 64 + k];
    M[e] = s;
  }
  if (tid < 4) {
    float m = -INFINITY;
    for (int r = 0; r < 9; ++r) m = fmaxf(m, disen[tid * 9 + r]);
    float den = 0.f;
    float ex[9];
    for (int r = 0; r < 9; ++r) { ex[r] = expf(disen[tid * 9 + r] - m); den += ex[r]; }
    for (int r = 0; r < 9; ++r) sm[tid * 9 + r] = ex[r] / den;
  }
  __syncthreads();
  for (int e = tid; e < 9 * 64; e += 256) {
    int r = e >> 6, i = e & 63;
    float s = 0.f;
    for (int k = 0; k < 64; ++k) s += M[i * 64 + k] * weight[r * 64 + k];
    V[e] = s;
  }
  if (tid < 9) {
    float s = 0.f;
    for (int c = 0; c < 64; ++c) { float w = weight[tid * 64 + c]; s += w * w; }
    wsq[tid] = s;
  }
  for (int e = tid; e < 4 * 64; e += 256) {
    int f = e >> 6, c = e & 63;
    float s = 0.f;
    for (int r = 0; r < 9; ++r) s += sm[f * 9 + r] * weight[r * 64 + c];
    dw[e] = s;
  }
  if (tid == 0) {
    float rowsum[4];
    for (int f = 0; f < 4; ++f) {
      float s = 0.f;
      for (int j = 0; j < 9; ++j) s += disen[f * 9 + j];
      rowsum[f] = s;
    }
    float cor = 0.f;
    for (int i = 0; i < 9; ++i) {
      float n2 = 0.f, ttl = 0.f;
      for (int f = 0; f < 4; ++f) {
        float v = disen[f * 9 + i];
        n2 += v * v;
        ttl += v * rowsum[f];
      }
      float nrm = sqrtf(n2);
      float pos = 0.f;
      for (int f = 0; f < 4; ++f) {
        float v = disen[f * 9 + i] / nrm;
        pos += v * v;
      }
      cor += (ttl - pos) / TEMPC;
    }
    *cor_out = cor;
  }
}

// ---------------- invariant mask (two scatter-softmaxes) ----------------
__global__ void k_mask(const float* __restrict__ ent0, const int* __restrict__ ptr,
                       const int* __restrict__ packed, const float* __restrict__ V,
                       const float* __restrict__ wsq, float* __restrict__ mask_s) {
  int wave = (blockIdx.x * blockDim.x + threadIdx.x) >> 6;
  int lane = threadIdx.x & 63;
  if (wave >= N_ENT) return;
  int s = ptr[wave], e = ptr[wave + 1];
  if (s == e) return;
  const float inv2s = 0.08838834764831845f; // 1/(2*sqrt(32))
  float eh = ent0[(size_t)wave * 64 + lane];
  float sb[9];
#pragma unroll
  for (int r = 0; r < 9; ++r) sb[r] = waveReduceSum(eh * V[r * 64 + lane]) * inv2s;
  int cnt[9] = {0, 0, 0, 0, 0, 0, 0, 0, 0};
  for (int base = s; base < e; base += 64) {
    int c = min(64, e - base);
    int pk = (lane < c) ? packed[base + lane] : -1;
    int t = pk >> 20; // -1 for inactive
#pragma unroll
    for (int r = 0; r < 9; ++r) cnt[r] += __popcll(__ballot(t == r));
  }
  float m1 = -INFINITY;
#pragma unroll
  for (int r = 0; r < 9; ++r)
    if (cnt[r] > 0) m1 = fmaxf(m1, sb[r]);
  float den1 = 0.f;
#pragma unroll
  for (int r = 0; r < 9; ++r)
    if (cnt[r] > 0) den1 += (float)cnt[r] * expf(sb[r] - m1);
  den1 += 1e-16f;
  float rel2[9];
#pragma unroll
  for (int r = 0; r < 9; ++r) {
    float rs = expf(sb[r] - m1) / den1;
    rel2[r] = rs * rs * wsq[r];
  }
  // pass 2: score_trip per edge -> mask_s (temp)
  for (int base = s; base < e; base += 64) {
    int c = min(64, e - base);
    int pk = (lane < c) ? packed[base + lane] : 0;
    float trip = 0.f;
    for (int j = 0; j < c; ++j) {
      int pkj = __shfl(pk, j);
      int tl = pkj & 0xFFFFF;
      int t = pkj >> 20;
      float d = waveReduceSum(eh * ent0[(size_t)tl * 64 + lane]);
      float r2 = rel2[0];
#pragma unroll
      for (int r = 1; r < 9; ++r) r2 = (t == r) ? rel2[r] : r2;
      if (lane == j) trip = d + r2;
    }
    if (lane < c) mask_s[base + lane] = trip;
  }
  // group softmax
  float m2 = -INFINITY;
  for (int base = s; base < e; base += 64) {
    int c = min(64, e - base);
    float v = (lane < c) ? mask_s[base + lane] : -INFINITY;
    m2 = fmaxf(m2, v);
  }
  m2 = waveReduceMax(m2);
  float den2 = 0.f;
  for (int base = s; base < e; base += 64) {
    int c = min(64, e - base);
    den2 += (lane < c) ? expf(mask_s[base + lane] - m2) : 0.f;
  }
  den2 = waveReduceSum(den2) + 1e-16f;
  for (int base = s; base < e; base += 64) {
    int c = min(64, e - base);
    if (lane < c) mask_s[base + lane] = expf(mask_s[base + lane] - m2) / den2;
  }
}

// ---------------- KG aggregation + l2norm + residual ----------------
__global__ void k_kgagg(const float* __restrict__ src, const float* __restrict__ addb,
                        float* __restrict__ outp, float* __restrict__ nxt,
                        const int* __restrict__ ptr, const int* __restrict__ packed,
                        const float* __restrict__ mask_s, const float* __restrict__ weight) {
  __shared__ float wl[9 * 64];
  for (int i = threadIdx.x; i < 9 * 64; i += blockDim.x) wl[i] = weight[i];
  __syncthreads();
  int wave = (blockIdx.x * blockDim.x + threadIdx.x) >> 6;
  int lane = threadIdx.x & 63;
  if (wave >= N_ENT) return;
  int s = ptr[wave], e = ptr[wave + 1];
  float acc = 0.f;
  for (int base = s; base < e; base += 64) {
    int c = min(64, e - base);
    int pk = (lane < c) ? packed[base + lane] : 0;
    float mk = (lane < c) ? mask_s[base + lane] : 0.f;
    for (int j = 0; j < c; ++j) {
      int pkj = __shfl(pk, j);
      float mkj = __shfl(mk, j);
      int tl = pkj & 0xFFFFF;
      int t = pkj >> 20;
      acc += src[(size_t)tl * 64 + lane] * wl[t * 64 + lane] * mkj;
    }
  }
  float n = (float)(e - s);
  float agg = acc / fmaxf(n, 1.0f);
  float nrm = sqrtf(waveReduceSum(agg * agg));
  float val = agg / fmaxf(nrm, 1e-12f);
  size_t o = (size_t)wave * 64 + lane;
  if (nxt) nxt[o] = val;
  outp[o] = addb[o] + val;
}

// ---------------- UI aggregation + factor attention + l2norm + residual ----------------
__global__ void k_uiagg(const float* __restrict__ src, const float* __restrict__ ucur,
                        const float* __restrict__ addb, float* __restrict__ outp,
                        float* __restrict__ nxt,
                        const int* __restrict__ ptr, const int* __restrict__ col_s,
                        const float* __restrict__ val_s, const float* __restrict__ latent,
                        const float* __restrict__ dw) {
  __shared__ float lat[256], dwl[256];
  if (threadIdx.x < 256) {
    lat[threadIdx.x] = latent[threadIdx.x];
    dwl[threadIdx.x] = dw[threadIdx.x];
  }
  __syncthreads();
  int wave = (blockIdx.x * blockDim.x + threadIdx.x) >> 6;
  int lane = threadIdx.x & 63;
  if (wave >= N_USR) return;
  float uc = ucur[(size_t)wave * 64 + lane];
  float sc[4];
#pragma unroll
  for (int f = 0; f < 4; ++f) sc[f] = waveReduceSum(uc * lat[f * 64 + lane]);
  float m = fmaxf(fmaxf(sc[0], sc[1]), fmaxf(sc[2], sc[3]));
  float e0 = expf(sc[0] - m), e1 = expf(sc[1] - m), e2 = expf(sc[2] - m), e3 = expf(sc[3] - m);
  float den = e0 + e1 + e2 + e3;
  float mix = (e0 * dwl[lane] + e1 * dwl[64 + lane] + e2 * dwl[128 + lane] + e3 * dwl[192 + lane]) / den;
  int s = ptr[wave], e = ptr[wave + 1];
  float acc = 0.f;
  for (int base = s; base < e; base += 64) {
    int c = min(64, e - base);
    int cl = (lane < c) ? col_s[base + lane] : 0;
    float vl = (lane < c) ? val_s[base + lane] : 0.f;
    for (int j = 0; j < c; ++j) {
      int cj = __shfl(cl, j);
      float vj = __shfl(vl, j);
      acc += src[(size_t)cj * 64 + lane] * vj;
    }
  }
  float ua = acc * mix + acc;
  float nrm = sqrtf(waveReduceSum(ua * ua));
  float val = ua / fmaxf(nrm, 1e-12f);
  size_t o = (size_t)wave * 64 + lane;
  if (nxt) nxt[o] = val;
  outp[o] = addb[o] + val;
}

extern "C" void kernel_launch(void* const* d_in, const int* in_sizes, int n_in,
                              void* d_out, int out_size, void* d_ws, size_t ws_size,
                              hipStream_t stream) {
  const float* user_emb = (const float*)d_in[0];
  const float* entity_emb = (const float*)d_in[1];
  const float* latent = (const float*)d_in[2];
  const float* weight = (const float*)d_in[3];
  const float* disen = (const float*)d_in[4];
  const float* kgW = (const float*)d_in[5];
  const float* ui_vals = (const float*)d_in[6];
  const int* edge_index = (const int*)d_in[7];
  const int* edge_type = (const int*)d_in[8];
  const int* ui_rows = (const int*)d_in[9];
  const int* ui_cols = (const int*)d_in[10];
  const int* head = edge_index;
  const int* tail = edge_index + N_EDGE;

  char* ws = (char*)d_ws;
  size_t o = 0;
  auto alloc = [&](size_t bytes) -> char* {
    char* p = ws + o;
    o += (bytes + 255) & ~(size_t)255;
    return p;
  };
  int* head_ptr = (int*)alloc((N_ENT + 1) * 4);
  int* head_cur = (int*)alloc((size_t)N_ENT * 4);
  int* ui_ptr = (int*)alloc((N_USR + 1) * 4);
  int* ui_cur = (int*)alloc((size_t)N_USR * 4);
  int* bsum_h = (int*)alloc(256 * 4);
  int* bsum_u = (int*)alloc(256 * 4);
  int* packed = (int*)alloc((size_t)N_EDGE * 4);
  int* col_s = (int*)alloc((size_t)N_EDGE * 4);
  float* val_s = (float*)alloc((size_t)N_EDGE * 4);
  float* mask_s = (float*)alloc((size_t)N_EDGE * 4);
  float* ent1 = (float*)alloc((size_t)N_ENT * 64 * 4);
  float* usr1 = (float*)alloc((size_t)N_USR * 64 * 4);
  float* V = (float*)alloc(9 * 64 * 4);
  float* wsq = (float*)alloc(16 * 4);
  float* dw = (float*)alloc(4 * 64 * 4);
  if (o > ws_size) return;  // scratch too small — fail loudly via poison output

  float* out_ent = (float*)d_out;
  float* out_usr = out_ent + (size_t)N_ENT * 64;
  float* out_cor = out_ent + (size_t)N_ENT * 64 + (size_t)N_USR * 64;

  hipMemsetAsync(head_cur, 0, (size_t)N_ENT * 4, stream);
  hipMemsetAsync(ui_cur, 0, (size_t)N_USR * 4, stream);

  int eb = (N_EDGE + 255) / 256;
  k_count<<<eb, 256, 0, stream>>>(head, ui_rows, head_cur, ui_cur);

  int nbh = (N_ENT + 1023) / 1024, nbu = (N_USR + 1023) / 1024;
  k_scan_reduce<<<nbh, 256, 0, stream>>>(head_cur, N_ENT, bsum_h);
  k_scan_reduce<<<nbu, 256, 0, stream>>>(ui_cur, N_USR, bsum_u);
  k_scan_tops<<<1, 64, 0, stream>>>(bsum_h, nbh, bsum_u, nbu, head_ptr, N_ENT, ui_ptr, N_USR, N_EDGE);
  k_scan_final<<<nbh, 256, 0, stream>>>(head_cur, N_ENT, bsum_h, head_ptr, head_cur);
  k_scan_final<<<nbu, 256, 0, stream>>>(ui_cur, N_USR, bsum_u, ui_ptr, ui_cur);

  k_build<<<eb, 256, 0, stream>>>(head, tail, edge_type, ui_rows, ui_cols, ui_vals,
                                  head_cur, ui_cur, packed, col_s, val_s);

  k_prep<<<1, 256, 0, stream>>>(weight, kgW, disen, V, wsq, dw, out_cor);

  int gbe = (N_ENT + 3) / 4;  // 4 waves/block
  int gbu = (N_USR + 3) / 4;
  k_mask<<<gbe, 256, 0, stream>>>(entity_emb, head_ptr, packed, V, wsq, mask_s);

  // hop 1
  k_kgagg<<<gbe, 256, 0, stream>>>(entity_emb, entity_emb, out_ent, ent1,
                                   head_ptr, packed, mask_s, weight);
  k_uiagg<<<gbu, 256, 0, stream>>>(entity_emb, user_emb, user_emb, out_usr, usr1,
                                   ui_ptr, col_s, val_s, latent, dw);
  // hop 2
  k_kgagg<<<gbe, 256, 0, stream>>>(ent1, out_ent, out_ent, nullptr,
                                   head_ptr, packed, mask_s, weight);
  k_uiagg<<<gbu, 256, 0, stream>>>(ent1, usr1, out_usr, out_usr, nullptr,
                                   ui_ptr, col_s, val_s, latent, dw);
}

// Round 3
// 829.224 us; speedup vs baseline: 1.1074x; 1.1074x over previous
//
#include <hip/hip_runtime.h>
#include <math.h>

#define N_ENT 100000
#define N_USR 50000
#define N_EDGE 1000000
#define TEMPC 0.2f
#define KG_BLOCKS (N_ENT / 4)   // 25000, exact
#define UI_BLOCKS (N_USR / 4)   // 12500, exact

__device__ __forceinline__ float waveReduceSum(float x) {
#pragma unroll
  for (int d = 32; d > 0; d >>= 1) x += __shfl_xor(x, d);
  return x;
}
__device__ __forceinline__ float waveReduceMax(float x) {
#pragma unroll
  for (int d = 32; d > 0; d >>= 1) x = fmaxf(x, __shfl_xor(x, d));
  return x;
}
__device__ __forceinline__ int waveReduceSumI(int x) {
#pragma unroll
  for (int d = 32; d > 0; d >>= 1) x += __shfl_xor(x, d);
  return x;
}

// ---------------- CSR build ----------------
__global__ void k_count(const int* __restrict__ head, const int* __restrict__ uir,
                        int* __restrict__ cnt_h, int* __restrict__ cnt_u) {
  int i = blockIdx.x * blockDim.x + threadIdx.x;
  if (i < N_EDGE) {
    atomicAdd(&cnt_h[head[i]], 1);
    atomicAdd(&cnt_u[uir[i]], 1);
  }
}

__global__ void k_scan_reduce(const int* __restrict__ cnt, int n, int* __restrict__ bsum) {
  int b = blockIdx.x, tid = threadIdx.x;
  int i0 = b * 1024 + tid * 4;
  int s = 0;
#pragma unroll
  for (int k = 0; k < 4; ++k)
    if (i0 + k < n) s += cnt[i0 + k];
  s = waveReduceSumI(s);
  __shared__ int l[4];
  int lane = tid & 63, wid = tid >> 6;
  if (lane == 0) l[wid] = s;
  __syncthreads();
  if (tid == 0) bsum[b] = l[0] + l[1] + l[2] + l[3];
}

__global__ void k_scan_tops(int* bsA, int nA, int* bsB, int nB,
                            int* ptrA, int NA, int* ptrB, int NB, int total) {
  if (threadIdx.x == 0) {
    int a = 0;
    for (int i = 0; i < nA; ++i) { int t = bsA[i]; bsA[i] = a; a += t; }
    ptrA[NA] = total;
  }
  if (threadIdx.x == 1) {
    int a = 0;
    for (int i = 0; i < nB; ++i) { int t = bsB[i]; bsB[i] = a; a += t; }
    ptrB[NB] = total;
  }
}

__global__ void k_scan_final(int* __restrict__ cnt, int n, const int* __restrict__ bsum,
                             int* __restrict__ ptr, int* __restrict__ cur) {
  int b = blockIdx.x, tid = threadIdx.x;
  int i0 = b * 1024 + tid * 4;
  int c[4];
  int s = 0;
  int loc[4];
#pragma unroll
  for (int k = 0; k < 4; ++k) {
    c[k] = (i0 + k < n) ? cnt[i0 + k] : 0;
    loc[k] = s;
    s += c[k];
  }
  int lane = tid & 63, wid = tid >> 6;
  int x = s;
#pragma unroll
  for (int d = 1; d < 64; d <<= 1) {
    int y = __shfl_up(x, d);
    if (lane >= d) x += y;
  }
  __shared__ int l[4];
  if (lane == 63) l[wid] = x;
  __syncthreads();
  if (tid == 0) {
    int a = 0;
    for (int w = 0; w < 4; ++w) { int t = l[w]; l[w] = a; a += t; }
  }
  __syncthreads();
  int excl = x - s + l[wid] + bsum[b];
#pragma unroll
  for (int k = 0; k < 4; ++k) {
    if (i0 + k < n) {
      int v = excl + loc[k];
      ptr[i0 + k] = v;
      cur[i0 + k] = v;
    }
  }
}

__global__ void k_build(const int* __restrict__ head, const int* __restrict__ tail,
                        const int* __restrict__ etype,
                        const int* __restrict__ uir, const int* __restrict__ uic,
                        const float* __restrict__ uival,
                        int* __restrict__ cur_h, int* __restrict__ cur_u,
                        int* __restrict__ packed, int* __restrict__ col_s,
                        float* __restrict__ val_s) {
  int i = blockIdx.x * blockDim.x + threadIdx.x;
  if (i < N_EDGE) {
    int h = head[i];
    int p = atomicAdd(&cur_h[h], 1);
    packed[p] = (tail[i] & 0xFFFFF) | ((etype[i] - 1) << 20);
    int u = uir[i];
    int q = atomicAdd(&cur_u[u], 1);
    col_s[q] = uic[i];
    val_s[q] = uival[i];
  }
}

// ---------------- tiny precompute: V = (W W^T) w_r, wsq, disen_w, cor ----------------
__global__ void k_prep(const float* __restrict__ weight, const float* __restrict__ kgW,
                       const float* __restrict__ disen,
                       float* __restrict__ V, float* __restrict__ wsq,
                       float* __restrict__ dw, float* __restrict__ cor_out) {
  __shared__ float M[64 * 64];
  __shared__ float sm[4 * 9];
  int tid = threadIdx.x;
  for (int e = tid; e < 64 * 64; e += 256) {
    int i = e >> 6, j = e & 63;
    float s = 0.f;
    for (int k = 0; k < 64; ++k) s += kgW[i * 64 + k] * kgW[j * 64 + k];
    M[e] = s;
  }
  if (tid < 4) {
    float m = -INFINITY;
    for (int r = 0; r < 9; ++r) m = fmaxf(m, disen[tid * 9 + r]);
    float den = 0.f;
    float ex[9];
    for (int r = 0; r < 9; ++r) { ex[r] = expf(disen[tid * 9 + r] - m); den += ex[r]; }
    for (int r = 0; r < 9; ++r) sm[tid * 9 + r] = ex[r] / den;
  }
  __syncthreads();
  for (int e = tid; e < 9 * 64; e += 256) {
    int r = e >> 6, i = e & 63;
    float s = 0.f;
    for (int k = 0; k < 64; ++k) s += M[i * 64 + k] * weight[r * 64 + k];
    V[e] = s;
  }
  if (tid < 9) {
    float s = 0.f;
    for (int c = 0; c < 64; ++c) { float w = weight[tid * 64 + c]; s += w * w; }
    wsq[tid] = s;
  }
  for (int e = tid; e < 4 * 64; e += 256) {
    int f = e >> 6, c = e & 63;
    float s = 0.f;
    for (int r = 0; r < 9; ++r) s += sm[f * 9 + r] * weight[r * 64 + c];
    dw[e] = s;
  }
  if (tid == 0) {
    float rowsum[4];
    for (int f = 0; f < 4; ++f) {
      float s = 0.f;
      for (int j = 0; j < 9; ++j) s += disen[f * 9 + j];
      rowsum[f] = s;
    }
    float cor = 0.f;
    for (int i = 0; i < 9; ++i) {
      float n2 = 0.f, ttl = 0.f;
      for (int f = 0; f < 4; ++f) {
        float v = disen[f * 9 + i];
        n2 += v * v;
        ttl += v * rowsum[f];
      }
      float nrm = sqrtf(n2);
      float pos = 0.f;
      for (int f = 0; f < 4; ++f) {
        float v = disen[f * 9 + i] / nrm;
        pos += v * v;
      }
      cor += (ttl - pos) / TEMPC;
    }
    *cor_out = cor;
  }
}

// ---------------- UI aggregation body (shared by fused kernels) ----------------
__device__ __forceinline__ void ui_body(int usr, int lane,
                                        const float* __restrict__ src,
                                        const float* __restrict__ ucur,
                                        const float* __restrict__ addb,
                                        float* __restrict__ outp, float* __restrict__ nxt,
                                        const int* __restrict__ uptr,
                                        const int* __restrict__ col_s,
                                        const float* __restrict__ val_s,
                                        const float* __restrict__ lat,
                                        const float* __restrict__ dwl) {
  float uc = ucur[(size_t)usr * 64 + lane];
  float sc[4];
#pragma unroll
  for (int f = 0; f < 4; ++f) sc[f] = waveReduceSum(uc * lat[f * 64 + lane]);
  float m = fmaxf(fmaxf(sc[0], sc[1]), fmaxf(sc[2], sc[3]));
  float e0 = expf(sc[0] - m), e1 = expf(sc[1] - m), e2 = expf(sc[2] - m), e3 = expf(sc[3] - m);
  float den = e0 + e1 + e2 + e3;
  float mix = (e0 * dwl[lane] + e1 * dwl[64 + lane] + e2 * dwl[128 + lane] + e3 * dwl[192 + lane]) / den;
  int s = uptr[usr], e = uptr[usr + 1];
  float acc = 0.f;
  for (int base = s; base < e; base += 64) {
    int c = min(64, e - base);
    int cl = (lane < c) ? col_s[base + lane] : 0;
    float vl = (lane < c) ? val_s[base + lane] : 0.f;
    int j = 0;
    for (; j + 4 <= c; j += 4) {
      int c0 = __shfl(cl, j), c1 = __shfl(cl, j + 1), c2 = __shfl(cl, j + 2), c3 = __shfl(cl, j + 3);
      float v0 = __shfl(vl, j), v1 = __shfl(vl, j + 1), v2 = __shfl(vl, j + 2), v3 = __shfl(vl, j + 3);
      float r0 = src[(size_t)c0 * 64 + lane];
      float r1 = src[(size_t)c1 * 64 + lane];
      float r2 = src[(size_t)c2 * 64 + lane];
      float r3 = src[(size_t)c3 * 64 + lane];
      acc += r0 * v0 + r1 * v1 + r2 * v2 + r3 * v3;
    }
    for (; j < c; ++j) {
      int cj = __shfl(cl, j);
      float vj = __shfl(vl, j);
      acc += src[(size_t)cj * 64 + lane] * vj;
    }
  }
  float ua = acc * mix + acc;
  float nrm = sqrtf(waveReduceSum(ua * ua));
  float val = ua / fmaxf(nrm, 1e-12f);
  size_t o = (size_t)usr * 64 + lane;
  if (nxt) nxt[o] = val;
  outp[o] = addb[o] + val;
}

// ---------------- D1: invariant mask (edge-parallel dots) + UI hop-1 ----------------
__global__ void k_mask_ui(const float* __restrict__ ent0, const int* __restrict__ hptr,
                          const int* __restrict__ packed, const float* __restrict__ V,
                          const float* __restrict__ wsq, float* __restrict__ mask_s,
                          const float* __restrict__ user_emb, float* __restrict__ out_usr,
                          float* __restrict__ usr1, const int* __restrict__ uptr,
                          const int* __restrict__ col_s, const float* __restrict__ val_s,
                          const float* __restrict__ latent, const float* __restrict__ dw) {
  int lane = threadIdx.x & 63, wid = threadIdx.x >> 6;
  if (blockIdx.x < KG_BLOCKS) {
    __shared__ float sh_eh[4][64];
    int ent = blockIdx.x * 4 + wid;  // always < N_ENT
    int s = hptr[ent], e = hptr[ent + 1];
    float eh = ent0[(size_t)ent * 64 + lane];
    sh_eh[wid][lane] = eh;
    __syncthreads();
    if (s == e) return;
    const float inv2s = 0.08838834764831845f;  // 1/(2*sqrt(32))
    float sb[9];
#pragma unroll
    for (int r = 0; r < 9; ++r) sb[r] = waveReduceSum(eh * V[r * 64 + lane]) * inv2s;
    const float4* eh4 = (const float4*)sh_eh[wid];
    int deg = e - s;
    if (deg <= 64) {
      // ---- hot path: whole group in one wave chunk, softmax in registers ----
      int pk = (lane < deg) ? packed[s + lane] : 0;
      int tb = (lane < deg) ? ((pk >> 20) & 15) : 15;  // 15 = sentinel
      int cnt[9];
#pragma unroll
      for (int r = 0; r < 9; ++r) cnt[r] = __popcll(__ballot(tb == r));
      float m1 = -INFINITY;
#pragma unroll
      for (int r = 0; r < 9; ++r)
        if (cnt[r] > 0) m1 = fmaxf(m1, sb[r]);
      float den1 = 0.f;
#pragma unroll
      for (int r = 0; r < 9; ++r)
        if (cnt[r] > 0) den1 += (float)cnt[r] * expf(sb[r] - m1);
      den1 += 1e-16f;
      float rel2[9];
#pragma unroll
      for (int r = 0; r < 9; ++r) {
        float rs = expf(sb[r] - m1) / den1;
        rel2[r] = rs * rs * wsq[r];
      }
      int tl = pk & 0xFFFFF;
      const float4* row = (const float4*)(ent0 + (size_t)tl * 64);
      float dx = 0.f, dy = 0.f, dz = 0.f, dw_ = 0.f;
#pragma unroll
      for (int q = 0; q < 16; ++q) {
        float4 a = eh4[q];
        float4 b = row[q];
        dx += a.x * b.x; dy += a.y * b.y; dz += a.z * b.z; dw_ += a.w * b.w;
      }
      float dot = (dx + dy) + (dz + dw_);
      float r2 = rel2[0];
#pragma unroll
      for (int r = 1; r < 9; ++r) r2 = (tb == r) ? rel2[r] : r2;
      float trip = (lane < deg) ? dot + r2 : -INFINITY;
      float m2 = waveReduceMax(trip);
      float ex = (lane < deg) ? expf(trip - m2) : 0.f;
      float den2 = waveReduceSum(ex) + 1e-16f;
      if (lane < deg) mask_s[s + lane] = ex / den2;
    } else {
      // ---- generic multi-chunk path (rare) ----
      int cnt[9] = {0, 0, 0, 0, 0, 0, 0, 0, 0};
      for (int base = s; base < e; base += 64) {
        int c = min(64, e - base);
        int pk = (lane < c) ? packed[base + lane] : -1;
        int t = pk >> 20;
#pragma unroll
        for (int r = 0; r < 9; ++r) cnt[r] += __popcll(__ballot(t == r));
      }
      float m1 = -INFINITY;
#pragma unroll
      for (int r = 0; r < 9; ++r)
        if (cnt[r] > 0) m1 = fmaxf(m1, sb[r]);
      float den1 = 0.f;
#pragma unroll
      for (int r = 0; r < 9; ++r)
        if (cnt[r] > 0) den1 += (float)cnt[r] * expf(sb[r] - m1);
      den1 += 1e-16f;
      float rel2[9];
#pragma unroll
      for (int r = 0; r < 9; ++r) {
        float rs = expf(sb[r] - m1) / den1;
        rel2[r] = rs * rs * wsq[r];
      }
      float m2l = -INFINITY;
      for (int base = s; base < e; base += 64) {
        int c = min(64, e - base);
        int pk = (lane < c) ? packed[base + lane] : 0;
        int tb = (pk >> 20) & 15;
        int tl = pk & 0xFFFFF;
        const float4* row = (const float4*)(ent0 + (size_t)tl * 64);
        float dx = 0.f, dy = 0.f, dz = 0.f, dw_ = 0.f;
#pragma unroll
        for (int q = 0; q < 16; ++q) {
          float4 a = eh4[q];
          float4 b = row[q];
          dx += a.x * b.x; dy += a.y * b.y; dz += a.z * b.z; dw_ += a.w * b.w;
        }
        float dot = (dx + dy) + (dz + dw_);
        float r2 = rel2[0];
#pragma unroll
        for (int r = 1; r < 9; ++r) r2 = (tb == r) ? rel2[r] : r2;
        float trip = dot + r2;
        if (lane < c) {
          mask_s[base + lane] = trip;
          m2l = fmaxf(m2l, trip);
        }
      }
      float m2 = waveReduceMax(m2l);
      float denl = 0.f;
      for (int base = s; base < e; base += 64) {
        int c = min(64, e - base);
        denl += (lane < c) ? expf(mask_s[base + lane] - m2) : 0.f;
      }
      float den2 = waveReduceSum(denl) + 1e-16f;
      for (int base = s; base < e; base += 64) {
        int c = min(64, e - base);
        if (lane < c) mask_s[base + lane] = expf(mask_s[base + lane] - m2) / den2;
      }
    }
  } else {
    __shared__ float lat[256];
    __shared__ float dwl[256];
    if (threadIdx.x < 256) {
      lat[threadIdx.x] = latent[threadIdx.x];
      dwl[threadIdx.x] = dw[threadIdx.x];
    }
    __syncthreads();
    int usr = (blockIdx.x - KG_BLOCKS) * 4 + wid;  // always < N_USR
    ui_body(usr, lane, ent0, user_emb, user_emb, out_usr, usr1,
            uptr, col_s, val_s, lat, dwl);
  }
}

// ---------------- hop kernel: KG agg (blocks < kg_blocks) + optional UI agg ----------------
__global__ void k_hop(const float* __restrict__ src,
                      const float* __restrict__ addb_e, float* __restrict__ outp_e,
                      float* __restrict__ nxt_e,
                      const int* __restrict__ hptr, const int* __restrict__ packed,
                      const float* __restrict__ mask_s, const float* __restrict__ weight,
                      const float* __restrict__ ucur, const float* __restrict__ addb_u,
                      float* __restrict__ outp_u, float* __restrict__ nxt_u,
                      const int* __restrict__ uptr, const int* __restrict__ col_s,
                      const float* __restrict__ val_s, const float* __restrict__ latent,
                      const float* __restrict__ dw, int kg_blocks) {
  int lane = threadIdx.x & 63, wid = threadIdx.x >> 6;
  if ((int)blockIdx.x < kg_blocks) {
    __shared__ float wl[576];
    for (int i = threadIdx.x; i < 576; i += 256) wl[i] = weight[i];
    __syncthreads();
    int ent = blockIdx.x * 4 + wid;  // always < N_ENT
    int s = hptr[ent], e = hptr[ent + 1];
    float acc = 0.f;
    for (int base = s; base < e; base += 64) {
      int c = min(64, e - base);
      int pk = (lane < c) ? packed[base + lane] : 0;
      float mk = (lane < c) ? mask_s[base + lane] : 0.f;
      int j = 0;
      for (; j + 4 <= c; j += 4) {
        int p0 = __shfl(pk, j), p1 = __shfl(pk, j + 1), p2 = __shfl(pk, j + 2), p3 = __shfl(pk, j + 3);
        float k0 = __shfl(mk, j), k1 = __shfl(mk, j + 1), k2 = __shfl(mk, j + 2), k3 = __shfl(mk, j + 3);
        float r0 = src[(size_t)(p0 & 0xFFFFF) * 64 + lane];
        float r1 = src[(size_t)(p1 & 0xFFFFF) * 64 + lane];
        float r2 = src[(size_t)(p2 & 0xFFFFF) * 64 + lane];
        float r3 = src[(size_t)(p3 & 0xFFFFF) * 64 + lane];
        acc += r0 * wl[((p0 >> 20) & 15) * 64 + lane] * k0;
        acc += r1 * wl[((p1 >> 20) & 15) * 64 + lane] * k1;
        acc += r2 * wl[((p2 >> 20) & 15) * 64 + lane] * k2;
        acc += r3 * wl[((p3 >> 20) & 15) * 64 + lane] * k3;
      }
      for (; j < c; ++j) {
        int pj = __shfl(pk, j);
        float kj = __shfl(mk, j);
        acc += src[(size_t)(pj & 0xFFFFF) * 64 + lane] * wl[((pj >> 20) & 15) * 64 + lane] * kj;
      }
    }
    float n = (float)(e - s);
    float agg = acc / fmaxf(n, 1.0f);
    float nrm = sqrtf(waveReduceSum(agg * agg));
    float val = agg / fmaxf(nrm, 1e-12f);
    size_t o = (size_t)ent * 64 + lane;
    if (nxt_e) nxt_e[o] = val;
    outp_e[o] = addb_e[o] + val;
  } else {
    __shared__ float lat[256];
    __shared__ float dwl[256];
    if (threadIdx.x < 256) {
      lat[threadIdx.x] = latent[threadIdx.x];
      dwl[threadIdx.x] = dw[threadIdx.x];
    }
    __syncthreads();
    int usr = (blockIdx.x - kg_blocks) * 4 + wid;  // always < N_USR
    ui_body(usr, lane, src, ucur, addb_u, outp_u, nxt_u,
            uptr, col_s, val_s, lat, dwl);
  }
}

extern "C" void kernel_launch(void* const* d_in, const int* in_sizes, int n_in,
                              void* d_out, int out_size, void* d_ws, size_t ws_size,
                              hipStream_t stream) {
  const float* user_emb = (const float*)d_in[0];
  const float* entity_emb = (const float*)d_in[1];
  const float* latent = (const float*)d_in[2];
  const float* weight = (const float*)d_in[3];
  const float* disen = (const float*)d_in[4];
  const float* kgW = (const float*)d_in[5];
  const float* ui_vals = (const float*)d_in[6];
  const int* edge_index = (const int*)d_in[7];
  const int* edge_type = (const int*)d_in[8];
  const int* ui_rows = (const int*)d_in[9];
  const int* ui_cols = (const int*)d_in[10];
  const int* head = edge_index;
  const int* tail = edge_index + N_EDGE;

  char* ws = (char*)d_ws;
  size_t o = 0;
  auto alloc = [&](size_t bytes) -> char* {
    char* p = ws + o;
    o += (bytes + 255) & ~(size_t)255;
    return p;
  };
  int* head_ptr = (int*)alloc((N_ENT + 1) * 4);
  int* head_cur = (int*)alloc((size_t)N_ENT * 4);
  int* ui_ptr = (int*)alloc((N_USR + 1) * 4);
  int* ui_cur = (int*)alloc((size_t)N_USR * 4);
  int* bsum_h = (int*)alloc(256 * 4);
  int* bsum_u = (int*)alloc(256 * 4);
  int* packed = (int*)alloc((size_t)N_EDGE * 4);
  int* col_s = (int*)alloc((size_t)N_EDGE * 4);
  float* val_s = (float*)alloc((size_t)N_EDGE * 4);
  float* mask_s = (float*)alloc((size_t)N_EDGE * 4);
  float* ent1 = (float*)alloc((size_t)N_ENT * 64 * 4);
  float* usr1 = (float*)alloc((size_t)N_USR * 64 * 4);
  float* V = (float*)alloc(9 * 64 * 4);
  float* wsq = (float*)alloc(16 * 4);
  float* dw = (float*)alloc(4 * 64 * 4);
  if (o > ws_size) return;

  float* out_ent = (float*)d_out;
  float* out_usr = out_ent + (size_t)N_ENT * 64;
  float* out_cor = out_ent + (size_t)N_ENT * 64 + (size_t)N_USR * 64;

  hipMemsetAsync(head_cur, 0, (size_t)N_ENT * 4, stream);
  hipMemsetAsync(ui_cur, 0, (size_t)N_USR * 4, stream);

  int eb = (N_EDGE + 255) / 256;
  k_count<<<eb, 256, 0, stream>>>(head, ui_rows, head_cur, ui_cur);

  int nbh = (N_ENT + 1023) / 1024, nbu = (N_USR + 1023) / 1024;
  k_scan_reduce<<<nbh, 256, 0, stream>>>(head_cur, N_ENT, bsum_h);
  k_scan_reduce<<<nbu, 256, 0, stream>>>(ui_cur, N_USR, bsum_u);
  k_scan_tops<<<1, 64, 0, stream>>>(bsum_h, nbh, bsum_u, nbu, head_ptr, N_ENT, ui_ptr, N_USR, N_EDGE);
  k_scan_final<<<nbh, 256, 0, stream>>>(head_cur, N_ENT, bsum_h, head_ptr, head_cur);
  k_scan_final<<<nbu, 256, 0, stream>>>(ui_cur, N_USR, bsum_u, ui_ptr, ui_cur);

  k_build<<<eb, 256, 0, stream>>>(head, tail, edge_type, ui_rows, ui_cols, ui_vals,
                                  head_cur, ui_cur, packed, col_s, val_s);

  k_prep<<<1, 256, 0, stream>>>(weight, kgW, disen, V, wsq, dw, out_cor);

  // D1: mask (edge-parallel dots) + UI hop-1 fused
  k_mask_ui<<<KG_BLOCKS + UI_BLOCKS, 256, 0, stream>>>(
      entity_emb, head_ptr, packed, V, wsq, mask_s,
      user_emb, out_usr, usr1, ui_ptr, col_s, val_s, latent, dw);

  // D2: KG hop-1 (no UI blocks)
  k_hop<<<KG_BLOCKS, 256, 0, stream>>>(
      entity_emb, entity_emb, out_ent, ent1, head_ptr, packed, mask_s, weight,
      nullptr, nullptr, nullptr, nullptr, ui_ptr, col_s, val_s, latent, dw, KG_BLOCKS);

  // D3: KG hop-2 + UI hop-2 fused
  k_hop<<<KG_BLOCKS + UI_BLOCKS, 256, 0, stream>>>(
      ent1, out_ent, out_ent, nullptr, head_ptr, packed, mask_s, weight,
      usr1, out_usr, out_usr, nullptr, ui_ptr, col_s, val_s, latent, dw, KG_BLOCKS);
}

// Round 4
// 746.446 us; speedup vs baseline: 1.2302x; 1.1109x over previous
//
#include <hip/hip_runtime.h>
#include <math.h>

#define N_ENT 100000
#define N_USR 50000
#define N_EDGE 1000000
#define TEMPC 0.2f
#define KG_BLOCKS (N_ENT / 4)   // 25000, exact
#define UI_BLOCKS (N_USR / 4)   // 12500, exact

typedef unsigned short ushort_t;

__device__ __forceinline__ float waveReduceSum(float x) {
#pragma unroll
  for (int d = 32; d > 0; d >>= 1) x += __shfl_xor(x, d);
  return x;
}
__device__ __forceinline__ float waveReduceMax(float x) {
#pragma unroll
  for (int d = 32; d > 0; d >>= 1) x = fmaxf(x, __shfl_xor(x, d));
  return x;
}
__device__ __forceinline__ int waveReduceSumI(int x) {
#pragma unroll
  for (int d = 32; d > 0; d >>= 1) x += __shfl_xor(x, d);
  return x;
}
__device__ __forceinline__ float bf2f(unsigned int u16) {
  union { unsigned int i; float f; } v;
  v.i = u16 << 16;
  return v.f;
}
__device__ __forceinline__ ushort_t f2bf(float f) {
  union { unsigned int i; float f; } v;
  v.f = f;
  unsigned int u = v.i;
  u = (u + 0x7FFFu + ((u >> 16) & 1u)) >> 16;
  return (ushort_t)u;
}

// ---------------- CSR build ----------------
__global__ void k_count(const int* __restrict__ head, const int* __restrict__ uir,
                        int* __restrict__ cnt_h, int* __restrict__ cnt_u) {
  int i = blockIdx.x * blockDim.x + threadIdx.x;
  if (i < N_EDGE) {
    atomicAdd(&cnt_h[head[i]], 1);
    atomicAdd(&cnt_u[uir[i]], 1);
  }
}

__global__ void k_scan_reduce(const int* __restrict__ cnt, int n, int* __restrict__ bsum) {
  int b = blockIdx.x, tid = threadIdx.x;
  int i0 = b * 1024 + tid * 4;
  int s = 0;
#pragma unroll
  for (int k = 0; k < 4; ++k)
    if (i0 + k < n) s += cnt[i0 + k];
  s = waveReduceSumI(s);
  __shared__ int l[4];
  int lane = tid & 63, wid = tid >> 6;
  if (lane == 0) l[wid] = s;
  __syncthreads();
  if (tid == 0) bsum[b] = l[0] + l[1] + l[2] + l[3];
}

__global__ void k_scan_tops(int* bsA, int nA, int* bsB, int nB,
                            int* ptrA, int NA, int* ptrB, int NB, int total) {
  if (threadIdx.x == 0) {
    int a = 0;
    for (int i = 0; i < nA; ++i) { int t = bsA[i]; bsA[i] = a; a += t; }
    ptrA[NA] = total;
  }
  if (threadIdx.x == 1) {
    int a = 0;
    for (int i = 0; i < nB; ++i) { int t = bsB[i]; bsB[i] = a; a += t; }
    ptrB[NB] = total;
  }
}

__global__ void k_scan_final(int* __restrict__ cnt, int n, const int* __restrict__ bsum,
                             int* __restrict__ ptr, int* __restrict__ cur) {
  int b = blockIdx.x, tid = threadIdx.x;
  int i0 = b * 1024 + tid * 4;
  int c[4];
  int s = 0;
  int loc[4];
#pragma unroll
  for (int k = 0; k < 4; ++k) {
    c[k] = (i0 + k < n) ? cnt[i0 + k] : 0;
    loc[k] = s;
    s += c[k];
  }
  int lane = tid & 63, wid = tid >> 6;
  int x = s;
#pragma unroll
  for (int d = 1; d < 64; d <<= 1) {
    int y = __shfl_up(x, d);
    if (lane >= d) x += y;
  }
  __shared__ int l[4];
  if (lane == 63) l[wid] = x;
  __syncthreads();
  if (tid == 0) {
    int a = 0;
    for (int w = 0; w < 4; ++w) { int t = l[w]; l[w] = a; a += t; }
  }
  __syncthreads();
  int excl = x - s + l[wid] + bsum[b];
#pragma unroll
  for (int k = 0; k < 4; ++k) {
    if (i0 + k < n) {
      int v = excl + loc[k];
      ptr[i0 + k] = v;
      cur[i0 + k] = v;
    }
  }
}

__global__ void k_build(const int* __restrict__ head, const int* __restrict__ tail,
                        const int* __restrict__ etype,
                        const int* __restrict__ uir, const int* __restrict__ uic,
                        const float* __restrict__ uival,
                        int* __restrict__ cur_h, int* __restrict__ cur_u,
                        int* __restrict__ packed, int* __restrict__ col_s,
                        float* __restrict__ val_s) {
  int i = blockIdx.x * blockDim.x + threadIdx.x;
  if (i < N_EDGE) {
    int h = head[i];
    int p = atomicAdd(&cur_h[h], 1);
    packed[p] = (tail[i] & 0xFFFFF) | ((etype[i] - 1) << 20);
    int u = uir[i];
    int q = atomicAdd(&cur_u[u], 1);
    col_s[q] = uic[i];
    val_s[q] = uival[i];
  }
}

// ---------------- fp32 -> bf16 table conversion ----------------
__global__ void k_tobf(const float* __restrict__ src, ushort_t* __restrict__ dst, int n4) {
  int i = blockIdx.x * blockDim.x + threadIdx.x;
  if (i < n4) {
    float4 v = ((const float4*)src)[i];
    ushort4 o;
    o.x = f2bf(v.x); o.y = f2bf(v.y); o.z = f2bf(v.z); o.w = f2bf(v.w);
    ((ushort4*)dst)[i] = o;
  }
}

// ---------------- tiny precompute: V = (W W^T) w_r, wsq, disen_w, cor ----------------
__global__ void k_prep(const float* __restrict__ weight, const float* __restrict__ kgW,
                       const float* __restrict__ disen,
                       float* __restrict__ V, float* __restrict__ wsq,
                       float* __restrict__ dw, float* __restrict__ cor_out) {
  __shared__ float M[64 * 64];
  __shared__ float sm[4 * 9];
  int tid = threadIdx.x;
  for (int e = tid; e < 64 * 64; e += 256) {
    int i = e >> 6, j = e & 63;
    float s = 0.f;
    for (int k = 0; k < 64; ++k) s += kgW[i * 64 + k] * kgW[j * 64 + k];
    M[e] = s;
  }
  if (tid < 4) {
    float m = -INFINITY;
    for (int r = 0; r < 9; ++r) m = fmaxf(m, disen[tid * 9 + r]);
    float den = 0.f;
    float ex[9];
    for (int r = 0; r < 9; ++r) { ex[r] = expf(disen[tid * 9 + r] - m); den += ex[r]; }
    for (int r = 0; r < 9; ++r) sm[tid * 9 + r] = ex[r] / den;
  }
  __syncthreads();
  for (int e = tid; e < 9 * 64; e += 256) {
    int r = e >> 6, i = e & 63;
    float s = 0.f;
    for (int k = 0; k < 64; ++k) s += M[i * 64 + k] * weight[r * 64 + k];
    V[e] = s;
  }
  if (tid < 9) {
    float s = 0.f;
    for (int c = 0; c < 64; ++c) { float w = weight[tid * 64 + c]; s += w * w; }
    wsq[tid] = s;
  }
  for (int e = tid; e < 4 * 64; e += 256) {
    int f = e >> 6, c = e & 63;
    float s = 0.f;
    for (int r = 0; r < 9; ++r) s += sm[f * 9 + r] * weight[r * 64 + c];
    dw[e] = s;
  }
  if (tid == 0) {
    float rowsum[4];
    for (int f = 0; f < 4; ++f) {
      float s = 0.f;
      for (int j = 0; j < 9; ++j) s += disen[f * 9 + j];
      rowsum[f] = s;
    }
    float cor = 0.f;
    for (int i = 0; i < 9; ++i) {
      float n2 = 0.f, ttl = 0.f;
      for (int f = 0; f < 4; ++f) {
        float v = disen[f * 9 + i];
        n2 += v * v;
        ttl += v * rowsum[f];
      }
      float nrm = sqrtf(n2);
      float pos = 0.f;
      for (int f = 0; f < 4; ++f) {
        float v = disen[f * 9 + i] / nrm;
        pos += v * v;
      }
      cor += (ttl - pos) / TEMPC;
    }
    *cor_out = cor;
  }
}

// ---------------- UI aggregation body (bf16 gather source) ----------------
__device__ __forceinline__ void ui_body(int usr, int lane,
                                        const ushort_t* __restrict__ srcbf,
                                        const float* __restrict__ ucur,
                                        const float* __restrict__ addb,
                                        float* __restrict__ outp, float* __restrict__ nxt,
                                        const int* __restrict__ uptr,
                                        const int* __restrict__ col_s,
                                        const float* __restrict__ val_s,
                                        const float* __restrict__ lat,
                                        const float* __restrict__ dwl) {
  float uc = ucur[(size_t)usr * 64 + lane];
  float sc[4];
#pragma unroll
  for (int f = 0; f < 4; ++f) sc[f] = waveReduceSum(uc * lat[f * 64 + lane]);
  float m = fmaxf(fmaxf(sc[0], sc[1]), fmaxf(sc[2], sc[3]));
  float e0 = expf(sc[0] - m), e1 = expf(sc[1] - m), e2 = expf(sc[2] - m), e3 = expf(sc[3] - m);
  float den = e0 + e1 + e2 + e3;
  float mix = (e0 * dwl[lane] + e1 * dwl[64 + lane] + e2 * dwl[128 + lane] + e3 * dwl[192 + lane]) / den;
  int s = uptr[usr], e = uptr[usr + 1];
  float acc = 0.f;
  for (int base = s; base < e; base += 64) {
    int c = min(64, e - base);
    int cl = (lane < c) ? col_s[base + lane] : 0;
    float vl = (lane < c) ? val_s[base + lane] : 0.f;
    int j = 0;
    for (; j + 4 <= c; j += 4) {
      int c0 = __shfl(cl, j), c1 = __shfl(cl, j + 1), c2 = __shfl(cl, j + 2), c3 = __shfl(cl, j + 3);
      float v0 = __shfl(vl, j), v1 = __shfl(vl, j + 1), v2 = __shfl(vl, j + 2), v3 = __shfl(vl, j + 3);
      float r0 = bf2f(srcbf[(size_t)c0 * 64 + lane]);
      float r1 = bf2f(srcbf[(size_t)c1 * 64 + lane]);
      float r2 = bf2f(srcbf[(size_t)c2 * 64 + lane]);
      float r3 = bf2f(srcbf[(size_t)c3 * 64 + lane]);
      acc += r0 * v0 + r1 * v1 + r2 * v2 + r3 * v3;
    }
    for (; j < c; ++j) {
      int cj = __shfl(cl, j);
      float vj = __shfl(vl, j);
      acc += bf2f(srcbf[(size_t)cj * 64 + lane]) * vj;
    }
  }
  float ua = acc * mix + acc;
  float nrm = sqrtf(waveReduceSum(ua * ua));
  float val = ua / fmaxf(nrm, 1e-12f);
  size_t o = (size_t)usr * 64 + lane;
  if (nxt) nxt[o] = val;
  outp[o] = addb[o] + val;
}

// ---------------- D1: mask + fused KG hop-1  |  UI hop-1 ----------------
__global__ void k_mask_kg_ui(const float* __restrict__ ent0,
                             const ushort_t* __restrict__ ent0bf,
                             const int* __restrict__ hptr, const int* __restrict__ packed,
                             const float* __restrict__ V, const float* __restrict__ wsq,
                             float* __restrict__ mask_s, const float* __restrict__ weight,
                             float* __restrict__ out_ent, ushort_t* __restrict__ ent1bf,
                             const float* __restrict__ user_emb, float* __restrict__ out_usr,
                             float* __restrict__ usr1, const int* __restrict__ uptr,
                             const int* __restrict__ col_s, const float* __restrict__ val_s,
                             const float* __restrict__ latent, const float* __restrict__ dw) {
  int lane = threadIdx.x & 63, wid = threadIdx.x >> 6;
  if (blockIdx.x < KG_BLOCKS) {
    __shared__ float sh_eh[4][64];
    __shared__ float wl[576];
    for (int i = threadIdx.x; i < 576; i += 256) wl[i] = weight[i];
    int ent = blockIdx.x * 4 + wid;  // always < N_ENT
    int s = hptr[ent], e = hptr[ent + 1];
    float eh = ent0[(size_t)ent * 64 + lane];
    sh_eh[wid][lane] = eh;
    __syncthreads();
    size_t o = (size_t)ent * 64 + lane;
    int deg = e - s;
    if (deg == 0) {  // no edges: agg=0 -> val=0
      ent1bf[o] = f2bf(0.f);
      out_ent[o] = eh;
      return;
    }
    const float inv2s = 0.08838834764831845f;  // 1/(2*sqrt(32))
    float sb[9];
#pragma unroll
    for (int r = 0; r < 9; ++r) sb[r] = waveReduceSum(eh * V[r * 64 + lane]) * inv2s;
    if (deg <= 64) {
      // ---- hot path: whole group in one wave, softmax in registers ----
      int pk = (lane < deg) ? packed[s + lane] : 0;
      int tb = (lane < deg) ? ((pk >> 20) & 15) : 15;
      int cnt[9];
#pragma unroll
      for (int r = 0; r < 9; ++r) cnt[r] = __popcll(__ballot(tb == r));
      float m1 = -INFINITY;
#pragma unroll
      for (int r = 0; r < 9; ++r)
        if (cnt[r] > 0) m1 = fmaxf(m1, sb[r]);
      float den1 = 0.f;
#pragma unroll
      for (int r = 0; r < 9; ++r)
        if (cnt[r] > 0) den1 += (float)cnt[r] * expf(sb[r] - m1);
      den1 += 1e-16f;
      float rel2[9];
#pragma unroll
      for (int r = 0; r < 9; ++r) {
        float rs = expf(sb[r] - m1) / den1;
        rel2[r] = rs * rs * wsq[r];
      }
      float trip = -INFINITY;
      if (lane < deg) {
        int tl = pk & 0xFFFFF;
        const uint4* row = (const uint4*)(ent0bf + (size_t)tl * 64);
        const float* ehp = sh_eh[wid];
        float d = 0.f;
#pragma unroll
        for (int q = 0; q < 8; ++q) {
          uint4 a = row[q];
          d += bf2f(a.x & 0xFFFF) * ehp[q * 8 + 0] + bf2f(a.x >> 16) * ehp[q * 8 + 1];
          d += bf2f(a.y & 0xFFFF) * ehp[q * 8 + 2] + bf2f(a.y >> 16) * ehp[q * 8 + 3];
          d += bf2f(a.z & 0xFFFF) * ehp[q * 8 + 4] + bf2f(a.z >> 16) * ehp[q * 8 + 5];
          d += bf2f(a.w & 0xFFFF) * ehp[q * 8 + 6] + bf2f(a.w >> 16) * ehp[q * 8 + 7];
        }
        float r2 = rel2[0];
#pragma unroll
        for (int r = 1; r < 9; ++r) r2 = (tb == r) ? rel2[r] : r2;
        trip = d + r2;
      }
      float m2 = waveReduceMax(trip);
      float ex = (lane < deg) ? expf(trip - m2) : 0.f;
      float den2 = waveReduceSum(ex) + 1e-16f;
      float mk = ex / den2;
      if (lane < deg) mask_s[s + lane] = mk;
      // ---- fused KG hop-1 aggregation (rows are L1/L2-hot) ----
      float acc = 0.f;
      int j = 0;
      for (; j + 4 <= deg; j += 4) {
        int p0 = __shfl(pk, j), p1 = __shfl(pk, j + 1), p2 = __shfl(pk, j + 2), p3 = __shfl(pk, j + 3);
        float k0 = __shfl(mk, j), k1 = __shfl(mk, j + 1), k2 = __shfl(mk, j + 2), k3 = __shfl(mk, j + 3);
        float r0 = bf2f(ent0bf[(size_t)(p0 & 0xFFFFF) * 64 + lane]);
        float r1 = bf2f(ent0bf[(size_t)(p1 & 0xFFFFF) * 64 + lane]);
        float r2_ = bf2f(ent0bf[(size_t)(p2 & 0xFFFFF) * 64 + lane]);
        float r3 = bf2f(ent0bf[(size_t)(p3 & 0xFFFFF) * 64 + lane]);
        acc += r0 * wl[((p0 >> 20) & 15) * 64 + lane] * k0;
        acc += r1 * wl[((p1 >> 20) & 15) * 64 + lane] * k1;
        acc += r2_ * wl[((p2 >> 20) & 15) * 64 + lane] * k2;
        acc += r3 * wl[((p3 >> 20) & 15) * 64 + lane] * k3;
      }
      for (; j < deg; ++j) {
        int pj = __shfl(pk, j);
        float kj = __shfl(mk, j);
        acc += bf2f(ent0bf[(size_t)(pj & 0xFFFFF) * 64 + lane]) * wl[((pj >> 20) & 15) * 64 + lane] * kj;
      }
      float agg = acc / (float)deg;
      float nrm = sqrtf(waveReduceSum(agg * agg));
      float val = agg / fmaxf(nrm, 1e-12f);
      ent1bf[o] = f2bf(val);
      out_ent[o] = eh + val;
    } else {
      // ---- generic multi-chunk path (statistically unreachable at mean deg 10) ----
      int cnt[9] = {0, 0, 0, 0, 0, 0, 0, 0, 0};
      for (int base = s; base < e; base += 64) {
        int c = min(64, e - base);
        int pk = (lane < c) ? packed[base + lane] : -1;
        int t = pk >> 20;
#pragma unroll
        for (int r = 0; r < 9; ++r) cnt[r] += __popcll(__ballot(t == r));
      }
      float m1 = -INFINITY;
#pragma unroll
      for (int r = 0; r < 9; ++r)
        if (cnt[r] > 0) m1 = fmaxf(m1, sb[r]);
      float den1 = 0.f;
#pragma unroll
      for (int r = 0; r < 9; ++r)
        if (cnt[r] > 0) den1 += (float)cnt[r] * expf(sb[r] - m1);
      den1 += 1e-16f;
      float rel2[9];
#pragma unroll
      for (int r = 0; r < 9; ++r) {
        float rs = expf(sb[r] - m1) / den1;
        rel2[r] = rs * rs * wsq[r];
      }
      float m2l = -INFINITY;
      for (int base = s; base < e; base += 64) {
        int c = min(64, e - base);
        int pk = (lane < c) ? packed[base + lane] : 0;
        int tb = (pk >> 20) & 15;
        int tl = pk & 0xFFFFF;
        const uint4* row = (const uint4*)(ent0bf + (size_t)tl * 64);
        const float* ehp = sh_eh[wid];
        float d = 0.f;
#pragma unroll
        for (int q = 0; q < 8; ++q) {
          uint4 a = row[q];
          d += bf2f(a.x & 0xFFFF) * ehp[q * 8 + 0] + bf2f(a.x >> 16) * ehp[q * 8 + 1];
          d += bf2f(a.y & 0xFFFF) * ehp[q * 8 + 2] + bf2f(a.y >> 16) * ehp[q * 8 + 3];
          d += bf2f(a.z & 0xFFFF) * ehp[q * 8 + 4] + bf2f(a.z >> 16) * ehp[q * 8 + 5];
          d += bf2f(a.w & 0xFFFF) * ehp[q * 8 + 6] + bf2f(a.w >> 16) * ehp[q * 8 + 7];
        }
        float r2 = rel2[0];
#pragma unroll
        for (int r = 1; r < 9; ++r) r2 = (tb == r) ? rel2[r] : r2;
        float trip = d + r2;
        if (lane < c) {
          mask_s[base + lane] = trip;
          m2l = fmaxf(m2l, trip);
        }
      }
      float m2 = waveReduceMax(m2l);
      float denl = 0.f;
      for (int base = s; base < e; base += 64) {
        int c = min(64, e - base);
        denl += (lane < c) ? expf(mask_s[base + lane] - m2) : 0.f;
      }
      float den2 = waveReduceSum(denl) + 1e-16f;
      float acc = 0.f;
      for (int base = s; base < e; base += 64) {
        int c = min(64, e - base);
        int pk = (lane < c) ? packed[base + lane] : 0;
        float mk = 0.f;
        if (lane < c) {
          mk = expf(mask_s[base + lane] - m2) / den2;
          mask_s[base + lane] = mk;
        }
        for (int j = 0; j < c; ++j) {
          int pj = __shfl(pk, j);
          float kj = __shfl(mk, j);
          acc += bf2f(ent0bf[(size_t)(pj & 0xFFFFF) * 64 + lane]) * wl[((pj >> 20) & 15) * 64 + lane] * kj;
        }
      }
      float agg = acc / (float)deg;
      float nrm = sqrtf(waveReduceSum(agg * agg));
      float val = agg / fmaxf(nrm, 1e-12f);
      ent1bf[o] = f2bf(val);
      out_ent[o] = eh + val;
    }
  } else {
    __shared__ float lat[256];
    __shared__ float dwl[256];
    if (threadIdx.x < 256) {
      lat[threadIdx.x] = latent[threadIdx.x];
      dwl[threadIdx.x] = dw[threadIdx.x];
    }
    __syncthreads();
    int usr = (blockIdx.x - KG_BLOCKS) * 4 + wid;  // always < N_USR
    ui_body(usr, lane, ent0bf, user_emb, user_emb, out_usr, usr1,
            uptr, col_s, val_s, lat, dwl);
  }
}

// ---------------- D2: KG hop-2 + UI hop-2 ----------------
__global__ void k_hop2(const ushort_t* __restrict__ srcbf,
                       float* __restrict__ out_ent,
                       const int* __restrict__ hptr, const int* __restrict__ packed,
                       const float* __restrict__ mask_s, const float* __restrict__ weight,
                       const float* __restrict__ usr1, float* __restrict__ out_usr,
                       const int* __restrict__ uptr, const int* __restrict__ col_s,
                       const float* __restrict__ val_s, const float* __restrict__ latent,
                       const float* __restrict__ dw) {
  int lane = threadIdx.x & 63, wid = threadIdx.x >> 6;
  if (blockIdx.x < KG_BLOCKS) {
    __shared__ float wl[576];
    for (int i = threadIdx.x; i < 576; i += 256) wl[i] = weight[i];
    __syncthreads();
    int ent = blockIdx.x * 4 + wid;
    int s = hptr[ent], e = hptr[ent + 1];
    float acc = 0.f;
    for (int base = s; base < e; base += 64) {
      int c = min(64, e - base);
      int pk = (lane < c) ? packed[base + lane] : 0;
      float mk = (lane < c) ? mask_s[base + lane] : 0.f;
      int j = 0;
      for (; j + 4 <= c; j += 4) {
        int p0 = __shfl(pk, j), p1 = __shfl(pk, j + 1), p2 = __shfl(pk, j + 2), p3 = __shfl(pk, j + 3);
        float k0 = __shfl(mk, j), k1 = __shfl(mk, j + 1), k2 = __shfl(mk, j + 2), k3 = __shfl(mk, j + 3);
        float r0 = bf2f(srcbf[(size_t)(p0 & 0xFFFFF) * 64 + lane]);
        float r1 = bf2f(srcbf[(size_t)(p1 & 0xFFFFF) * 64 + lane]);
        float r2 = bf2f(srcbf[(size_t)(p2 & 0xFFFFF) * 64 + lane]);
        float r3 = bf2f(srcbf[(size_t)(p3 & 0xFFFFF) * 64 + lane]);
        acc += r0 * wl[((p0 >> 20) & 15) * 64 + lane] * k0;
        acc += r1 * wl[((p1 >> 20) & 15) * 64 + lane] * k1;
        acc += r2 * wl[((p2 >> 20) & 15) * 64 + lane] * k2;
        acc += r3 * wl[((p3 >> 20) & 15) * 64 + lane] * k3;
      }
      for (; j < c; ++j) {
        int pj = __shfl(pk, j);
        float kj = __shfl(mk, j);
        acc += bf2f(srcbf[(size_t)(pj & 0xFFFFF) * 64 + lane]) * wl[((pj >> 20) & 15) * 64 + lane] * kj;
      }
    }
    float n = (float)(e - s);
    float agg = acc / fmaxf(n, 1.0f);
    float nrm = sqrtf(waveReduceSum(agg * agg));
    float val = agg / fmaxf(nrm, 1e-12f);
    size_t o = (size_t)ent * 64 + lane;
    out_ent[o] = out_ent[o] + val;
  } else {
    __shared__ float lat[256];
    __shared__ float dwl[256];
    if (threadIdx.x < 256) {
      lat[threadIdx.x] = latent[threadIdx.x];
      dwl[threadIdx.x] = dw[threadIdx.x];
    }
    __syncthreads();
    int usr = (blockIdx.x - KG_BLOCKS) * 4 + wid;
    ui_body(usr, lane, srcbf, usr1, out_usr, out_usr, nullptr,
            uptr, col_s, val_s, lat, dwl);
  }
}

extern "C" void kernel_launch(void* const* d_in, const int* in_sizes, int n_in,
                              void* d_out, int out_size, void* d_ws, size_t ws_size,
                              hipStream_t stream) {
  const float* user_emb = (const float*)d_in[0];
  const float* entity_emb = (const float*)d_in[1];
  const float* latent = (const float*)d_in[2];
  const float* weight = (const float*)d_in[3];
  const float* disen = (const float*)d_in[4];
  const float* kgW = (const float*)d_in[5];
  const float* ui_vals = (const float*)d_in[6];
  const int* edge_index = (const int*)d_in[7];
  const int* edge_type = (const int*)d_in[8];
  const int* ui_rows = (const int*)d_in[9];
  const int* ui_cols = (const int*)d_in[10];
  const int* head = edge_index;
  const int* tail = edge_index + N_EDGE;

  char* ws = (char*)d_ws;
  size_t o = 0;
  auto alloc = [&](size_t bytes) -> char* {
    char* p = ws + o;
    o += (bytes + 255) & ~(size_t)255;
    return p;
  };
  int* head_ptr = (int*)alloc((N_ENT + 1) * 4);
  int* head_cur = (int*)alloc((size_t)N_ENT * 4);
  int* ui_ptr = (int*)alloc((N_USR + 1) * 4);
  int* ui_cur = (int*)alloc((size_t)N_USR * 4);
  int* bsum_h = (int*)alloc(256 * 4);
  int* bsum_u = (int*)alloc(256 * 4);
  int* packed = (int*)alloc((size_t)N_EDGE * 4);
  int* col_s = (int*)alloc((size_t)N_EDGE * 4);
  float* val_s = (float*)alloc((size_t)N_EDGE * 4);
  float* mask_s = (float*)alloc((size_t)N_EDGE * 4);
  ushort_t* ent0bf = (ushort_t*)alloc((size_t)N_ENT * 64 * 2);
  ushort_t* ent1bf = (ushort_t*)alloc((size_t)N_ENT * 64 * 2);
  float* usr1 = (float*)alloc((size_t)N_USR * 64 * 4);
  float* V = (float*)alloc(9 * 64 * 4);
  float* wsq = (float*)alloc(16 * 4);
  float* dw = (float*)alloc(4 * 64 * 4);
  if (o > ws_size) return;

  float* out_ent = (float*)d_out;
  float* out_usr = out_ent + (size_t)N_ENT * 64;
  float* out_cor = out_ent + (size_t)N_ENT * 64 + (size_t)N_USR * 64;

  hipMemsetAsync(head_cur, 0, (size_t)N_ENT * 4, stream);
  hipMemsetAsync(ui_cur, 0, (size_t)N_USR * 4, stream);

  int eb = (N_EDGE + 255) / 256;
  k_count<<<eb, 256, 0, stream>>>(head, ui_rows, head_cur, ui_cur);

  int nbh = (N_ENT + 1023) / 1024, nbu = (N_USR + 1023) / 1024;
  k_scan_reduce<<<nbh, 256, 0, stream>>>(head_cur, N_ENT, bsum_h);
  k_scan_reduce<<<nbu, 256, 0, stream>>>(ui_cur, N_USR, bsum_u);
  k_scan_tops<<<1, 64, 0, stream>>>(bsum_h, nbh, bsum_u, nbu, head_ptr, N_ENT, ui_ptr, N_USR, N_EDGE);
  k_scan_final<<<nbh, 256, 0, stream>>>(head_cur, N_ENT, bsum_h, head_ptr, head_cur);
  k_scan_final<<<nbu, 256, 0, stream>>>(ui_cur, N_USR, bsum_u, ui_ptr, ui_cur);

  k_build<<<eb, 256, 0, stream>>>(head, tail, edge_type, ui_rows, ui_cols, ui_vals,
                                  head_cur, ui_cur, packed, col_s, val_s);

  k_tobf<<<(N_ENT * 64 / 4 + 255) / 256, 256, 0, stream>>>(entity_emb, ent0bf, N_ENT * 64 / 4);
  k_prep<<<1, 256, 0, stream>>>(weight, kgW, disen, V, wsq, dw, out_cor);

  // D1: mask + fused KG hop-1 + UI hop-1
  k_mask_kg_ui<<<KG_BLOCKS + UI_BLOCKS, 256, 0, stream>>>(
      entity_emb, ent0bf, head_ptr, packed, V, wsq, mask_s, weight,
      out_ent, ent1bf, user_emb, out_usr, usr1, ui_ptr, col_s, val_s, latent, dw);

  // D2: KG hop-2 + UI hop-2
  k_hop2<<<KG_BLOCKS + UI_BLOCKS, 256, 0, stream>>>(
      ent1bf, out_ent, head_ptr, packed, mask_s, weight,
      usr1, out_usr, ui_ptr, col_s, val_s, latent, dw);
}

// Round 5
// 724.220 us; speedup vs baseline: 1.2679x; 1.0307x over previous
//
#include <hip/hip_runtime.h>
#include <math.h>

#define N_ENT 100000
#define N_USR 50000
#define N_EDGE 1000000
#define TEMPC 0.2f
#define KG_BLOCKS (N_ENT / 4)   // 25000, exact
#define UI_BLOCKS (N_USR / 4)   // 12500, exact

typedef unsigned short ushort_t;

__device__ __forceinline__ float waveReduceSum(float x) {
#pragma unroll
  for (int d = 32; d > 0; d >>= 1) x += __shfl_xor(x, d);
  return x;
}
__device__ __forceinline__ float waveReduceMax(float x) {
#pragma unroll
  for (int d = 32; d > 0; d >>= 1) x = fmaxf(x, __shfl_xor(x, d));
  return x;
}
__device__ __forceinline__ int waveReduceSumI(int x) {
#pragma unroll
  for (int d = 32; d > 0; d >>= 1) x += __shfl_xor(x, d);
  return x;
}
__device__ __forceinline__ float bf2f(unsigned int u16) {
  union { unsigned int i; float f; } v;
  v.i = u16 << 16;
  return v.f;
}
__device__ __forceinline__ ushort_t f2bf(float f) {
  union { unsigned int i; float f; } v;
  v.f = f;
  unsigned int u = v.i;
  u = (u + 0x7FFFu + ((u >> 16) & 1u)) >> 16;
  return (ushort_t)u;
}

// ---------------- CSR build ----------------
__global__ void k_count(const int* __restrict__ head, const int* __restrict__ uir,
                        int* __restrict__ cnt_h, int* __restrict__ cnt_u) {
  int i = blockIdx.x * blockDim.x + threadIdx.x;
  if (i < N_EDGE) {
    atomicAdd(&cnt_h[head[i]], 1);
    atomicAdd(&cnt_u[uir[i]], 1);
  }
}

__global__ void k_scan_reduce(const int* __restrict__ cnt, int n, int* __restrict__ bsum) {
  int b = blockIdx.x, tid = threadIdx.x;
  int i0 = b * 1024 + tid * 4;
  int s = 0;
#pragma unroll
  for (int k = 0; k < 4; ++k)
    if (i0 + k < n) s += cnt[i0 + k];
  s = waveReduceSumI(s);
  __shared__ int l[4];
  int lane = tid & 63, wid = tid >> 6;
  if (lane == 0) l[wid] = s;
  __syncthreads();
  if (tid == 0) bsum[b] = l[0] + l[1] + l[2] + l[3];
}

__global__ void k_scan_tops(int* bsA, int nA, int* bsB, int nB,
                            int* ptrA, int NA, int* ptrB, int NB, int total) {
  if (threadIdx.x == 0) {
    int a = 0;
    for (int i = 0; i < nA; ++i) { int t = bsA[i]; bsA[i] = a; a += t; }
    ptrA[NA] = total;
  }
  if (threadIdx.x == 1) {
    int a = 0;
    for (int i = 0; i < nB; ++i) { int t = bsB[i]; bsB[i] = a; a += t; }
    ptrB[NB] = total;
  }
}

__global__ void k_scan_final(int* __restrict__ cnt, int n, const int* __restrict__ bsum,
                             int* __restrict__ ptr, int* __restrict__ cur) {
  int b = blockIdx.x, tid = threadIdx.x;
  int i0 = b * 1024 + tid * 4;
  int c[4];
  int s = 0;
  int loc[4];
#pragma unroll
  for (int k = 0; k < 4; ++k) {
    c[k] = (i0 + k < n) ? cnt[i0 + k] : 0;
    loc[k] = s;
    s += c[k];
  }
  int lane = tid & 63, wid = tid >> 6;
  int x = s;
#pragma unroll
  for (int d = 1; d < 64; d <<= 1) {
    int y = __shfl_up(x, d);
    if (lane >= d) x += y;
  }
  __shared__ int l[4];
  if (lane == 63) l[wid] = x;
  __syncthreads();
  if (tid == 0) {
    int a = 0;
    for (int w = 0; w < 4; ++w) { int t = l[w]; l[w] = a; a += t; }
  }
  __syncthreads();
  int excl = x - s + l[wid] + bsum[b];
#pragma unroll
  for (int k = 0; k < 4; ++k) {
    if (i0 + k < n) {
      int v = excl + loc[k];
      ptr[i0 + k] = v;
      cur[i0 + k] = v;
    }
  }
}

__global__ void k_build(const int* __restrict__ head, const int* __restrict__ tail,
                        const int* __restrict__ etype,
                        const int* __restrict__ uir, const int* __restrict__ uic,
                        const float* __restrict__ uival,
                        int* __restrict__ cur_h, int* __restrict__ cur_u,
                        int* __restrict__ packed, int* __restrict__ col_s,
                        float* __restrict__ val_s) {
  int i = blockIdx.x * blockDim.x + threadIdx.x;
  if (i < N_EDGE) {
    int h = head[i];
    int p = atomicAdd(&cur_h[h], 1);
    packed[p] = (tail[i] & 0xFFFFF) | ((etype[i] - 1) << 20);
    int u = uir[i];
    int q = atomicAdd(&cur_u[u], 1);
    col_s[q] = uic[i];
    val_s[q] = uival[i];
  }
}

// ---------------- fp32 -> bf16 table conversion ----------------
__global__ void k_tobf(const float* __restrict__ src, ushort_t* __restrict__ dst, int n4) {
  int i = blockIdx.x * blockDim.x + threadIdx.x;
  if (i < n4) {
    float4 v = ((const float4*)src)[i];
    ushort4 o;
    o.x = f2bf(v.x); o.y = f2bf(v.y); o.z = f2bf(v.z); o.w = f2bf(v.w);
    ((ushort4*)dst)[i] = o;
  }
}

// ---------------- tiny precompute: V = (W W^T) w_r, wsq, disen_w, cor ----------------
__global__ void k_prep(const float* __restrict__ weight, const float* __restrict__ kgW,
                       const float* __restrict__ disen,
                       float* __restrict__ V, float* __restrict__ wsq,
                       float* __restrict__ dw, float* __restrict__ cor_out) {
  __shared__ float M[64 * 64];
  __shared__ float sm[4 * 9];
  int tid = threadIdx.x;
  for (int e = tid; e < 64 * 64; e += 256) {
    int i = e >> 6, j = e & 63;
    float s = 0.f;
    for (int k = 0; k < 64; ++k) s += kgW[i * 64 + k] * kgW[j * 64 + k];
    M[e] = s;
  }
  if (tid < 4) {
    float m = -INFINITY;
    for (int r = 0; r < 9; ++r) m = fmaxf(m, disen[tid * 9 + r]);
    float den = 0.f;
    float ex[9];
    for (int r = 0; r < 9; ++r) { ex[r] = expf(disen[tid * 9 + r] - m); den += ex[r]; }
    for (int r = 0; r < 9; ++r) sm[tid * 9 + r] = ex[r] / den;
  }
  __syncthreads();
  for (int e = tid; e < 9 * 64; e += 256) {
    int r = e >> 6, i = e & 63;
    float s = 0.f;
    for (int k = 0; k < 64; ++k) s += M[i * 64 + k] * weight[r * 64 + k];
    V[e] = s;
  }
  if (tid < 9) {
    float s = 0.f;
    for (int c = 0; c < 64; ++c) { float w = weight[tid * 64 + c]; s += w * w; }
    wsq[tid] = s;
  }
  for (int e = tid; e < 4 * 64; e += 256) {
    int f = e >> 6, c = e & 63;
    float s = 0.f;
    for (int r = 0; r < 9; ++r) s += sm[f * 9 + r] * weight[r * 64 + c];
    dw[e] = s;
  }
  if (tid == 0) {
    float rowsum[4];
    for (int f = 0; f < 4; ++f) {
      float s = 0.f;
      for (int j = 0; j < 9; ++j) s += disen[f * 9 + j];
      rowsum[f] = s;
    }
    float cor = 0.f;
    for (int i = 0; i < 9; ++i) {
      float n2 = 0.f, ttl = 0.f;
      for (int f = 0; f < 4; ++f) {
        float v = disen[f * 9 + i];
        n2 += v * v;
        ttl += v * rowsum[f];
      }
      float nrm = sqrtf(n2);
      float pos = 0.f;
      for (int f = 0; f < 4; ++f) {
        float v = disen[f * 9 + i] / nrm;
        pos += v * v;
      }
      cor += (ttl - pos) / TEMPC;
    }
    *cor_out = cor;
  }
}

// ---------------- UI aggregation body (bf16 gather source, 4 acc chains) ----------------
__device__ __forceinline__ void ui_body(int usr, int lane,
                                        const ushort_t* __restrict__ srcbf,
                                        const float* __restrict__ ucur,
                                        const float* __restrict__ addb,
                                        float* __restrict__ outp, float* __restrict__ nxt,
                                        const int* __restrict__ uptr,
                                        const int* __restrict__ col_s,
                                        const float* __restrict__ val_s,
                                        const float* __restrict__ lat,
                                        const float* __restrict__ dwl) {
  float uc = ucur[(size_t)usr * 64 + lane];
  float sc[4];
#pragma unroll
  for (int f = 0; f < 4; ++f) sc[f] = waveReduceSum(uc * lat[f * 64 + lane]);
  float m = fmaxf(fmaxf(sc[0], sc[1]), fmaxf(sc[2], sc[3]));
  float e0 = expf(sc[0] - m), e1 = expf(sc[1] - m), e2 = expf(sc[2] - m), e3 = expf(sc[3] - m);
  float den = e0 + e1 + e2 + e3;
  float mix = (e0 * dwl[lane] + e1 * dwl[64 + lane] + e2 * dwl[128 + lane] + e3 * dwl[192 + lane]) / den;
  int s = uptr[usr], e = uptr[usr + 1];
  float a0 = 0.f, a1 = 0.f, a2 = 0.f, a3 = 0.f;
  for (int base = s; base < e; base += 64) {
    int c = min(64, e - base);
    int cl = (lane < c) ? col_s[base + lane] : 0;
    float vl = (lane < c) ? val_s[base + lane] : 0.f;
    int j = 0;
    for (; j + 8 <= c; j += 8) {
      int c0 = __shfl(cl, j), c1 = __shfl(cl, j + 1), c2 = __shfl(cl, j + 2), c3 = __shfl(cl, j + 3);
      int c4 = __shfl(cl, j + 4), c5 = __shfl(cl, j + 5), c6 = __shfl(cl, j + 6), c7 = __shfl(cl, j + 7);
      float v0 = __shfl(vl, j), v1 = __shfl(vl, j + 1), v2 = __shfl(vl, j + 2), v3 = __shfl(vl, j + 3);
      float v4 = __shfl(vl, j + 4), v5 = __shfl(vl, j + 5), v6 = __shfl(vl, j + 6), v7 = __shfl(vl, j + 7);
      float r0 = bf2f(srcbf[(c0 << 6) + lane]);
      float r1 = bf2f(srcbf[(c1 << 6) + lane]);
      float r2 = bf2f(srcbf[(c2 << 6) + lane]);
      float r3 = bf2f(srcbf[(c3 << 6) + lane]);
      float r4 = bf2f(srcbf[(c4 << 6) + lane]);
      float r5 = bf2f(srcbf[(c5 << 6) + lane]);
      float r6 = bf2f(srcbf[(c6 << 6) + lane]);
      float r7 = bf2f(srcbf[(c7 << 6) + lane]);
      a0 = fmaf(r0, v0, a0); a1 = fmaf(r1, v1, a1);
      a2 = fmaf(r2, v2, a2); a3 = fmaf(r3, v3, a3);
      a0 = fmaf(r4, v4, a0); a1 = fmaf(r5, v5, a1);
      a2 = fmaf(r6, v6, a2); a3 = fmaf(r7, v7, a3);
    }
    for (; j < c; ++j) {
      int cj = __shfl(cl, j);
      float vj = __shfl(vl, j);
      a0 = fmaf(bf2f(srcbf[(cj << 6) + lane]), vj, a0);
    }
  }
  float acc = (a0 + a1) + (a2 + a3);
  float ua = acc * mix + acc;
  float nrm = sqrtf(waveReduceSum(ua * ua));
  float val = ua / fmaxf(nrm, 1e-12f);
  size_t o = (size_t)usr * 64 + lane;
  if (nxt) nxt[o] = val;
  outp[o] = addb[o] + val;
}

// KG aggregation inner (4 acc chains), deg<=64 hot form over lane-resident pk/mk
__device__ __forceinline__ float kg_agg64(int deg, int lane, int pk, float mk,
                                          const ushort_t* __restrict__ srcbf,
                                          const float* __restrict__ wl) {
  float a0 = 0.f, a1 = 0.f, a2 = 0.f, a3 = 0.f;
  int j = 0;
  for (; j + 4 <= deg; j += 4) {
    int p0 = __shfl(pk, j), p1 = __shfl(pk, j + 1), p2 = __shfl(pk, j + 2), p3 = __shfl(pk, j + 3);
    float k0 = __shfl(mk, j), k1 = __shfl(mk, j + 1), k2 = __shfl(mk, j + 2), k3 = __shfl(mk, j + 3);
    float r0 = bf2f(srcbf[((p0 & 0xFFFFF) << 6) + lane]);
    float r1 = bf2f(srcbf[((p1 & 0xFFFFF) << 6) + lane]);
    float r2 = bf2f(srcbf[((p2 & 0xFFFFF) << 6) + lane]);
    float r3 = bf2f(srcbf[((p3 & 0xFFFFF) << 6) + lane]);
    a0 = fmaf(r0 * wl[(((p0 >> 20) & 15) << 6) + lane], k0, a0);
    a1 = fmaf(r1 * wl[(((p1 >> 20) & 15) << 6) + lane], k1, a1);
    a2 = fmaf(r2 * wl[(((p2 >> 20) & 15) << 6) + lane], k2, a2);
    a3 = fmaf(r3 * wl[(((p3 >> 20) & 15) << 6) + lane], k3, a3);
  }
  for (; j < deg; ++j) {
    int pj = __shfl(pk, j);
    float kj = __shfl(mk, j);
    a0 = fmaf(bf2f(srcbf[((pj & 0xFFFFF) << 6) + lane]) * wl[(((pj >> 20) & 15) << 6) + lane], kj, a0);
  }
  return (a0 + a1) + (a2 + a3);
}

// ---------------- D1: mask + fused KG hop-1  |  UI hop-1 ----------------
__global__ void k_mask_kg_ui(const float* __restrict__ ent0,
                             const ushort_t* __restrict__ ent0bf,
                             const int* __restrict__ hptr, const int* __restrict__ packed,
                             const float* __restrict__ V, const float* __restrict__ wsq,
                             float* __restrict__ mask_s, const float* __restrict__ weight,
                             float* __restrict__ out_ent, ushort_t* __restrict__ ent1bf,
                             const float* __restrict__ user_emb, float* __restrict__ out_usr,
                             float* __restrict__ usr1, const int* __restrict__ uptr,
                             const int* __restrict__ col_s, const float* __restrict__ val_s,
                             const float* __restrict__ latent, const float* __restrict__ dw) {
  int lane = threadIdx.x & 63, wid = threadIdx.x >> 6;
  if (blockIdx.x < KG_BLOCKS) {
    __shared__ __align__(16) float sh_eh[4][64];
    __shared__ float wl[576];
    for (int i = threadIdx.x; i < 576; i += 256) wl[i] = weight[i];
    int ent = blockIdx.x * 4 + wid;  // always < N_ENT
    int s = hptr[ent], e = hptr[ent + 1];
    float eh = ent0[(size_t)ent * 64 + lane];
    sh_eh[wid][lane] = eh;
    __syncthreads();
    size_t o = (size_t)ent * 64 + lane;
    int deg = e - s;
    if (deg == 0) {
      ent1bf[o] = f2bf(0.f);
      out_ent[o] = eh;
      return;
    }
    const float inv2s = 0.08838834764831845f;  // 1/(2*sqrt(32))
    float sb[9];
#pragma unroll
    for (int r = 0; r < 9; ++r) sb[r] = waveReduceSum(eh * V[r * 64 + lane]) * inv2s;
    if (deg <= 64) {
      // ---- hot path ----
      int pk = (lane < deg) ? packed[s + lane] : 0;
      int tb = (lane < deg) ? ((pk >> 20) & 15) : 15;
      int cnt[9];
#pragma unroll
      for (int r = 0; r < 9; ++r) cnt[r] = __popcll(__ballot(tb == r));
      float m1 = -INFINITY;
#pragma unroll
      for (int r = 0; r < 9; ++r)
        if (cnt[r] > 0) m1 = fmaxf(m1, sb[r]);
      float den1 = 0.f;
#pragma unroll
      for (int r = 0; r < 9; ++r)
        if (cnt[r] > 0) den1 += (float)cnt[r] * expf(sb[r] - m1);
      den1 += 1e-16f;
      float rel2[9];
#pragma unroll
      for (int r = 0; r < 9; ++r) {
        float rs = expf(sb[r] - m1) / den1;
        rel2[r] = rs * rs * wsq[r];
      }
      // ---- 8-lane-per-edge dot: lane = 8*slot + part ----
      int part = lane & 7;
      const float4* ehq = (const float4*)(sh_eh[wid] + (part << 3));
      float4 ef0 = ehq[0], ef1 = ehq[1];
      float myDot = 0.f;
      int nch = (deg + 7) >> 3;
      for (int c2 = 0; c2 < nch; ++c2) {
        int pkj = __shfl(pk, (c2 << 3) + (lane >> 3));
        const uint4* row = (const uint4*)(ent0bf + ((pkj & 0xFFFFF) << 6)) + part;
        uint4 b = *row;
        float s0 = bf2f(b.x & 0xFFFFu) * ef0.x;
        float s1 = bf2f(b.y & 0xFFFFu) * ef0.z;
        float s2 = bf2f(b.z & 0xFFFFu) * ef1.x;
        float s3 = bf2f(b.w & 0xFFFFu) * ef1.z;
        s0 = fmaf(bf2f(b.x >> 16), ef0.y, s0);
        s1 = fmaf(bf2f(b.y >> 16), ef0.w, s1);
        s2 = fmaf(bf2f(b.z >> 16), ef1.y, s2);
        s3 = fmaf(bf2f(b.w >> 16), ef1.w, s3);
        float sv = (s0 + s1) + (s2 + s3);
        sv += __shfl_xor(sv, 1);
        sv += __shfl_xor(sv, 2);
        sv += __shfl_xor(sv, 4);
        float got = __shfl(sv, part << 3);
        myDot = ((lane >> 3) == c2) ? got : myDot;
      }
      float r2sel = rel2[0];
#pragma unroll
      for (int r = 1; r < 9; ++r) r2sel = (tb == r) ? rel2[r] : r2sel;
      float trip = (lane < deg) ? myDot + r2sel : -INFINITY;
      float m2 = waveReduceMax(trip);
      float ex = (lane < deg) ? expf(trip - m2) : 0.f;
      float den2 = waveReduceSum(ex) + 1e-16f;
      float mk = ex / den2;
      if (lane < deg) mask_s[s + lane] = mk;
      // ---- fused KG hop-1 aggregation (rows L1/L2-hot) ----
      float acc = kg_agg64(deg, lane, pk, mk, ent0bf, wl);
      float agg = acc / (float)deg;
      float nrm = sqrtf(waveReduceSum(agg * agg));
      float val = agg / fmaxf(nrm, 1e-12f);
      ent1bf[o] = f2bf(val);
      out_ent[o] = eh + val;
    } else {
      // ---- generic multi-chunk path (statistically unreachable at mean deg 10) ----
      int cnt[9] = {0, 0, 0, 0, 0, 0, 0, 0, 0};
      for (int base = s; base < e; base += 64) {
        int c = min(64, e - base);
        int pk = (lane < c) ? packed[base + lane] : -1;
        int t = pk >> 20;
#pragma unroll
        for (int r = 0; r < 9; ++r) cnt[r] += __popcll(__ballot(t == r));
      }
      float m1 = -INFINITY;
#pragma unroll
      for (int r = 0; r < 9; ++r)
        if (cnt[r] > 0) m1 = fmaxf(m1, sb[r]);
      float den1 = 0.f;
#pragma unroll
      for (int r = 0; r < 9; ++r)
        if (cnt[r] > 0) den1 += (float)cnt[r] * expf(sb[r] - m1);
      den1 += 1e-16f;
      float rel2[9];
#pragma unroll
      for (int r = 0; r < 9; ++r) {
        float rs = expf(sb[r] - m1) / den1;
        rel2[r] = rs * rs * wsq[r];
      }
      float m2l = -INFINITY;
      for (int base = s; base < e; base += 64) {
        int c = min(64, e - base);
        int pk = (lane < c) ? packed[base + lane] : 0;
        int tb = (pk >> 20) & 15;
        int tl = pk & 0xFFFFF;
        const uint4* row = (const uint4*)(ent0bf + (tl << 6));
        const float* ehp = sh_eh[wid];
        float d = 0.f;
#pragma unroll
        for (int q = 0; q < 8; ++q) {
          uint4 a = row[q];
          d += bf2f(a.x & 0xFFFF) * ehp[q * 8 + 0] + bf2f(a.x >> 16) * ehp[q * 8 + 1];
          d += bf2f(a.y & 0xFFFF) * ehp[q * 8 + 2] + bf2f(a.y >> 16) * ehp[q * 8 + 3];
          d += bf2f(a.z & 0xFFFF) * ehp[q * 8 + 4] + bf2f(a.z >> 16) * ehp[q * 8 + 5];
          d += bf2f(a.w & 0xFFFF) * ehp[q * 8 + 6] + bf2f(a.w >> 16) * ehp[q * 8 + 7];
        }
        float r2 = rel2[0];
#pragma unroll
        for (int r = 1; r < 9; ++r) r2 = (tb == r) ? rel2[r] : r2;
        float trip = d + r2;
        if (lane < c) {
          mask_s[base + lane] = trip;
          m2l = fmaxf(m2l, trip);
        }
      }
      float m2 = waveReduceMax(m2l);
      float denl = 0.f;
      for (int base = s; base < e; base += 64) {
        int c = min(64, e - base);
        denl += (lane < c) ? expf(mask_s[base + lane] - m2) : 0.f;
      }
      float den2 = waveReduceSum(denl) + 1e-16f;
      float acc = 0.f;
      for (int base = s; base < e; base += 64) {
        int c = min(64, e - base);
        int pk = (lane < c) ? packed[base + lane] : 0;
        float mk = 0.f;
        if (lane < c) {
          mk = expf(mask_s[base + lane] - m2) / den2;
          mask_s[base + lane] = mk;
        }
        acc += kg_agg64(c, lane, pk, mk, ent0bf, wl);
      }
      float agg = acc / (float)deg;
      float nrm = sqrtf(waveReduceSum(agg * agg));
      float val = agg / fmaxf(nrm, 1e-12f);
      ent1bf[o] = f2bf(val);
      out_ent[o] = eh + val;
    }
  } else {
    __shared__ float lat[256];
    __shared__ float dwl[256];
    if (threadIdx.x < 256) {
      lat[threadIdx.x] = latent[threadIdx.x];
      dwl[threadIdx.x] = dw[threadIdx.x];
    }
    __syncthreads();
    int usr = (blockIdx.x - KG_BLOCKS) * 4 + wid;  // always < N_USR
    ui_body(usr, lane, ent0bf, user_emb, user_emb, out_usr, usr1,
            uptr, col_s, val_s, lat, dwl);
  }
}

// ---------------- D2: KG hop-2 + UI hop-2 ----------------
__global__ void k_hop2(const ushort_t* __restrict__ srcbf,
                       float* __restrict__ out_ent,
                       const int* __restrict__ hptr, const int* __restrict__ packed,
                       const float* __restrict__ mask_s, const float* __restrict__ weight,
                       const float* __restrict__ usr1, float* __restrict__ out_usr,
                       const int* __restrict__ uptr, const int* __restrict__ col_s,
                       const float* __restrict__ val_s, const float* __restrict__ latent,
                       const float* __restrict__ dw) {
  int lane = threadIdx.x & 63, wid = threadIdx.x >> 6;
  if (blockIdx.x < KG_BLOCKS) {
    __shared__ float wl[576];
    for (int i = threadIdx.x; i < 576; i += 256) wl[i] = weight[i];
    __syncthreads();
    int ent = blockIdx.x * 4 + wid;
    int s = hptr[ent], e = hptr[ent + 1];
    float acc = 0.f;
    for (int base = s; base < e; base += 64) {
      int c = min(64, e - base);
      int pk = (lane < c) ? packed[base + lane] : 0;
      float mk = (lane < c) ? mask_s[base + lane] : 0.f;
      acc += kg_agg64(c, lane, pk, mk, srcbf, wl);
    }
    float n = (float)(e - s);
    float agg = acc / fmaxf(n, 1.0f);
    float nrm = sqrtf(waveReduceSum(agg * agg));
    float val = agg / fmaxf(nrm, 1e-12f);
    size_t o = (size_t)ent * 64 + lane;
    out_ent[o] = out_ent[o] + val;
  } else {
    __shared__ float lat[256];
    __shared__ float dwl[256];
    if (threadIdx.x < 256) {
      lat[threadIdx.x] = latent[threadIdx.x];
      dwl[threadIdx.x] = dw[threadIdx.x];
    }
    __syncthreads();
    int usr = (blockIdx.x - KG_BLOCKS) * 4 + wid;
    ui_body(usr, lane, srcbf, usr1, out_usr, out_usr, nullptr,
            uptr, col_s, val_s, lat, dwl);
  }
}

extern "C" void kernel_launch(void* const* d_in, const int* in_sizes, int n_in,
                              void* d_out, int out_size, void* d_ws, size_t ws_size,
                              hipStream_t stream) {
  const float* user_emb = (const float*)d_in[0];
  const float* entity_emb = (const float*)d_in[1];
  const float* latent = (const float*)d_in[2];
  const float* weight = (const float*)d_in[3];
  const float* disen = (const float*)d_in[4];
  const float* kgW = (const float*)d_in[5];
  const float* ui_vals = (const float*)d_in[6];
  const int* edge_index = (const int*)d_in[7];
  const int* edge_type = (const int*)d_in[8];
  const int* ui_rows = (const int*)d_in[9];
  const int* ui_cols = (const int*)d_in[10];
  const int* head = edge_index;
  const int* tail = edge_index + N_EDGE;

  char* ws = (char*)d_ws;
  size_t o = 0;
  auto alloc = [&](size_t bytes) -> char* {
    char* p = ws + o;
    o += (bytes + 255) & ~(size_t)255;
    return p;
  };
  int* head_ptr = (int*)alloc((N_ENT + 1) * 4);
  int* head_cur = (int*)alloc((size_t)N_ENT * 4);
  int* ui_ptr = (int*)alloc((N_USR + 1) * 4);
  int* ui_cur = (int*)alloc((size_t)N_USR * 4);
  int* bsum_h = (int*)alloc(256 * 4);
  int* bsum_u = (int*)alloc(256 * 4);
  int* packed = (int*)alloc((size_t)N_EDGE * 4);
  int* col_s = (int*)alloc((size_t)N_EDGE * 4);
  float* val_s = (float*)alloc((size_t)N_EDGE * 4);
  float* mask_s = (float*)alloc((size_t)N_EDGE * 4);
  ushort_t* ent0bf = (ushort_t*)alloc((size_t)N_ENT * 64 * 2);
  ushort_t* ent1bf = (ushort_t*)alloc((size_t)N_ENT * 64 * 2);
  float* usr1 = (float*)alloc((size_t)N_USR * 64 * 4);
  float* V = (float*)alloc(9 * 64 * 4);
  float* wsq = (float*)alloc(16 * 4);
  float* dw = (float*)alloc(4 * 64 * 4);
  if (o > ws_size) return;

  float* out_ent = (float*)d_out;
  float* out_usr = out_ent + (size_t)N_ENT * 64;
  float* out_cor = out_ent + (size_t)N_ENT * 64 + (size_t)N_USR * 64;

  hipMemsetAsync(head_cur, 0, (size_t)N_ENT * 4, stream);
  hipMemsetAsync(ui_cur, 0, (size_t)N_USR * 4, stream);

  int eb = (N_EDGE + 255) / 256;
  k_count<<<eb, 256, 0, stream>>>(head, ui_rows, head_cur, ui_cur);

  int nbh = (N_ENT + 1023) / 1024, nbu = (N_USR + 1023) / 1024;
  k_scan_reduce<<<nbh, 256, 0, stream>>>(head_cur, N_ENT, bsum_h);
  k_scan_reduce<<<nbu, 256, 0, stream>>>(ui_cur, N_USR, bsum_u);
  k_scan_tops<<<1, 64, 0, stream>>>(bsum_h, nbh, bsum_u, nbu, head_ptr, N_ENT, ui_ptr, N_USR, N_EDGE);
  k_scan_final<<<nbh, 256, 0, stream>>>(head_cur, N_ENT, bsum_h, head_ptr, head_cur);
  k_scan_final<<<nbu, 256, 0, stream>>>(ui_cur, N_USR, bsum_u, ui_ptr, ui_cur);

  k_build<<<eb, 256, 0, stream>>>(head, tail, edge_type, ui_rows, ui_cols, ui_vals,
                                  head_cur, ui_cur, packed, col_s, val_s);

  k_tobf<<<(N_ENT * 64 / 4 + 255) / 256, 256, 0, stream>>>(entity_emb, ent0bf, N_ENT * 64 / 4);
  k_prep<<<1, 256, 0, stream>>>(weight, kgW, disen, V, wsq, dw, out_cor);

  // D1: mask + fused KG hop-1 + UI hop-1
  k_mask_kg_ui<<<KG_BLOCKS + UI_BLOCKS, 256, 0, stream>>>(
      entity_emb, ent0bf, head_ptr, packed, V, wsq, mask_s, weight,
      out_ent, ent1bf, user_emb, out_usr, usr1, ui_ptr, col_s, val_s, latent, dw);

  // D2: KG hop-2 + UI hop-2
  k_hop2<<<KG_BLOCKS + UI_BLOCKS, 256, 0, stream>>>(
      ent1bf, out_ent, head_ptr, packed, mask_s, weight,
      usr1, out_usr, ui_ptr, col_s, val_s, latent, dw);
}

// Round 6
// 694.172 us; speedup vs baseline: 1.3228x; 1.0433x over previous
//
#include <hip/hip_runtime.h>
#include <math.h>

#define N_ENT 100000
#define N_USR 50000
#define N_EDGE 1000000
#define TEMPC 0.2f
#define KG_BLOCKS (N_ENT / 4)   // 25000, exact
#define UI_BLOCKS (N_USR / 4)   // 12500, exact

typedef unsigned short ushort_t;

__device__ __forceinline__ float waveReduceSum(float x) {
#pragma unroll
  for (int d = 32; d > 0; d >>= 1) x += __shfl_xor(x, d);
  return x;
}
__device__ __forceinline__ float waveReduceMax(float x) {
#pragma unroll
  for (int d = 32; d > 0; d >>= 1) x = fmaxf(x, __shfl_xor(x, d));
  return x;
}
__device__ __forceinline__ int waveReduceSumI(int x) {
#pragma unroll
  for (int d = 32; d > 0; d >>= 1) x += __shfl_xor(x, d);
  return x;
}
__device__ __forceinline__ float bf2f(unsigned int u16) {
  union { unsigned int i; float f; } v;
  v.i = u16 << 16;
  return v.f;
}
__device__ __forceinline__ ushort_t f2bf(float f) {
  union { unsigned int i; float f; } v;
  v.f = f;
  unsigned int u = v.i;
  u = (u + 0x7FFFu + ((u >> 16) & 1u)) >> 16;
  return (ushort_t)u;
}

// ---------------- CSR build ----------------
__global__ void k_count(const int* __restrict__ head, const int* __restrict__ uir,
                        const int* __restrict__ etype,
                        int* __restrict__ cnt_h, int* __restrict__ cnt_u,
                        int* __restrict__ cnt9) {
  int i = blockIdx.x * blockDim.x + threadIdx.x;
  if (i < N_EDGE) {
    int h = head[i];
    atomicAdd(&cnt_h[h], 1);
    atomicAdd(&cnt9[h * 9 + (etype[i] - 1)], 1);
    atomicAdd(&cnt_u[uir[i]], 1);
  }
}

__global__ void k_scan_reduce(const int* __restrict__ cnt, int n, int* __restrict__ bsum) {
  int b = blockIdx.x, tid = threadIdx.x;
  int i0 = b * 1024 + tid * 4;
  int s = 0;
#pragma unroll
  for (int k = 0; k < 4; ++k)
    if (i0 + k < n) s += cnt[i0 + k];
  s = waveReduceSumI(s);
  __shared__ int l[4];
  int lane = tid & 63, wid = tid >> 6;
  if (lane == 0) l[wid] = s;
  __syncthreads();
  if (tid == 0) bsum[b] = l[0] + l[1] + l[2] + l[3];
}

__global__ void k_scan_tops(int* bsA, int nA, int* bsB, int nB,
                            int* ptrA, int NA, int* ptrB, int NB, int total) {
  if (threadIdx.x == 0) {
    int a = 0;
    for (int i = 0; i < nA; ++i) { int t = bsA[i]; bsA[i] = a; a += t; }
    ptrA[NA] = total;
  }
  if (threadIdx.x == 1) {
    int a = 0;
    for (int i = 0; i < nB; ++i) { int t = bsB[i]; bsB[i] = a; a += t; }
    ptrB[NB] = total;
  }
}

__global__ void k_scan_final(int* __restrict__ cnt, int n, const int* __restrict__ bsum,
                             int* __restrict__ ptr, int* __restrict__ cur) {
  int b = blockIdx.x, tid = threadIdx.x;
  int i0 = b * 1024 + tid * 4;
  int c[4];
  int s = 0;
  int loc[4];
#pragma unroll
  for (int k = 0; k < 4; ++k) {
    c[k] = (i0 + k < n) ? cnt[i0 + k] : 0;
    loc[k] = s;
    s += c[k];
  }
  int lane = tid & 63, wid = tid >> 6;
  int x = s;
#pragma unroll
  for (int d = 1; d < 64; d <<= 1) {
    int y = __shfl_up(x, d);
    if (lane >= d) x += y;
  }
  __shared__ int l[4];
  if (lane == 63) l[wid] = x;
  __syncthreads();
  if (tid == 0) {
    int a = 0;
    for (int w = 0; w < 4; ++w) { int t = l[w]; l[w] = a; a += t; }
  }
  __syncthreads();
  int excl = x - s + l[wid] + bsum[b];
#pragma unroll
  for (int k = 0; k < 4; ++k) {
    if (i0 + k < n) {
      int v = excl + loc[k];
      ptr[i0 + k] = v;
      cur[i0 + k] = v;
    }
  }
}

__global__ void k_build(const int* __restrict__ head, const int* __restrict__ tail,
                        const int* __restrict__ etype,
                        const int* __restrict__ uir, const int* __restrict__ uic,
                        const float* __restrict__ uival,
                        int* __restrict__ cur_h, int* __restrict__ cur_u,
                        int* __restrict__ packed, int* __restrict__ col_s,
                        float* __restrict__ val_s) {
  int i = blockIdx.x * blockDim.x + threadIdx.x;
  if (i < N_EDGE) {
    int h = head[i];
    int p = atomicAdd(&cur_h[h], 1);
    packed[p] = (tail[i] & 0xFFFFF) | ((etype[i] - 1) << 20);
    int u = uir[i];
    int q = atomicAdd(&cur_u[u], 1);
    col_s[q] = uic[i];
    val_s[q] = uival[i];
  }
}

// ---------------- fp32 -> bf16 table conversion ----------------
__global__ void k_tobf(const float* __restrict__ src, ushort_t* __restrict__ dst, int n4) {
  int i = blockIdx.x * blockDim.x + threadIdx.x;
  if (i < n4) {
    float4 v = ((const float4*)src)[i];
    ushort4 o;
    o.x = f2bf(v.x); o.y = f2bf(v.y); o.z = f2bf(v.z); o.w = f2bf(v.w);
    ((ushort4*)dst)[i] = o;
  }
}

// ------- tiny precompute: V = (W W^T) w_r  (via T = W^T w_r), wsq, disen_w, cor -------
__global__ void k_prep(const float* __restrict__ weight, const float* __restrict__ kgW,
                       const float* __restrict__ disen,
                       float* __restrict__ V, float* __restrict__ wsq,
                       float* __restrict__ dw, float* __restrict__ cor_out) {
  __shared__ float T[9 * 64];
  __shared__ float sm[4 * 9];
  int tid = threadIdx.x;
  // T[r][d] = sum_k kgW[k][d] * weight[r][k]
  for (int e = tid; e < 9 * 64; e += 256) {
    int r = e >> 6, d = e & 63;
    float s = 0.f;
    for (int k = 0; k < 64; ++k) s += kgW[k * 64 + d] * weight[r * 64 + k];
    T[e] = s;
  }
  if (tid < 4) {
    float m = -INFINITY;
    for (int r = 0; r < 9; ++r) m = fmaxf(m, disen[tid * 9 + r]);
    float den = 0.f;
    float ex[9];
    for (int r = 0; r < 9; ++r) { ex[r] = expf(disen[tid * 9 + r] - m); den += ex[r]; }
    for (int r = 0; r < 9; ++r) sm[tid * 9 + r] = ex[r] / den;
  }
  __syncthreads();
  // V[r][i] = sum_d kgW[i][d] * T[r][d]
  for (int e = tid; e < 9 * 64; e += 256) {
    int r = e >> 6, i = e & 63;
    float s = 0.f;
    for (int d = 0; d < 64; ++d) s += kgW[i * 64 + d] * T[r * 64 + d];
    V[e] = s;
  }
  if (tid < 9) {
    float s = 0.f;
    for (int c = 0; c < 64; ++c) { float w = weight[tid * 64 + c]; s += w * w; }
    wsq[tid] = s;
  }
  for (int e = tid; e < 4 * 64; e += 256) {
    int f = e >> 6, c = e & 63;
    float s = 0.f;
    for (int r = 0; r < 9; ++r) s += sm[f * 9 + r] * weight[r * 64 + c];
    dw[e] = s;
  }
  if (tid == 0) {
    float rowsum[4];
    for (int f = 0; f < 4; ++f) {
      float s = 0.f;
      for (int j = 0; j < 9; ++j) s += disen[f * 9 + j];
      rowsum[f] = s;
    }
    float cor = 0.f;
    for (int i = 0; i < 9; ++i) {
      float n2 = 0.f, ttl = 0.f;
      for (int f = 0; f < 4; ++f) {
        float v = disen[f * 9 + i];
        n2 += v * v;
        ttl += v * rowsum[f];
      }
      float nrm = sqrtf(n2);
      float pos = 0.f;
      for (int f = 0; f < 4; ++f) {
        float v = disen[f * 9 + i] / nrm;
        pos += v * v;
      }
      cor += (ttl - pos) / TEMPC;
    }
    *cor_out = cor;
  }
}

// ------- dense per-entity relation attention: rel2t[ent][r] = rel_score_r^2 * wsq[r] -------
__global__ void k_rel2(const ushort_t* __restrict__ ent0bf, const float* __restrict__ V,
                       const float* __restrict__ wsq, const int* __restrict__ cnt9,
                       float* __restrict__ rel2t) {
  __shared__ __align__(16) float Vl[576];
  __shared__ float wsql[9];
  for (int i = threadIdx.x; i < 576; i += 256) Vl[i] = V[i];
  if (threadIdx.x < 9) wsql[threadIdx.x] = wsq[threadIdx.x];
  __syncthreads();
  int ent = blockIdx.x * 256 + threadIdx.x;
  if (ent >= N_ENT) return;
  float a[9] = {0, 0, 0, 0, 0, 0, 0, 0, 0};
  const uint4* row = (const uint4*)(ent0bf + (ent << 6));
#pragma unroll
  for (int q = 0; q < 8; ++q) {
    uint4 b = row[q];
    float ch0 = bf2f(b.x & 0xFFFFu), ch1 = bf2f(b.x >> 16);
    float ch2 = bf2f(b.y & 0xFFFFu), ch3 = bf2f(b.y >> 16);
    float ch4 = bf2f(b.z & 0xFFFFu), ch5 = bf2f(b.z >> 16);
    float ch6 = bf2f(b.w & 0xFFFFu), ch7 = bf2f(b.w >> 16);
#pragma unroll
    for (int r = 0; r < 9; ++r) {
      const float4* vp = (const float4*)(Vl + r * 64 + q * 8);
      float4 v0 = vp[0], v1 = vp[1];
      float t = a[r];
      t = fmaf(ch0, v0.x, t); t = fmaf(ch1, v0.y, t);
      t = fmaf(ch2, v0.z, t); t = fmaf(ch3, v0.w, t);
      t = fmaf(ch4, v1.x, t); t = fmaf(ch5, v1.y, t);
      t = fmaf(ch6, v1.z, t); t = fmaf(ch7, v1.w, t);
      a[r] = t;
    }
  }
  const float inv2s = 0.08838834764831845f;  // 1/(2*sqrt(32))
  int cnt[9];
#pragma unroll
  for (int r = 0; r < 9; ++r) cnt[r] = cnt9[ent * 9 + r];
  float m1 = -INFINITY;
#pragma unroll
  for (int r = 0; r < 9; ++r)
    if (cnt[r] > 0) m1 = fmaxf(m1, a[r] * inv2s);
  if (m1 == -INFINITY) {
#pragma unroll
    for (int r = 0; r < 9; ++r) rel2t[ent * 9 + r] = 0.f;
    return;
  }
  float den1 = 1e-16f;
#pragma unroll
  for (int r = 0; r < 9; ++r)
    if (cnt[r] > 0) den1 += (float)cnt[r] * expf(a[r] * inv2s - m1);
#pragma unroll
  for (int r = 0; r < 9; ++r) {
    float rs = expf(a[r] * inv2s - m1) / den1;
    rel2t[ent * 9 + r] = rs * rs * wsql[r];
  }
}

// ------- dense per-user factor scores: sc4[u] = usr[u] @ latent^T -------
__global__ void k_sc(const float* __restrict__ usr, const float* __restrict__ latent,
                     float4* __restrict__ sc4) {
  __shared__ __align__(16) float lat[256];
  if (threadIdx.x < 256) lat[threadIdx.x] = latent[threadIdx.x];
  __syncthreads();
  int u = blockIdx.x * 256 + threadIdx.x;
  if (u >= N_USR) return;
  float a0 = 0.f, a1 = 0.f, a2 = 0.f, a3 = 0.f;
  const float4* row = (const float4*)(usr + (size_t)u * 64);
#pragma unroll
  for (int q = 0; q < 16; ++q) {
    float4 v = row[q];
    float4 l0 = *(const float4*)(lat + 0 * 64 + q * 4);
    float4 l1 = *(const float4*)(lat + 1 * 64 + q * 4);
    float4 l2 = *(const float4*)(lat + 2 * 64 + q * 4);
    float4 l3 = *(const float4*)(lat + 3 * 64 + q * 4);
    a0 = fmaf(v.x, l0.x, a0); a0 = fmaf(v.y, l0.y, a0); a0 = fmaf(v.z, l0.z, a0); a0 = fmaf(v.w, l0.w, a0);
    a1 = fmaf(v.x, l1.x, a1); a1 = fmaf(v.y, l1.y, a1); a1 = fmaf(v.z, l1.z, a1); a1 = fmaf(v.w, l1.w, a1);
    a2 = fmaf(v.x, l2.x, a2); a2 = fmaf(v.y, l2.y, a2); a2 = fmaf(v.z, l2.z, a2); a2 = fmaf(v.w, l2.w, a2);
    a3 = fmaf(v.x, l3.x, a3); a3 = fmaf(v.y, l3.y, a3); a3 = fmaf(v.z, l3.z, a3); a3 = fmaf(v.w, l3.w, a3);
  }
  sc4[u] = make_float4(a0, a1, a2, a3);
}

// ---------------- UI aggregation body (precomputed sc4, 4 acc chains) ----------------
__device__ __forceinline__ void ui_body(int usr, int lane,
                                        const ushort_t* __restrict__ srcbf,
                                        const float4* __restrict__ sc4,
                                        const float* __restrict__ addb,
                                        float* __restrict__ outp, float* __restrict__ nxt,
                                        const int* __restrict__ uptr,
                                        const int* __restrict__ col_s,
                                        const float* __restrict__ val_s,
                                        const float* __restrict__ dwl) {
  float4 s4 = sc4[usr];
  float m = fmaxf(fmaxf(s4.x, s4.y), fmaxf(s4.z, s4.w));
  float e0 = expf(s4.x - m), e1 = expf(s4.y - m), e2 = expf(s4.z - m), e3 = expf(s4.w - m);
  float den = e0 + e1 + e2 + e3;
  float mix = (e0 * dwl[lane] + e1 * dwl[64 + lane] + e2 * dwl[128 + lane] + e3 * dwl[192 + lane]) / den;
  int s = uptr[usr], e = uptr[usr + 1];
  float a0 = 0.f, a1 = 0.f, a2 = 0.f, a3 = 0.f;
  for (int base = s; base < e; base += 64) {
    int c = min(64, e - base);
    int cl = (lane < c) ? col_s[base + lane] : 0;
    float vl = (lane < c) ? val_s[base + lane] : 0.f;
    int j = 0;
    for (; j + 8 <= c; j += 8) {
      int c0 = __shfl(cl, j), c1 = __shfl(cl, j + 1), c2 = __shfl(cl, j + 2), c3 = __shfl(cl, j + 3);
      int c4 = __shfl(cl, j + 4), c5 = __shfl(cl, j + 5), c6 = __shfl(cl, j + 6), c7 = __shfl(cl, j + 7);
      float v0 = __shfl(vl, j), v1 = __shfl(vl, j + 1), v2 = __shfl(vl, j + 2), v3 = __shfl(vl, j + 3);
      float v4 = __shfl(vl, j + 4), v5 = __shfl(vl, j + 5), v6 = __shfl(vl, j + 6), v7 = __shfl(vl, j + 7);
      float r0 = bf2f(srcbf[(c0 << 6) + lane]);
      float r1 = bf2f(srcbf[(c1 << 6) + lane]);
      float r2 = bf2f(srcbf[(c2 << 6) + lane]);
      float r3 = bf2f(srcbf[(c3 << 6) + lane]);
      float r4 = bf2f(srcbf[(c4 << 6) + lane]);
      float r5 = bf2f(srcbf[(c5 << 6) + lane]);
      float r6 = bf2f(srcbf[(c6 << 6) + lane]);
      float r7 = bf2f(srcbf[(c7 << 6) + lane]);
      a0 = fmaf(r0, v0, a0); a1 = fmaf(r1, v1, a1);
      a2 = fmaf(r2, v2, a2); a3 = fmaf(r3, v3, a3);
      a0 = fmaf(r4, v4, a0); a1 = fmaf(r5, v5, a1);
      a2 = fmaf(r6, v6, a2); a3 = fmaf(r7, v7, a3);
    }
    for (; j < c; ++j) {
      int cj = __shfl(cl, j);
      float vj = __shfl(vl, j);
      a0 = fmaf(bf2f(srcbf[(cj << 6) + lane]), vj, a0);
    }
  }
  float acc = (a0 + a1) + (a2 + a3);
  float ua = acc * mix + acc;
  float nrm = sqrtf(waveReduceSum(ua * ua));
  float val = ua / fmaxf(nrm, 1e-12f);
  size_t o = (size_t)usr * 64 + lane;
  if (nxt) nxt[o] = val;
  outp[o] = addb[o] + val;
}

// KG aggregation inner (4 acc chains) over lane-resident pk/mk
__device__ __forceinline__ float kg_agg64(int deg, int lane, int pk, float mk,
                                          const ushort_t* __restrict__ srcbf,
                                          const float* __restrict__ wl) {
  float a0 = 0.f, a1 = 0.f, a2 = 0.f, a3 = 0.f;
  int j = 0;
  for (; j + 4 <= deg; j += 4) {
    int p0 = __shfl(pk, j), p1 = __shfl(pk, j + 1), p2 = __shfl(pk, j + 2), p3 = __shfl(pk, j + 3);
    float k0 = __shfl(mk, j), k1 = __shfl(mk, j + 1), k2 = __shfl(mk, j + 2), k3 = __shfl(mk, j + 3);
    float r0 = bf2f(srcbf[((p0 & 0xFFFFF) << 6) + lane]);
    float r1 = bf2f(srcbf[((p1 & 0xFFFFF) << 6) + lane]);
    float r2 = bf2f(srcbf[((p2 & 0xFFFFF) << 6) + lane]);
    float r3 = bf2f(srcbf[((p3 & 0xFFFFF) << 6) + lane]);
    a0 = fmaf(r0 * wl[(((p0 >> 20) & 15) << 6) + lane], k0, a0);
    a1 = fmaf(r1 * wl[(((p1 >> 20) & 15) << 6) + lane], k1, a1);
    a2 = fmaf(r2 * wl[(((p2 >> 20) & 15) << 6) + lane], k2, a2);
    a3 = fmaf(r3 * wl[(((p3 >> 20) & 15) << 6) + lane], k3, a3);
  }
  for (; j < deg; ++j) {
    int pj = __shfl(pk, j);
    float kj = __shfl(mk, j);
    a0 = fmaf(bf2f(srcbf[((pj & 0xFFFFF) << 6) + lane]) * wl[(((pj >> 20) & 15) << 6) + lane], kj, a0);
  }
  return (a0 + a1) + (a2 + a3);
}

// ---------------- D1: mask + fused KG hop-1  |  UI hop-1 ----------------
__global__ void k_mask_kg_ui(const float* __restrict__ ent0,
                             const ushort_t* __restrict__ ent0bf,
                             const int* __restrict__ hptr, const int* __restrict__ packed,
                             const float* __restrict__ rel2t,
                             float* __restrict__ mask_s, const float* __restrict__ weight,
                             float* __restrict__ out_ent, ushort_t* __restrict__ ent1bf,
                             const float4* __restrict__ sc4,
                             float* __restrict__ out_usr,
                             float* __restrict__ usr1, const int* __restrict__ uptr,
                             const int* __restrict__ col_s, const float* __restrict__ val_s,
                             const float* __restrict__ user_emb, const float* __restrict__ dw) {
  int lane = threadIdx.x & 63, wid = threadIdx.x >> 6;
  if (blockIdx.x < KG_BLOCKS) {
    __shared__ __align__(16) float sh_eh[4][64];
    __shared__ float wl[576];
    for (int i = threadIdx.x; i < 576; i += 256) wl[i] = weight[i];
    int ent = blockIdx.x * 4 + wid;  // always < N_ENT
    int s = hptr[ent], e = hptr[ent + 1];
    float eh = ent0[(size_t)ent * 64 + lane];
    sh_eh[wid][lane] = eh;
    __syncthreads();
    size_t o = (size_t)ent * 64 + lane;
    int deg = e - s;
    if (deg == 0) {
      ent1bf[o] = f2bf(0.f);
      out_ent[o] = eh;
      return;
    }
    if (deg <= 64) {
      // ---- hot path ----
      int pk = (lane < deg) ? packed[s + lane] : 0;
      int tb = (pk >> 20) & 15;
      float r2sel = rel2t[ent * 9 + ((lane < deg) ? tb : 0)];
      // ---- 8-lane-per-edge dot: lane = 8*slot + part ----
      int part = lane & 7;
      const float4* ehq = (const float4*)(sh_eh[wid] + (part << 3));
      float4 ef0 = ehq[0], ef1 = ehq[1];
      float myDot = 0.f;
      int nch = (deg + 7) >> 3;
      for (int c2 = 0; c2 < nch; ++c2) {
        int pkj = __shfl(pk, (c2 << 3) + (lane >> 3));
        const uint4* row = (const uint4*)(ent0bf + ((pkj & 0xFFFFF) << 6)) + part;
        uint4 b = *row;
        float s0 = bf2f(b.x & 0xFFFFu) * ef0.x;
        float s1 = bf2f(b.y & 0xFFFFu) * ef0.z;
        float s2 = bf2f(b.z & 0xFFFFu) * ef1.x;
        float s3 = bf2f(b.w & 0xFFFFu) * ef1.z;
        s0 = fmaf(bf2f(b.x >> 16), ef0.y, s0);
        s1 = fmaf(bf2f(b.y >> 16), ef0.w, s1);
        s2 = fmaf(bf2f(b.z >> 16), ef1.y, s2);
        s3 = fmaf(bf2f(b.w >> 16), ef1.w, s3);
        float sv = (s0 + s1) + (s2 + s3);
        sv += __shfl_xor(sv, 1);
        sv += __shfl_xor(sv, 2);
        sv += __shfl_xor(sv, 4);
        float got = __shfl(sv, part << 3);
        myDot = ((lane >> 3) == c2) ? got : myDot;
      }
      float trip = (lane < deg) ? myDot + r2sel : -INFINITY;
      float m2 = waveReduceMax(trip);
      float ex = (lane < deg) ? expf(trip - m2) : 0.f;
      float den2 = waveReduceSum(ex) + 1e-16f;
      float mk = ex / den2;
      if (lane < deg) mask_s[s + lane] = mk;
      // ---- fused KG hop-1 aggregation (rows L1/L2-hot) ----
      float acc = kg_agg64(deg, lane, pk, mk, ent0bf, wl);
      float agg = acc / (float)deg;
      float nrm = sqrtf(waveReduceSum(agg * agg));
      float val = agg / fmaxf(nrm, 1e-12f);
      ent1bf[o] = f2bf(val);
      out_ent[o] = eh + val;
    } else {
      // ---- generic multi-chunk path (statistically unreachable at mean deg 10) ----
      float m2l = -INFINITY;
      for (int base = s; base < e; base += 64) {
        int c = min(64, e - base);
        int pk = (lane < c) ? packed[base + lane] : 0;
        int tb = (pk >> 20) & 15;
        float r2 = rel2t[ent * 9 + ((lane < c) ? tb : 0)];
        int tl = pk & 0xFFFFF;
        const uint4* row = (const uint4*)(ent0bf + (tl << 6));
        const float* ehp = sh_eh[wid];
        float d = 0.f;
#pragma unroll
        for (int q = 0; q < 8; ++q) {
          uint4 a = row[q];
          d += bf2f(a.x & 0xFFFF) * ehp[q * 8 + 0] + bf2f(a.x >> 16) * ehp[q * 8 + 1];
          d += bf2f(a.y & 0xFFFF) * ehp[q * 8 + 2] + bf2f(a.y >> 16) * ehp[q * 8 + 3];
          d += bf2f(a.z & 0xFFFF) * ehp[q * 8 + 4] + bf2f(a.z >> 16) * ehp[q * 8 + 5];
          d += bf2f(a.w & 0xFFFF) * ehp[q * 8 + 6] + bf2f(a.w >> 16) * ehp[q * 8 + 7];
        }
        float trip = d + r2;
        if (lane < c) {
          mask_s[base + lane] = trip;
          m2l = fmaxf(m2l, trip);
        }
      }
      float m2 = waveReduceMax(m2l);
      float denl = 0.f;
      for (int base = s; base < e; base += 64) {
        int c = min(64, e - base);
        denl += (lane < c) ? expf(mask_s[base + lane] - m2) : 0.f;
      }
      float den2 = waveReduceSum(denl) + 1e-16f;
      float acc = 0.f;
      for (int base = s; base < e; base += 64) {
        int c = min(64, e - base);
        int pk = (lane < c) ? packed[base + lane] : 0;
        float mk = 0.f;
        if (lane < c) {
          mk = expf(mask_s[base + lane] - m2) / den2;
          mask_s[base + lane] = mk;
        }
        acc += kg_agg64(c, lane, pk, mk, ent0bf, wl);
      }
      float agg = acc / (float)deg;
      float nrm = sqrtf(waveReduceSum(agg * agg));
      float val = agg / fmaxf(nrm, 1e-12f);
      ent1bf[o] = f2bf(val);
      out_ent[o] = eh + val;
    }
  } else {
    __shared__ float dwl[256];
    if (threadIdx.x < 256) dwl[threadIdx.x] = dw[threadIdx.x];
    __syncthreads();
    int usr = (blockIdx.x - KG_BLOCKS) * 4 + wid;  // always < N_USR
    ui_body(usr, lane, ent0bf, sc4, user_emb, out_usr, usr1,
            uptr, col_s, val_s, dwl);
  }
}

// ---------------- D2: KG hop-2 + UI hop-2 ----------------
__global__ void k_hop2(const ushort_t* __restrict__ srcbf,
                       float* __restrict__ out_ent,
                       const int* __restrict__ hptr, const int* __restrict__ packed,
                       const float* __restrict__ mask_s, const float* __restrict__ weight,
                       const float* __restrict__ usr1, float* __restrict__ out_usr,
                       const int* __restrict__ uptr, const int* __restrict__ col_s,
                       const float* __restrict__ val_s, const float4* __restrict__ sc4,
                       const float* __restrict__ dw) {
  int lane = threadIdx.x & 63, wid = threadIdx.x >> 6;
  if (blockIdx.x < KG_BLOCKS) {
    __shared__ float wl[576];
    for (int i = threadIdx.x; i < 576; i += 256) wl[i] = weight[i];
    __syncthreads();
    int ent = blockIdx.x * 4 + wid;
    int s = hptr[ent], e = hptr[ent + 1];
    float acc = 0.f;
    for (int base = s; base < e; base += 64) {
      int c = min(64, e - base);
      int pk = (lane < c) ? packed[base + lane] : 0;
      float mk = (lane < c) ? mask_s[base + lane] : 0.f;
      acc += kg_agg64(c, lane, pk, mk, srcbf, wl);
    }
    float n = (float)(e - s);
    float agg = acc / fmaxf(n, 1.0f);
    float nrm = sqrtf(waveReduceSum(agg * agg));
    float val = agg / fmaxf(nrm, 1e-12f);
    size_t o = (size_t)ent * 64 + lane;
    out_ent[o] = out_ent[o] + val;
  } else {
    __shared__ float dwl[256];
    if (threadIdx.x < 256) dwl[threadIdx.x] = dw[threadIdx.x];
    __syncthreads();
    int usr = (blockIdx.x - KG_BLOCKS) * 4 + wid;
    ui_body(usr, lane, srcbf, sc4, out_usr, out_usr, nullptr,
            uptr, col_s, val_s, dwl);
  }
}

extern "C" void kernel_launch(void* const* d_in, const int* in_sizes, int n_in,
                              void* d_out, int out_size, void* d_ws, size_t ws_size,
                              hipStream_t stream) {
  const float* user_emb = (const float*)d_in[0];
  const float* entity_emb = (const float*)d_in[1];
  const float* latent = (const float*)d_in[2];
  const float* weight = (const float*)d_in[3];
  const float* disen = (const float*)d_in[4];
  const float* kgW = (const float*)d_in[5];
  const float* ui_vals = (const float*)d_in[6];
  const int* edge_index = (const int*)d_in[7];
  const int* edge_type = (const int*)d_in[8];
  const int* ui_rows = (const int*)d_in[9];
  const int* ui_cols = (const int*)d_in[10];
  const int* head = edge_index;
  const int* tail = edge_index + N_EDGE;

  char* ws = (char*)d_ws;
  size_t o = 0;
  auto alloc = [&](size_t bytes) -> char* {
    char* p = ws + o;
    o += (bytes + 255) & ~(size_t)255;
    return p;
  };
  int* head_ptr = (int*)alloc((N_ENT + 1) * 4);
  int* head_cur = (int*)alloc((size_t)N_ENT * 4);
  int* ui_ptr = (int*)alloc((N_USR + 1) * 4);
  int* ui_cur = (int*)alloc((size_t)N_USR * 4);
  int* bsum_h = (int*)alloc(256 * 4);
  int* bsum_u = (int*)alloc(256 * 4);
  int* packed = (int*)alloc((size_t)N_EDGE * 4);
  int* col_s = (int*)alloc((size_t)N_EDGE * 4);
  float* val_s = (float*)alloc((size_t)N_EDGE * 4);
  float* mask_s = (float*)alloc((size_t)N_EDGE * 4);
  ushort_t* ent0bf = (ushort_t*)alloc((size_t)N_ENT * 64 * 2);
  ushort_t* ent1bf = (ushort_t*)alloc((size_t)N_ENT * 64 * 2);
  float* usr1 = (float*)alloc((size_t)N_USR * 64 * 4);
  int* cnt9 = (int*)alloc((size_t)N_ENT * 9 * 4);
  float* rel2t = (float*)alloc((size_t)N_ENT * 9 * 4);
  float4* sc4a = (float4*)alloc((size_t)N_USR * 16);
  float4* sc4b = (float4*)alloc((size_t)N_USR * 16);
  float* V = (float*)alloc(9 * 64 * 4);
  float* wsq = (float*)alloc(16 * 4);
  float* dw = (float*)alloc(4 * 64 * 4);
  if (o > ws_size) return;

  float* out_ent = (float*)d_out;
  float* out_usr = out_ent + (size_t)N_ENT * 64;
  float* out_cor = out_ent + (size_t)N_ENT * 64 + (size_t)N_USR * 64;

  hipMemsetAsync(head_cur, 0, (size_t)N_ENT * 4, stream);
  hipMemsetAsync(ui_cur, 0, (size_t)N_USR * 4, stream);
  hipMemsetAsync(cnt9, 0, (size_t)N_ENT * 9 * 4, stream);

  int eb = (N_EDGE + 255) / 256;
  k_count<<<eb, 256, 0, stream>>>(head, ui_rows, edge_type, head_cur, ui_cur, cnt9);

  int nbh = (N_ENT + 1023) / 1024, nbu = (N_USR + 1023) / 1024;
  k_scan_reduce<<<nbh, 256, 0, stream>>>(head_cur, N_ENT, bsum_h);
  k_scan_reduce<<<nbu, 256, 0, stream>>>(ui_cur, N_USR, bsum_u);
  k_scan_tops<<<1, 64, 0, stream>>>(bsum_h, nbh, bsum_u, nbu, head_ptr, N_ENT, ui_ptr, N_USR, N_EDGE);
  k_scan_final<<<nbh, 256, 0, stream>>>(head_cur, N_ENT, bsum_h, head_ptr, head_cur);
  k_scan_final<<<nbu, 256, 0, stream>>>(ui_cur, N_USR, bsum_u, ui_ptr, ui_cur);

  k_build<<<eb, 256, 0, stream>>>(head, tail, edge_type, ui_rows, ui_cols, ui_vals,
                                  head_cur, ui_cur, packed, col_s, val_s);

  k_tobf<<<(N_ENT * 64 / 4 + 255) / 256, 256, 0, stream>>>(entity_emb, ent0bf, N_ENT * 64 / 4);
  k_prep<<<1, 256, 0, stream>>>(weight, kgW, disen, V, wsq, dw, out_cor);
  k_rel2<<<(N_ENT + 255) / 256, 256, 0, stream>>>(ent0bf, V, wsq, cnt9, rel2t);
  k_sc<<<(N_USR + 255) / 256, 256, 0, stream>>>(user_emb, latent, sc4a);

  // D1: mask + fused KG hop-1 + UI hop-1
  k_mask_kg_ui<<<KG_BLOCKS + UI_BLOCKS, 256, 0, stream>>>(
      entity_emb, ent0bf, head_ptr, packed, rel2t, mask_s, weight,
      out_ent, ent1bf, sc4a, out_usr, usr1, ui_ptr, col_s, val_s, user_emb, dw);

  // sc for hop-2 from usr1
  k_sc<<<(N_USR + 255) / 256, 256, 0, stream>>>(usr1, latent, sc4b);

  // D2: KG hop-2 + UI hop-2
  k_hop2<<<KG_BLOCKS + UI_BLOCKS, 256, 0, stream>>>(
      ent1bf, out_ent, head_ptr, packed, mask_s, weight,
      usr1, out_usr, ui_ptr, col_s, val_s, sc4b, dw);
}

// Round 7
// 635.614 us; speedup vs baseline: 1.4447x; 1.0921x over previous
//
#include <hip/hip_runtime.h>
#include <math.h>

#define N_ENT 100000
#define N_USR 50000
#define N_EDGE 1000000
#define TEMPC 0.2f
#define KG_BLOCKS (N_ENT / 4)   // 25000, exact
#define UI_BLOCKS (N_USR / 4)   // 12500, exact

typedef unsigned short ushort_t;

__device__ __forceinline__ float waveReduceSum(float x) {
#pragma unroll
  for (int d = 32; d > 0; d >>= 1) x += __shfl_xor(x, d);
  return x;
}
__device__ __forceinline__ float waveReduceMax(float x) {
#pragma unroll
  for (int d = 32; d > 0; d >>= 1) x = fmaxf(x, __shfl_xor(x, d));
  return x;
}
__device__ __forceinline__ int waveReduceSumI(int x) {
#pragma unroll
  for (int d = 32; d > 0; d >>= 1) x += __shfl_xor(x, d);
  return x;
}
__device__ __forceinline__ float bf2f(unsigned int u16) {
  union { unsigned int i; float f; } v;
  v.i = u16 << 16;
  return v.f;
}
__device__ __forceinline__ ushort_t f2bf(float f) {
  union { unsigned int i; float f; } v;
  v.f = f;
  unsigned int u = v.i;
  u = (u + 0x7FFFu + ((u >> 16) & 1u)) >> 16;
  return (ushort_t)u;
}

// ---------------- CSR build ----------------
// 4 edges/thread: 8 independent atomics in flight (latency-bound path)
__global__ void k_count(const int* __restrict__ head, const int* __restrict__ uir,
                        const int* __restrict__ etype,
                        int* __restrict__ cnt_u, int* __restrict__ cnt9) {
  int i0 = (blockIdx.x * blockDim.x + threadIdx.x) * 4;
  if (i0 >= N_EDGE) return;
  int4 h4 = *(const int4*)(head + i0);
  int4 e4 = *(const int4*)(etype + i0);
  int4 u4 = *(const int4*)(uir + i0);
  atomicAdd(&cnt9[h4.x * 9 + (e4.x - 1)], 1);
  atomicAdd(&cnt9[h4.y * 9 + (e4.y - 1)], 1);
  atomicAdd(&cnt9[h4.z * 9 + (e4.z - 1)], 1);
  atomicAdd(&cnt9[h4.w * 9 + (e4.w - 1)], 1);
  atomicAdd(&cnt_u[u4.x], 1);
  atomicAdd(&cnt_u[u4.y], 1);
  atomicAdd(&cnt_u[u4.z], 1);
  atomicAdd(&cnt_u[u4.w], 1);
}

// dense degree = row-sum of cnt9 (every KG edge has a relation)
__global__ void k_sumrow9(const int* __restrict__ cnt9, int* __restrict__ cnt_h) {
  int ent = blockIdx.x * 256 + threadIdx.x;
  if (ent < N_ENT) {
    int s = 0;
#pragma unroll
    for (int r = 0; r < 9; ++r) s += cnt9[ent * 9 + r];
    cnt_h[ent] = s;
  }
}

__global__ void k_scan_reduce(const int* __restrict__ cnt, int n, int* __restrict__ bsum) {
  int b = blockIdx.x, tid = threadIdx.x;
  int i0 = b * 1024 + tid * 4;
  int s = 0;
#pragma unroll
  for (int k = 0; k < 4; ++k)
    if (i0 + k < n) s += cnt[i0 + k];
  s = waveReduceSumI(s);
  __shared__ int l[4];
  int lane = tid & 63, wid = tid >> 6;
  if (lane == 0) l[wid] = s;
  __syncthreads();
  if (tid == 0) bsum[b] = l[0] + l[1] + l[2] + l[3];
}

__global__ void k_scan_tops(int* bsA, int nA, int* bsB, int nB,
                            int* ptrA, int NA, int* ptrB, int NB, int total) {
  if (threadIdx.x == 0) {
    int a = 0;
    for (int i = 0; i < nA; ++i) { int t = bsA[i]; bsA[i] = a; a += t; }
    ptrA[NA] = total;
  }
  if (threadIdx.x == 1) {
    int a = 0;
    for (int i = 0; i < nB; ++i) { int t = bsB[i]; bsB[i] = a; a += t; }
    ptrB[NB] = total;
  }
}

__global__ void k_scan_final(int* __restrict__ cnt, int n, const int* __restrict__ bsum,
                             int* __restrict__ ptr, int* __restrict__ cur) {
  int b = blockIdx.x, tid = threadIdx.x;
  int i0 = b * 1024 + tid * 4;
  int c[4];
  int s = 0;
  int loc[4];
#pragma unroll
  for (int k = 0; k < 4; ++k) {
    c[k] = (i0 + k < n) ? cnt[i0 + k] : 0;
    loc[k] = s;
    s += c[k];
  }
  int lane = tid & 63, wid = tid >> 6;
  int x = s;
#pragma unroll
  for (int d = 1; d < 64; d <<= 1) {
    int y = __shfl_up(x, d);
    if (lane >= d) x += y;
  }
  __shared__ int l[4];
  if (lane == 63) l[wid] = x;
  __syncthreads();
  if (tid == 0) {
    int a = 0;
    for (int w = 0; w < 4; ++w) { int t = l[w]; l[w] = a; a += t; }
  }
  __syncthreads();
  int excl = x - s + l[wid] + bsum[b];
#pragma unroll
  for (int k = 0; k < 4; ++k) {
    if (i0 + k < n) {
      int v = excl + loc[k];
      ptr[i0 + k] = v;
      cur[i0 + k] = v;
    }
  }
}

// 4 edges/thread, cv = (col, val) 8B scatter
__global__ void k_build(const int* __restrict__ head, const int* __restrict__ tail,
                        const int* __restrict__ etype,
                        const int* __restrict__ uir, const int* __restrict__ uic,
                        const float* __restrict__ uival,
                        int* __restrict__ cur_h, int* __restrict__ cur_u,
                        int* __restrict__ packed, int2* __restrict__ cv) {
  int i0 = (blockIdx.x * blockDim.x + threadIdx.x) * 4;
  if (i0 >= N_EDGE) return;
  int4 h4 = *(const int4*)(head + i0);
  int4 t4 = *(const int4*)(tail + i0);
  int4 e4 = *(const int4*)(etype + i0);
  int4 u4 = *(const int4*)(uir + i0);
  int4 c4 = *(const int4*)(uic + i0);
  float4 v4 = *(const float4*)(uival + i0);
  int p0 = atomicAdd(&cur_h[h4.x], 1);
  int p1 = atomicAdd(&cur_h[h4.y], 1);
  int p2 = atomicAdd(&cur_h[h4.z], 1);
  int p3 = atomicAdd(&cur_h[h4.w], 1);
  int q0 = atomicAdd(&cur_u[u4.x], 1);
  int q1 = atomicAdd(&cur_u[u4.y], 1);
  int q2 = atomicAdd(&cur_u[u4.z], 1);
  int q3 = atomicAdd(&cur_u[u4.w], 1);
  packed[p0] = (t4.x & 0xFFFFF) | ((e4.x - 1) << 20);
  packed[p1] = (t4.y & 0xFFFFF) | ((e4.y - 1) << 20);
  packed[p2] = (t4.z & 0xFFFFF) | ((e4.z - 1) << 20);
  packed[p3] = (t4.w & 0xFFFFF) | ((e4.w - 1) << 20);
  cv[q0] = make_int2(c4.x, __float_as_int(v4.x));
  cv[q1] = make_int2(c4.y, __float_as_int(v4.y));
  cv[q2] = make_int2(c4.z, __float_as_int(v4.z));
  cv[q3] = make_int2(c4.w, __float_as_int(v4.w));
}

// ---------------- fp32 -> bf16 table conversion ----------------
__global__ void k_tobf(const float* __restrict__ src, ushort_t* __restrict__ dst, int n4) {
  int i = blockIdx.x * blockDim.x + threadIdx.x;
  if (i < n4) {
    float4 v = ((const float4*)src)[i];
    ushort4 o;
    o.x = f2bf(v.x); o.y = f2bf(v.y); o.z = f2bf(v.z); o.w = f2bf(v.w);
    ((ushort4*)dst)[i] = o;
  }
}

// ------- tiny precompute: V = (W W^T) w_r  (via T = W^T w_r), wsq, disen_w, cor -------
__global__ void k_prep(const float* __restrict__ weight, const float* __restrict__ kgW,
                       const float* __restrict__ disen,
                       float* __restrict__ V, float* __restrict__ wsq,
                       float* __restrict__ dw, float* __restrict__ cor_out) {
  __shared__ float T[9 * 64];
  __shared__ float sm[4 * 9];
  int tid = threadIdx.x;
  for (int e = tid; e < 9 * 64; e += 256) {
    int r = e >> 6, d = e & 63;
    float s = 0.f;
    for (int k = 0; k < 64; ++k) s += kgW[k * 64 + d] * weight[r * 64 + k];
    T[e] = s;
  }
  if (tid < 4) {
    float m = -INFINITY;
    for (int r = 0; r < 9; ++r) m = fmaxf(m, disen[tid * 9 + r]);
    float den = 0.f;
    float ex[9];
    for (int r = 0; r < 9; ++r) { ex[r] = expf(disen[tid * 9 + r] - m); den += ex[r]; }
    for (int r = 0; r < 9; ++r) sm[tid * 9 + r] = ex[r] / den;
  }
  __syncthreads();
  for (int e = tid; e < 9 * 64; e += 256) {
    int r = e >> 6, i = e & 63;
    float s = 0.f;
    for (int d = 0; d < 64; ++d) s += kgW[i * 64 + d] * T[r * 64 + d];
    V[e] = s;
  }
  if (tid < 9) {
    float s = 0.f;
    for (int c = 0; c < 64; ++c) { float w = weight[tid * 64 + c]; s += w * w; }
    wsq[tid] = s;
  }
  for (int e = tid; e < 4 * 64; e += 256) {
    int f = e >> 6, c = e & 63;
    float s = 0.f;
    for (int r = 0; r < 9; ++r) s += sm[f * 9 + r] * weight[r * 64 + c];
    dw[e] = s;
  }
  if (tid == 0) {
    float rowsum[4];
    for (int f = 0; f < 4; ++f) {
      float s = 0.f;
      for (int j = 0; j < 9; ++j) s += disen[f * 9 + j];
      rowsum[f] = s;
    }
    float cor = 0.f;
    for (int i = 0; i < 9; ++i) {
      float n2 = 0.f, ttl = 0.f;
      for (int f = 0; f < 4; ++f) {
        float v = disen[f * 9 + i];
        n2 += v * v;
        ttl += v * rowsum[f];
      }
      float nrm = sqrtf(n2);
      float pos = 0.f;
      for (int f = 0; f < 4; ++f) {
        float v = disen[f * 9 + i] / nrm;
        pos += v * v;
      }
      cor += (ttl - pos) / TEMPC;
    }
    *cor_out = cor;
  }
}

// ------- dense per-entity relation attention: rel2t[ent][r] = rel_score_r^2 * wsq[r] -------
__global__ void k_rel2(const ushort_t* __restrict__ ent0bf, const float* __restrict__ V,
                       const float* __restrict__ wsq, const int* __restrict__ cnt9,
                       float* __restrict__ rel2t) {
  __shared__ __align__(16) float Vl[576];
  __shared__ float wsql[9];
  for (int i = threadIdx.x; i < 576; i += 256) Vl[i] = V[i];
  if (threadIdx.x < 9) wsql[threadIdx.x] = wsq[threadIdx.x];
  __syncthreads();
  int ent = blockIdx.x * 256 + threadIdx.x;
  if (ent >= N_ENT) return;
  float a[9] = {0, 0, 0, 0, 0, 0, 0, 0, 0};
  const uint4* row = (const uint4*)(ent0bf + (ent << 6));
#pragma unroll
  for (int q = 0; q < 8; ++q) {
    uint4 b = row[q];
    float ch0 = bf2f(b.x & 0xFFFFu), ch1 = bf2f(b.x >> 16);
    float ch2 = bf2f(b.y & 0xFFFFu), ch3 = bf2f(b.y >> 16);
    float ch4 = bf2f(b.z & 0xFFFFu), ch5 = bf2f(b.z >> 16);
    float ch6 = bf2f(b.w & 0xFFFFu), ch7 = bf2f(b.w >> 16);
#pragma unroll
    for (int r = 0; r < 9; ++r) {
      const float4* vp = (const float4*)(Vl + r * 64 + q * 8);
      float4 v0 = vp[0], v1 = vp[1];
      float t = a[r];
      t = fmaf(ch0, v0.x, t); t = fmaf(ch1, v0.y, t);
      t = fmaf(ch2, v0.z, t); t = fmaf(ch3, v0.w, t);
      t = fmaf(ch4, v1.x, t); t = fmaf(ch5, v1.y, t);
      t = fmaf(ch6, v1.z, t); t = fmaf(ch7, v1.w, t);
      a[r] = t;
    }
  }
  const float inv2s = 0.08838834764831845f;  // 1/(2*sqrt(32))
  int cnt[9];
#pragma unroll
  for (int r = 0; r < 9; ++r) cnt[r] = cnt9[ent * 9 + r];
  float m1 = -INFINITY;
#pragma unroll
  for (int r = 0; r < 9; ++r)
    if (cnt[r] > 0) m1 = fmaxf(m1, a[r] * inv2s);
  if (m1 == -INFINITY) {
#pragma unroll
    for (int r = 0; r < 9; ++r) rel2t[ent * 9 + r] = 0.f;
    return;
  }
  float den1 = 1e-16f;
#pragma unroll
  for (int r = 0; r < 9; ++r)
    if (cnt[r] > 0) den1 += (float)cnt[r] * expf(a[r] * inv2s - m1);
#pragma unroll
  for (int r = 0; r < 9; ++r) {
    float rs = expf(a[r] * inv2s - m1) / den1;
    rel2t[ent * 9 + r] = rs * rs * wsql[r];
  }
}

// ------- dense per-user factor scores: sc4[u] = usr[u] @ latent^T -------
__global__ void k_sc(const float* __restrict__ usr, const float* __restrict__ latent,
                     float4* __restrict__ sc4) {
  __shared__ __align__(16) float lat[256];
  if (threadIdx.x < 256) lat[threadIdx.x] = latent[threadIdx.x];
  __syncthreads();
  int u = blockIdx.x * 256 + threadIdx.x;
  if (u >= N_USR) return;
  float a0 = 0.f, a1 = 0.f, a2 = 0.f, a3 = 0.f;
  const float4* row = (const float4*)(usr + (size_t)u * 64);
#pragma unroll
  for (int q = 0; q < 16; ++q) {
    float4 v = row[q];
    float4 l0 = *(const float4*)(lat + 0 * 64 + q * 4);
    float4 l1 = *(const float4*)(lat + 1 * 64 + q * 4);
    float4 l2 = *(const float4*)(lat + 2 * 64 + q * 4);
    float4 l3 = *(const float4*)(lat + 3 * 64 + q * 4);
    a0 = fmaf(v.x, l0.x, a0); a0 = fmaf(v.y, l0.y, a0); a0 = fmaf(v.z, l0.z, a0); a0 = fmaf(v.w, l0.w, a0);
    a1 = fmaf(v.x, l1.x, a1); a1 = fmaf(v.y, l1.y, a1); a1 = fmaf(v.z, l1.z, a1); a1 = fmaf(v.w, l1.w, a1);
    a2 = fmaf(v.x, l2.x, a2); a2 = fmaf(v.y, l2.y, a2); a2 = fmaf(v.z, l2.z, a2); a2 = fmaf(v.w, l2.w, a2);
    a3 = fmaf(v.x, l3.x, a3); a3 = fmaf(v.y, l3.y, a3); a3 = fmaf(v.z, l3.z, a3); a3 = fmaf(v.w, l3.w, a3);
  }
  sc4[u] = make_float4(a0, a1, a2, a3);
}

// ---------------- UI aggregation body (precomputed sc4, cv int2, 4 acc chains) ----------------
__device__ __forceinline__ void ui_body(int usr, int lane,
                                        const ushort_t* __restrict__ srcbf,
                                        const float4* __restrict__ sc4,
                                        const float* __restrict__ addb,
                                        float* __restrict__ outp, float* __restrict__ nxt,
                                        const int* __restrict__ uptr,
                                        const int2* __restrict__ cv,
                                        const float* __restrict__ dwl) {
  float4 s4 = sc4[usr];
  float m = fmaxf(fmaxf(s4.x, s4.y), fmaxf(s4.z, s4.w));
  float e0 = expf(s4.x - m), e1 = expf(s4.y - m), e2 = expf(s4.z - m), e3 = expf(s4.w - m);
  float den = e0 + e1 + e2 + e3;
  float mix = (e0 * dwl[lane] + e1 * dwl[64 + lane] + e2 * dwl[128 + lane] + e3 * dwl[192 + lane]) / den;
  int s = uptr[usr], e = uptr[usr + 1];
  float a0 = 0.f, a1 = 0.f, a2 = 0.f, a3 = 0.f;
  for (int base = s; base < e; base += 64) {
    int c = min(64, e - base);
    int2 cvl = (lane < c) ? cv[base + lane] : make_int2(0, 0);
    int cl = cvl.x;
    float vl = __int_as_float(cvl.y);
    int j = 0;
    for (; j + 8 <= c; j += 8) {
      int c0 = __shfl(cl, j), c1 = __shfl(cl, j + 1), c2 = __shfl(cl, j + 2), c3 = __shfl(cl, j + 3);
      int c4 = __shfl(cl, j + 4), c5 = __shfl(cl, j + 5), c6 = __shfl(cl, j + 6), c7 = __shfl(cl, j + 7);
      float v0 = __shfl(vl, j), v1 = __shfl(vl, j + 1), v2 = __shfl(vl, j + 2), v3 = __shfl(vl, j + 3);
      float v4 = __shfl(vl, j + 4), v5 = __shfl(vl, j + 5), v6 = __shfl(vl, j + 6), v7 = __shfl(vl, j + 7);
      float r0 = bf2f(srcbf[(c0 << 6) + lane]);
      float r1 = bf2f(srcbf[(c1 << 6) + lane]);
      float r2 = bf2f(srcbf[(c2 << 6) + lane]);
      float r3 = bf2f(srcbf[(c3 << 6) + lane]);
      float r4 = bf2f(srcbf[(c4 << 6) + lane]);
      float r5 = bf2f(srcbf[(c5 << 6) + lane]);
      float r6 = bf2f(srcbf[(c6 << 6) + lane]);
      float r7 = bf2f(srcbf[(c7 << 6) + lane]);
      a0 = fmaf(r0, v0, a0); a1 = fmaf(r1, v1, a1);
      a2 = fmaf(r2, v2, a2); a3 = fmaf(r3, v3, a3);
      a0 = fmaf(r4, v4, a0); a1 = fmaf(r5, v5, a1);
      a2 = fmaf(r6, v6, a2); a3 = fmaf(r7, v7, a3);
    }
    for (; j < c; ++j) {
      int cj = __shfl(cl, j);
      float vj = __shfl(vl, j);
      a0 = fmaf(bf2f(srcbf[(cj << 6) + lane]), vj, a0);
    }
  }
  float acc = (a0 + a1) + (a2 + a3);
  float ua = acc * mix + acc;
  float nrm = sqrtf(waveReduceSum(ua * ua));
  float val = ua / fmaxf(nrm, 1e-12f);
  size_t o = (size_t)usr * 64 + lane;
  if (nxt) nxt[o] = val;
  outp[o] = addb[o] + val;
}

// KG aggregation inner (4 acc chains) over lane-resident pk/mk
__device__ __forceinline__ float kg_agg64(int deg, int lane, int pk, float mk,
                                          const ushort_t* __restrict__ srcbf,
                                          const float* __restrict__ wl) {
  float a0 = 0.f, a1 = 0.f, a2 = 0.f, a3 = 0.f;
  int j = 0;
  for (; j + 4 <= deg; j += 4) {
    int p0 = __shfl(pk, j), p1 = __shfl(pk, j + 1), p2 = __shfl(pk, j + 2), p3 = __shfl(pk, j + 3);
    float k0 = __shfl(mk, j), k1 = __shfl(mk, j + 1), k2 = __shfl(mk, j + 2), k3 = __shfl(mk, j + 3);
    float r0 = bf2f(srcbf[((p0 & 0xFFFFF) << 6) + lane]);
    float r1 = bf2f(srcbf[((p1 & 0xFFFFF) << 6) + lane]);
    float r2 = bf2f(srcbf[((p2 & 0xFFFFF) << 6) + lane]);
    float r3 = bf2f(srcbf[((p3 & 0xFFFFF) << 6) + lane]);
    a0 = fmaf(r0 * wl[(((p0 >> 20) & 15) << 6) + lane], k0, a0);
    a1 = fmaf(r1 * wl[(((p1 >> 20) & 15) << 6) + lane], k1, a1);
    a2 = fmaf(r2 * wl[(((p2 >> 20) & 15) << 6) + lane], k2, a2);
    a3 = fmaf(r3 * wl[(((p3 >> 20) & 15) << 6) + lane], k3, a3);
  }
  for (; j < deg; ++j) {
    int pj = __shfl(pk, j);
    float kj = __shfl(mk, j);
    a0 = fmaf(bf2f(srcbf[((pj & 0xFFFFF) << 6) + lane]) * wl[(((pj >> 20) & 15) << 6) + lane], kj, a0);
  }
  return (a0 + a1) + (a2 + a3);
}

// ---------------- D1: mask + fused KG hop-1  |  UI hop-1 ----------------
__global__ void k_mask_kg_ui(const float* __restrict__ ent0,
                             const ushort_t* __restrict__ ent0bf,
                             const int* __restrict__ hptr, const int* __restrict__ packed,
                             const float* __restrict__ rel2t,
                             float* __restrict__ mask_s, const float* __restrict__ weight,
                             float* __restrict__ out_ent, ushort_t* __restrict__ ent1bf,
                             const float4* __restrict__ sc4,
                             float* __restrict__ out_usr,
                             float* __restrict__ usr1, const int* __restrict__ uptr,
                             const int2* __restrict__ cv,
                             const float* __restrict__ user_emb, const float* __restrict__ dw) {
  int lane = threadIdx.x & 63, wid = threadIdx.x >> 6;
  if (blockIdx.x < KG_BLOCKS) {
    __shared__ __align__(16) float sh_eh[4][64];
    __shared__ float wl[576];
    for (int i = threadIdx.x; i < 576; i += 256) wl[i] = weight[i];
    int ent = blockIdx.x * 4 + wid;  // always < N_ENT
    int s = hptr[ent], e = hptr[ent + 1];
    float eh = ent0[(size_t)ent * 64 + lane];
    sh_eh[wid][lane] = eh;
    __syncthreads();
    size_t o = (size_t)ent * 64 + lane;
    int deg = e - s;
    if (deg == 0) {
      ent1bf[o] = f2bf(0.f);
      out_ent[o] = eh;
      return;
    }
    if (deg <= 64) {
      // ---- hot path ----
      int pk = (lane < deg) ? packed[s + lane] : 0;
      int tb = (pk >> 20) & 15;
      float r2sel = rel2t[ent * 9 + ((lane < deg) ? tb : 0)];
      // ---- 8-lane-per-edge dot: lane = 8*slot + part ----
      int part = lane & 7;
      const float4* ehq = (const float4*)(sh_eh[wid] + (part << 3));
      float4 ef0 = ehq[0], ef1 = ehq[1];
      float myDot = 0.f;
      int nch = (deg + 7) >> 3;
      for (int c2 = 0; c2 < nch; ++c2) {
        int pkj = __shfl(pk, (c2 << 3) + (lane >> 3));
        const uint4* row = (const uint4*)(ent0bf + ((pkj & 0xFFFFF) << 6)) + part;
        uint4 b = *row;
        float s0 = bf2f(b.x & 0xFFFFu) * ef0.x;
        float s1 = bf2f(b.y & 0xFFFFu) * ef0.z;
        float s2 = bf2f(b.z & 0xFFFFu) * ef1.x;
        float s3 = bf2f(b.w & 0xFFFFu) * ef1.z;
        s0 = fmaf(bf2f(b.x >> 16), ef0.y, s0);
        s1 = fmaf(bf2f(b.y >> 16), ef0.w, s1);
        s2 = fmaf(bf2f(b.z >> 16), ef1.y, s2);
        s3 = fmaf(bf2f(b.w >> 16), ef1.w, s3);
        float sv = (s0 + s1) + (s2 + s3);
        sv += __shfl_xor(sv, 1);
        sv += __shfl_xor(sv, 2);
        sv += __shfl_xor(sv, 4);
        float got = __shfl(sv, part << 3);
        myDot = ((lane >> 3) == c2) ? got : myDot;
      }
      float trip = (lane < deg) ? myDot + r2sel : -INFINITY;
      float m2 = waveReduceMax(trip);
      float ex = (lane < deg) ? expf(trip - m2) : 0.f;
      float den2 = waveReduceSum(ex) + 1e-16f;
      float mk = ex / den2;
      if (lane < deg) mask_s[s + lane] = mk;
      // ---- fused KG hop-1 aggregation (rows L1/L2-hot) ----
      float acc = kg_agg64(deg, lane, pk, mk, ent0bf, wl);
      float agg = acc / (float)deg;
      float nrm = sqrtf(waveReduceSum(agg * agg));
      float val = agg / fmaxf(nrm, 1e-12f);
      ent1bf[o] = f2bf(val);
      out_ent[o] = eh + val;
    } else {
      // ---- generic multi-chunk path (statistically unreachable at mean deg 10) ----
      float m2l = -INFINITY;
      for (int base = s; base < e; base += 64) {
        int c = min(64, e - base);
        int pk = (lane < c) ? packed[base + lane] : 0;
        int tb = (pk >> 20) & 15;
        float r2 = rel2t[ent * 9 + ((lane < c) ? tb : 0)];
        int tl = pk & 0xFFFFF;
        const uint4* row = (const uint4*)(ent0bf + (tl << 6));
        const float* ehp = sh_eh[wid];
        float d = 0.f;
#pragma unroll
        for (int q = 0; q < 8; ++q) {
          uint4 a = row[q];
          d += bf2f(a.x & 0xFFFF) * ehp[q * 8 + 0] + bf2f(a.x >> 16) * ehp[q * 8 + 1];
          d += bf2f(a.y & 0xFFFF) * ehp[q * 8 + 2] + bf2f(a.y >> 16) * ehp[q * 8 + 3];
          d += bf2f(a.z & 0xFFFF) * ehp[q * 8 + 4] + bf2f(a.z >> 16) * ehp[q * 8 + 5];
          d += bf2f(a.w & 0xFFFF) * ehp[q * 8 + 6] + bf2f(a.w >> 16) * ehp[q * 8 + 7];
        }
        float trip = d + r2;
        if (lane < c) {
          mask_s[base + lane] = trip;
          m2l = fmaxf(m2l, trip);
        }
      }
      float m2 = waveReduceMax(m2l);
      float denl = 0.f;
      for (int base = s; base < e; base += 64) {
        int c = min(64, e - base);
        denl += (lane < c) ? expf(mask_s[base + lane] - m2) : 0.f;
      }
      float den2 = waveReduceSum(denl) + 1e-16f;
      float acc = 0.f;
      for (int base = s; base < e; base += 64) {
        int c = min(64, e - base);
        int pk = (lane < c) ? packed[base + lane] : 0;
        float mk = 0.f;
        if (lane < c) {
          mk = expf(mask_s[base + lane] - m2) / den2;
          mask_s[base + lane] = mk;
        }
        acc += kg_agg64(c, lane, pk, mk, ent0bf, wl);
      }
      float agg = acc / (float)deg;
      float nrm = sqrtf(waveReduceSum(agg * agg));
      float val = agg / fmaxf(nrm, 1e-12f);
      ent1bf[o] = f2bf(val);
      out_ent[o] = eh + val;
    }
  } else {
    __shared__ float dwl[256];
    if (threadIdx.x < 256) dwl[threadIdx.x] = dw[threadIdx.x];
    __syncthreads();
    int usr = (blockIdx.x - KG_BLOCKS) * 4 + wid;  // always < N_USR
    ui_body(usr, lane, ent0bf, sc4, user_emb, out_usr, usr1,
            uptr, cv, dwl);
  }
}

// ---------------- D2: KG hop-2 + UI hop-2 ----------------
__global__ void k_hop2(const ushort_t* __restrict__ srcbf,
                       float* __restrict__ out_ent,
                       const int* __restrict__ hptr, const int* __restrict__ packed,
                       const float* __restrict__ mask_s, const float* __restrict__ weight,
                       const float* __restrict__ usr1, float* __restrict__ out_usr,
                       const int* __restrict__ uptr, const int2* __restrict__ cv,
                       const float4* __restrict__ sc4,
                       const float* __restrict__ dw) {
  int lane = threadIdx.x & 63, wid = threadIdx.x >> 6;
  if (blockIdx.x < KG_BLOCKS) {
    __shared__ float wl[576];
    for (int i = threadIdx.x; i < 576; i += 256) wl[i] = weight[i];
    __syncthreads();
    int ent = blockIdx.x * 4 + wid;
    int s = hptr[ent], e = hptr[ent + 1];
    float acc = 0.f;
    for (int base = s; base < e; base += 64) {
      int c = min(64, e - base);
      int pk = (lane < c) ? packed[base + lane] : 0;
      float mk = (lane < c) ? mask_s[base + lane] : 0.f;
      acc += kg_agg64(c, lane, pk, mk, srcbf, wl);
    }
    float n = (float)(e - s);
    float agg = acc / fmaxf(n, 1.0f);
    float nrm = sqrtf(waveReduceSum(agg * agg));
    float val = agg / fmaxf(nrm, 1e-12f);
    size_t o = (size_t)ent * 64 + lane;
    out_ent[o] = out_ent[o] + val;
  } else {
    __shared__ float dwl[256];
    if (threadIdx.x < 256) dwl[threadIdx.x] = dw[threadIdx.x];
    __syncthreads();
    int usr = (blockIdx.x - KG_BLOCKS) * 4 + wid;
    ui_body(usr, lane, srcbf, sc4, out_usr, out_usr, nullptr,
            uptr, cv, dwl);
  }
}

extern "C" void kernel_launch(void* const* d_in, const int* in_sizes, int n_in,
                              void* d_out, int out_size, void* d_ws, size_t ws_size,
                              hipStream_t stream) {
  const float* user_emb = (const float*)d_in[0];
  const float* entity_emb = (const float*)d_in[1];
  const float* latent = (const float*)d_in[2];
  const float* weight = (const float*)d_in[3];
  const float* disen = (const float*)d_in[4];
  const float* kgW = (const float*)d_in[5];
  const float* ui_vals = (const float*)d_in[6];
  const int* edge_index = (const int*)d_in[7];
  const int* edge_type = (const int*)d_in[8];
  const int* ui_rows = (const int*)d_in[9];
  const int* ui_cols = (const int*)d_in[10];
  const int* head = edge_index;
  const int* tail = edge_index + N_EDGE;

  char* ws = (char*)d_ws;
  size_t o = 0;
  auto alloc = [&](size_t bytes) -> char* {
    char* p = ws + o;
    o += (bytes + 255) & ~(size_t)255;
    return p;
  };
  int* head_ptr = (int*)alloc((N_ENT + 1) * 4);
  int* head_cur = (int*)alloc((size_t)N_ENT * 4);
  int* ui_ptr = (int*)alloc((N_USR + 1) * 4);
  int* ui_cur = (int*)alloc((size_t)N_USR * 4);
  int* bsum_h = (int*)alloc(256 * 4);
  int* bsum_u = (int*)alloc(256 * 4);
  int* packed = (int*)alloc((size_t)N_EDGE * 4);
  int2* cv = (int2*)alloc((size_t)N_EDGE * 8);
  float* mask_s = (float*)alloc((size_t)N_EDGE * 4);
  ushort_t* ent0bf = (ushort_t*)alloc((size_t)N_ENT * 64 * 2);
  ushort_t* ent1bf = (ushort_t*)alloc((size_t)N_ENT * 64 * 2);
  float* usr1 = (float*)alloc((size_t)N_USR * 64 * 4);
  int* cnt9 = (int*)alloc((size_t)N_ENT * 9 * 4);
  float* rel2t = (float*)alloc((size_t)N_ENT * 9 * 4);
  float4* sc4a = (float4*)alloc((size_t)N_USR * 16);
  float4* sc4b = (float4*)alloc((size_t)N_USR * 16);
  float* V = (float*)alloc(9 * 64 * 4);
  float* wsq = (float*)alloc(16 * 4);
  float* dw = (float*)alloc(4 * 64 * 4);
  if (o > ws_size) return;

  float* out_ent = (float*)d_out;
  float* out_usr = out_ent + (size_t)N_ENT * 64;
  float* out_cor = out_ent + (size_t)N_ENT * 64 + (size_t)N_USR * 64;

  hipMemsetAsync(ui_cur, 0, (size_t)N_USR * 4, stream);
  hipMemsetAsync(cnt9, 0, (size_t)N_ENT * 9 * 4, stream);

  int eb4 = (N_EDGE / 4 + 255) / 256;
  k_count<<<eb4, 256, 0, stream>>>(head, ui_rows, edge_type, ui_cur, cnt9);
  k_sumrow9<<<(N_ENT + 255) / 256, 256, 0, stream>>>(cnt9, head_cur);

  int nbh = (N_ENT + 1023) / 1024, nbu = (N_USR + 1023) / 1024;
  k_scan_reduce<<<nbh, 256, 0, stream>>>(head_cur, N_ENT, bsum_h);
  k_scan_reduce<<<nbu, 256, 0, stream>>>(ui_cur, N_USR, bsum_u);
  k_scan_tops<<<1, 64, 0, stream>>>(bsum_h, nbh, bsum_u, nbu, head_ptr, N_ENT, ui_ptr, N_USR, N_EDGE);
  k_scan_final<<<nbh, 256, 0, stream>>>(head_cur, N_ENT, bsum_h, head_ptr, head_cur);
  k_scan_final<<<nbu, 256, 0, stream>>>(ui_cur, N_USR, bsum_u, ui_ptr, ui_cur);

  k_build<<<eb4, 256, 0, stream>>>(head, tail, edge_type, ui_rows, ui_cols, ui_vals,
                                   head_cur, ui_cur, packed, cv);

  k_tobf<<<(N_ENT * 64 / 4 + 255) / 256, 256, 0, stream>>>(entity_emb, ent0bf, N_ENT * 64 / 4);
  k_prep<<<1, 256, 0, stream>>>(weight, kgW, disen, V, wsq, dw, out_cor);
  k_rel2<<<(N_ENT + 255) / 256, 256, 0, stream>>>(ent0bf, V, wsq, cnt9, rel2t);
  k_sc<<<(N_USR + 255) / 256, 256, 0, stream>>>(user_emb, latent, sc4a);

  // D1: mask + fused KG hop-1 + UI hop-1
  k_mask_kg_ui<<<KG_BLOCKS + UI_BLOCKS, 256, 0, stream>>>(
      entity_emb, ent0bf, head_ptr, packed, rel2t, mask_s, weight,
      out_ent, ent1bf, sc4a, out_usr, usr1, ui_ptr, cv, user_emb, dw);

  // sc for hop-2 from usr1
  k_sc<<<(N_USR + 255) / 256, 256, 0, stream>>>(usr1, latent, sc4b);

  // D2: KG hop-2 + UI hop-2
  k_hop2<<<KG_BLOCKS + UI_BLOCKS, 256, 0, stream>>>(
      ent1bf, out_ent, head_ptr, packed, mask_s, weight,
      usr1, out_usr, ui_ptr, cv, sc4b, dw);
}

// Round 9
// 592.850 us; speedup vs baseline: 1.5489x; 1.0721x over previous
//
#include <hip/hip_runtime.h>
#include <math.h>

#define N_ENT 100000
#define N_USR 50000
#define N_EDGE 1000000
#define TEMPC 0.2f
#define KG_BLOCKS (N_ENT / 4)   // 25000, exact
#define UI_BLOCKS (N_USR / 4)   // 12500, exact

// fused-kernel block ranges
#define TB_BLOCKS 6250   // ceil(N_ENT*64/4 / 256) : bf16 convert (float4 granules)
#define CNT_BLOCKS 489   // ceil(N_EDGE/8 / 256) : count, 8 edges/thread
#define SC_BLOCKS 196    // ceil(N_USR / 256)
#define BUILD_BLOCKS 489 // ceil(N_EDGE/8 / 256)
#define REL2_BLOCKS 391  // ceil(N_ENT / 256)

typedef unsigned short ushort_t;

__device__ __forceinline__ float waveReduceSum(float x) {
#pragma unroll
  for (int d = 32; d > 0; d >>= 1) x += __shfl_xor(x, d);
  return x;
}
__device__ __forceinline__ float waveReduceMax(float x) {
#pragma unroll
  for (int d = 32; d > 0; d >>= 1) x = fmaxf(x, __shfl_xor(x, d));
  return x;
}
__device__ __forceinline__ int waveReduceSumI(int x) {
#pragma unroll
  for (int d = 32; d > 0; d >>= 1) x += __shfl_xor(x, d);
  return x;
}
__device__ __forceinline__ float bf2f(unsigned int u16) {
  union { unsigned int i; float f; } v;
  v.i = u16 << 16;
  return v.f;
}
__device__ __forceinline__ ushort_t f2bf(float f) {
  union { unsigned int i; float f; } v;
  v.f = f;
  unsigned int u = v.i;
  u = (u + 0x7FFFu + ((u >> 16) & 1u)) >> 16;
  return (ushort_t)u;
}
// wave-uniform broadcast via v_readlane -> SGPR (cheap scalar addressing downstream)
__device__ __forceinline__ int rl(int v, int l) { return __builtin_amdgcn_readlane(v, l); }
__device__ __forceinline__ float rlf(float v, int l) {
  return __int_as_float(__builtin_amdgcn_readlane(__float_as_int(v), l));
}

// ============ K1: bf16 convert | edge count (8/thr) | prep | sc(user) ============
__global__ void k_pre(const float* __restrict__ ent0, ushort_t* __restrict__ ent0bf,
                      const int* __restrict__ head, const int* __restrict__ uir,
                      const int* __restrict__ etype,
                      int* __restrict__ cnt_u, int* __restrict__ cnt9,
                      const float* __restrict__ weight, const float* __restrict__ kgW,
                      const float* __restrict__ disen,
                      float* __restrict__ V, float* __restrict__ wsq,
                      float* __restrict__ dw, float* __restrict__ cor_out,
                      const float* __restrict__ user_emb, const float* __restrict__ latent,
                      float4* __restrict__ sc4a) {
  int bid = blockIdx.x;
  if (bid < TB_BLOCKS) {
    int i = bid * 256 + threadIdx.x;
    if (i < N_ENT * 16) {
      float4 v = ((const float4*)ent0)[i];
      ushort4 o;
      o.x = f2bf(v.x); o.y = f2bf(v.y); o.z = f2bf(v.z); o.w = f2bf(v.w);
      ((ushort4*)ent0bf)[i] = o;
    }
  } else if (bid < TB_BLOCKS + CNT_BLOCKS) {
    int i0 = ((bid - TB_BLOCKS) * 256 + threadIdx.x) * 8;
    if (i0 < N_EDGE) {
      int4 ha = *(const int4*)(head + i0), hb = *(const int4*)(head + i0 + 4);
      int4 ea = *(const int4*)(etype + i0), eb = *(const int4*)(etype + i0 + 4);
      int4 ua = *(const int4*)(uir + i0), ub = *(const int4*)(uir + i0 + 4);
      atomicAdd(&cnt9[ha.x * 9 + (ea.x - 1)], 1);
      atomicAdd(&cnt9[ha.y * 9 + (ea.y - 1)], 1);
      atomicAdd(&cnt9[ha.z * 9 + (ea.z - 1)], 1);
      atomicAdd(&cnt9[ha.w * 9 + (ea.w - 1)], 1);
      atomicAdd(&cnt9[hb.x * 9 + (eb.x - 1)], 1);
      atomicAdd(&cnt9[hb.y * 9 + (eb.y - 1)], 1);
      atomicAdd(&cnt9[hb.z * 9 + (eb.z - 1)], 1);
      atomicAdd(&cnt9[hb.w * 9 + (eb.w - 1)], 1);
      atomicAdd(&cnt_u[ua.x], 1);
      atomicAdd(&cnt_u[ua.y], 1);
      atomicAdd(&cnt_u[ua.z], 1);
      atomicAdd(&cnt_u[ua.w], 1);
      atomicAdd(&cnt_u[ub.x], 1);
      atomicAdd(&cnt_u[ub.y], 1);
      atomicAdd(&cnt_u[ub.z], 1);
      atomicAdd(&cnt_u[ub.w], 1);
    }
  } else if (bid == TB_BLOCKS + CNT_BLOCKS) {
    // ---- prep: V=(W W^T)w_r via T-factorization, wsq, dw, cor ----
    __shared__ float T[9 * 64];
    __shared__ float sm[4 * 9];
    int tid = threadIdx.x;
    for (int e = tid; e < 9 * 64; e += 256) {
      int r = e >> 6, d = e & 63;
      float s = 0.f;
      for (int k = 0; k < 64; ++k) s += kgW[k * 64 + d] * weight[r * 64 + k];
      T[e] = s;
    }
    if (tid < 4) {
      float m = -INFINITY;
      for (int r = 0; r < 9; ++r) m = fmaxf(m, disen[tid * 9 + r]);
      float den = 0.f;
      float ex[9];
      for (int r = 0; r < 9; ++r) { ex[r] = expf(disen[tid * 9 + r] - m); den += ex[r]; }
      for (int r = 0; r < 9; ++r) sm[tid * 9 + r] = ex[r] / den;
    }
    __syncthreads();
    for (int e = tid; e < 9 * 64; e += 256) {
      int r = e >> 6, i = e & 63;
      float s = 0.f;
      for (int d = 0; d < 64; ++d) s += kgW[i * 64 + d] * T[r * 64 + d];
      V[e] = s;
    }
    if (tid < 9) {
      float s = 0.f;
      for (int c = 0; c < 64; ++c) { float w = weight[tid * 64 + c]; s += w * w; }
      wsq[tid] = s;
    }
    for (int e = tid; e < 4 * 64; e += 256) {
      int f = e >> 6, c = e & 63;
      float s = 0.f;
      for (int r = 0; r < 9; ++r) s += sm[f * 9 + r] * weight[r * 64 + c];
      dw[e] = s;
    }
    if (tid == 0) {
      float rowsum[4];
      for (int f = 0; f < 4; ++f) {
        float s = 0.f;
        for (int j = 0; j < 9; ++j) s += disen[f * 9 + j];
        rowsum[f] = s;
      }
      float cor = 0.f;
      for (int i = 0; i < 9; ++i) {
        float n2 = 0.f, ttl = 0.f;
        for (int f = 0; f < 4; ++f) {
          float v = disen[f * 9 + i];
          n2 += v * v;
          ttl += v * rowsum[f];
        }
        float nrm = sqrtf(n2);
        float pos = 0.f;
        for (int f = 0; f < 4; ++f) {
          float v = disen[f * 9 + i] / nrm;
          pos += v * v;
        }
        cor += (ttl - pos) / TEMPC;
      }
      *cor_out = cor;
    }
  } else {
    // ---- sc on user_emb -> sc4a ----
    __shared__ __align__(16) float lat[256];
    if (threadIdx.x < 256) lat[threadIdx.x] = latent[threadIdx.x];
    __syncthreads();
    int u = (bid - TB_BLOCKS - CNT_BLOCKS - 1) * 256 + threadIdx.x;
    if (u >= N_USR) return;
    float a0 = 0.f, a1 = 0.f, a2 = 0.f, a3 = 0.f;
    const float4* row = (const float4*)(user_emb + (size_t)u * 64);
#pragma unroll
    for (int q = 0; q < 16; ++q) {
      float4 v = row[q];
      float4 l0 = *(const float4*)(lat + 0 * 64 + q * 4);
      float4 l1 = *(const float4*)(lat + 1 * 64 + q * 4);
      float4 l2 = *(const float4*)(lat + 2 * 64 + q * 4);
      float4 l3 = *(const float4*)(lat + 3 * 64 + q * 4);
      a0 = fmaf(v.x, l0.x, a0); a0 = fmaf(v.y, l0.y, a0); a0 = fmaf(v.z, l0.z, a0); a0 = fmaf(v.w, l0.w, a0);
      a1 = fmaf(v.x, l1.x, a1); a1 = fmaf(v.y, l1.y, a1); a1 = fmaf(v.z, l1.z, a1); a1 = fmaf(v.w, l1.w, a1);
      a2 = fmaf(v.x, l2.x, a2); a2 = fmaf(v.y, l2.y, a2); a2 = fmaf(v.z, l2.z, a2); a2 = fmaf(v.w, l2.w, a2);
      a3 = fmaf(v.x, l3.x, a3); a3 = fmaf(v.y, l3.y, a3); a3 = fmaf(v.z, l3.z, a3); a3 = fmaf(v.w, l3.w, a3);
    }
    sc4a[u] = make_float4(a0, a1, a2, a3);
  }
}

// ============ K2: fused scan-reduce (head from cnt9 rowsums | ui) ============
__global__ void k_scanred(const int* __restrict__ cnt9, const int* __restrict__ cnt_u,
                          int* __restrict__ bsum_h, int* __restrict__ bsum_u, int nbh) {
  int b = blockIdx.x, tid = threadIdx.x;
  int s = 0;
  if (b < nbh) {
    int i0 = b * 1024 + tid * 4;
#pragma unroll
    for (int k = 0; k < 4; ++k)
      if (i0 + k < N_ENT) {
        int base = (i0 + k) * 9;
#pragma unroll
        for (int r = 0; r < 9; ++r) s += cnt9[base + r];
      }
  } else {
    int i0 = (b - nbh) * 1024 + tid * 4;
#pragma unroll
    for (int k = 0; k < 4; ++k)
      if (i0 + k < N_USR) s += cnt_u[i0 + k];
  }
  s = waveReduceSumI(s);
  __shared__ int l[4];
  int lane = tid & 63, wid = tid >> 6;
  if (lane == 0) l[wid] = s;
  __syncthreads();
  if (tid == 0) {
    int v = l[0] + l[1] + l[2] + l[3];
    if (b < nbh) bsum_h[b] = v; else bsum_u[b - nbh] = v;
  }
}

__global__ void k_scan_tops(int* bsA, int nA, int* bsB, int nB,
                            int* ptrA, int NA, int* ptrB, int NB, int total) {
  if (threadIdx.x == 0) {
    int a = 0;
    for (int i = 0; i < nA; ++i) { int t = bsA[i]; bsA[i] = a; a += t; }
    ptrA[NA] = total;
  }
  if (threadIdx.x == 1) {
    int a = 0;
    for (int i = 0; i < nB; ++i) { int t = bsB[i]; bsB[i] = a; a += t; }
    ptrB[NB] = total;
  }
}

// ============ K4: fused scan-final (head from cnt9 | ui) ============
__global__ void k_scanfin(const int* __restrict__ cnt9, const int* __restrict__ bsum_h,
                          const int* __restrict__ bsum_u,
                          int* __restrict__ head_ptr, int* __restrict__ head_cur,
                          int* __restrict__ ui_ptr, int* __restrict__ ui_cur, int nbh) {
  int b = blockIdx.x, tid = threadIdx.x;
  bool isH = (b < nbh);
  int bl = isH ? b : b - nbh;
  int n = isH ? N_ENT : N_USR;
  int i0 = bl * 1024 + tid * 4;
  int c[4];
  int s = 0;
  int loc[4];
#pragma unroll
  for (int k = 0; k < 4; ++k) {
    int v = 0;
    if (i0 + k < n) {
      if (isH) {
        int base = (i0 + k) * 9;
#pragma unroll
        for (int r = 0; r < 9; ++r) v += cnt9[base + r];
      } else {
        v = ui_cur[i0 + k];
      }
    }
    c[k] = v;
    loc[k] = s;
    s += v;
  }
  int lane = tid & 63, wid = tid >> 6;
  int x = s;
#pragma unroll
  for (int d = 1; d < 64; d <<= 1) {
    int y = __shfl_up(x, d);
    if (lane >= d) x += y;
  }
  __shared__ int l[4];
  if (lane == 63) l[wid] = x;
  __syncthreads();
  if (tid == 0) {
    int a = 0;
    for (int w = 0; w < 4; ++w) { int t = l[w]; l[w] = a; a += t; }
  }
  __syncthreads();
  int excl = x - s + l[wid] + (isH ? bsum_h[bl] : bsum_u[bl]);
#pragma unroll
  for (int k = 0; k < 4; ++k) {
    if (i0 + k < n) {
      int v = excl + loc[k];
      if (isH) {
        head_ptr[i0 + k] = v;
        head_cur[i0 + k] = v;
      } else {
        ui_ptr[i0 + k] = v;
        ui_cur[i0 + k] = v;
      }
    }
  }
}

// ============ K5: build (8/thr) | rel2 ============
__global__ void k_build_rel2(const int* __restrict__ head, const int* __restrict__ tail,
                             const int* __restrict__ etype,
                             const int* __restrict__ uir, const int* __restrict__ uic,
                             const float* __restrict__ uival,
                             int* __restrict__ cur_h, int* __restrict__ cur_u,
                             int* __restrict__ packed, int2* __restrict__ cv,
                             const ushort_t* __restrict__ ent0bf, const float* __restrict__ V,
                             const float* __restrict__ wsq, const int* __restrict__ cnt9,
                             float* __restrict__ rel2t) {
  if (blockIdx.x < BUILD_BLOCKS) {
    int i0 = (blockIdx.x * 256 + threadIdx.x) * 8;
    if (i0 >= N_EDGE) return;
    int4 ha = *(const int4*)(head + i0), hb = *(const int4*)(head + i0 + 4);
    int4 ta = *(const int4*)(tail + i0), tb4 = *(const int4*)(tail + i0 + 4);
    int4 ea = *(const int4*)(etype + i0), eb = *(const int4*)(etype + i0 + 4);
    int4 ua = *(const int4*)(uir + i0), ub = *(const int4*)(uir + i0 + 4);
    int4 ca = *(const int4*)(uic + i0), cb = *(const int4*)(uic + i0 + 4);
    float4 va = *(const float4*)(uival + i0), vb = *(const float4*)(uival + i0 + 4);
    int p0 = atomicAdd(&cur_h[ha.x], 1);
    int p1 = atomicAdd(&cur_h[ha.y], 1);
    int p2 = atomicAdd(&cur_h[ha.z], 1);
    int p3 = atomicAdd(&cur_h[ha.w], 1);
    int p4 = atomicAdd(&cur_h[hb.x], 1);
    int p5 = atomicAdd(&cur_h[hb.y], 1);
    int p6 = atomicAdd(&cur_h[hb.z], 1);
    int p7 = atomicAdd(&cur_h[hb.w], 1);
    int q0 = atomicAdd(&cur_u[ua.x], 1);
    int q1 = atomicAdd(&cur_u[ua.y], 1);
    int q2 = atomicAdd(&cur_u[ua.z], 1);
    int q3 = atomicAdd(&cur_u[ua.w], 1);
    int q4 = atomicAdd(&cur_u[ub.x], 1);
    int q5 = atomicAdd(&cur_u[ub.y], 1);
    int q6 = atomicAdd(&cur_u[ub.z], 1);
    int q7 = atomicAdd(&cur_u[ub.w], 1);
    packed[p0] = (ta.x & 0xFFFFF) | ((ea.x - 1) << 20);
    packed[p1] = (ta.y & 0xFFFFF) | ((ea.y - 1) << 20);
    packed[p2] = (ta.z & 0xFFFFF) | ((ea.z - 1) << 20);
    packed[p3] = (ta.w & 0xFFFFF) | ((ea.w - 1) << 20);
    packed[p4] = (tb4.x & 0xFFFFF) | ((eb.x - 1) << 20);
    packed[p5] = (tb4.y & 0xFFFFF) | ((eb.y - 1) << 20);
    packed[p6] = (tb4.z & 0xFFFFF) | ((eb.z - 1) << 20);
    packed[p7] = (tb4.w & 0xFFFFF) | ((eb.w - 1) << 20);
    cv[q0] = make_int2(ca.x, __float_as_int(va.x));
    cv[q1] = make_int2(ca.y, __float_as_int(va.y));
    cv[q2] = make_int2(ca.z, __float_as_int(va.z));
    cv[q3] = make_int2(ca.w, __float_as_int(va.w));
    cv[q4] = make_int2(cb.x, __float_as_int(vb.x));
    cv[q5] = make_int2(cb.y, __float_as_int(vb.y));
    cv[q6] = make_int2(cb.z, __float_as_int(vb.z));
    cv[q7] = make_int2(cb.w, __float_as_int(vb.w));
  } else {
    // ---- rel2: dense per-entity relation softmax table ----
    __shared__ __align__(16) float Vl[576];
    __shared__ float wsql[9];
    for (int i = threadIdx.x; i < 576; i += 256) Vl[i] = V[i];
    if (threadIdx.x < 9) wsql[threadIdx.x] = wsq[threadIdx.x];
    __syncthreads();
    int ent = (blockIdx.x - BUILD_BLOCKS) * 256 + threadIdx.x;
    if (ent >= N_ENT) return;
    float a[9] = {0, 0, 0, 0, 0, 0, 0, 0, 0};
    const uint4* row = (const uint4*)(ent0bf + (ent << 6));
#pragma unroll
    for (int q = 0; q < 8; ++q) {
      uint4 b = row[q];
      float ch0 = bf2f(b.x & 0xFFFFu), ch1 = bf2f(b.x >> 16);
      float ch2 = bf2f(b.y & 0xFFFFu), ch3 = bf2f(b.y >> 16);
      float ch4 = bf2f(b.z & 0xFFFFu), ch5 = bf2f(b.z >> 16);
      float ch6 = bf2f(b.w & 0xFFFFu), ch7 = bf2f(b.w >> 16);
#pragma unroll
      for (int r = 0; r < 9; ++r) {
        const float4* vp = (const float4*)(Vl + r * 64 + q * 8);
        float4 v0 = vp[0], v1 = vp[1];
        float t = a[r];
        t = fmaf(ch0, v0.x, t); t = fmaf(ch1, v0.y, t);
        t = fmaf(ch2, v0.z, t); t = fmaf(ch3, v0.w, t);
        t = fmaf(ch4, v1.x, t); t = fmaf(ch5, v1.y, t);
        t = fmaf(ch6, v1.z, t); t = fmaf(ch7, v1.w, t);
        a[r] = t;
      }
    }
    const float inv2s = 0.08838834764831845f;  // 1/(2*sqrt(32))
    int cnt[9];
#pragma unroll
    for (int r = 0; r < 9; ++r) cnt[r] = cnt9[ent * 9 + r];
    float m1 = -INFINITY;
#pragma unroll
    for (int r = 0; r < 9; ++r)
      if (cnt[r] > 0) m1 = fmaxf(m1, a[r] * inv2s);
    if (m1 == -INFINITY) {
#pragma unroll
      for (int r = 0; r < 9; ++r) rel2t[ent * 9 + r] = 0.f;
      return;
    }
    float den1 = 1e-16f;
#pragma unroll
    for (int r = 0; r < 9; ++r)
      if (cnt[r] > 0) den1 += (float)cnt[r] * expf(a[r] * inv2s - m1);
#pragma unroll
    for (int r = 0; r < 9; ++r) {
      float rs = expf(a[r] * inv2s - m1) / den1;
      rel2t[ent * 9 + r] = rs * rs * wsql[r];
    }
  }
}

// ---------------- UI aggregation body (readlane broadcasts) ----------------
__device__ __forceinline__ void ui_body(int usr, int lane,
                                        const ushort_t* __restrict__ srcbf,
                                        const float4* __restrict__ sc4,
                                        const float* __restrict__ addb,
                                        float* __restrict__ outp, float* __restrict__ nxt,
                                        const int* __restrict__ uptr,
                                        const int2* __restrict__ cv,
                                        const float* __restrict__ dwl,
                                        const float* __restrict__ latl,
                                        float4* __restrict__ sc4out) {
  float4 s4 = sc4[usr];
  float m = fmaxf(fmaxf(s4.x, s4.y), fmaxf(s4.z, s4.w));
  float e0 = expf(s4.x - m), e1 = expf(s4.y - m), e2 = expf(s4.z - m), e3 = expf(s4.w - m);
  float den = e0 + e1 + e2 + e3;
  float mix = (e0 * dwl[lane] + e1 * dwl[64 + lane] + e2 * dwl[128 + lane] + e3 * dwl[192 + lane]) / den;
  int s = uptr[usr], e = uptr[usr + 1];
  float a0 = 0.f, a1 = 0.f, a2 = 0.f, a3 = 0.f;
  for (int base = s; base < e; base += 64) {
    int c = min(64, e - base);
    int2 cvl = (lane < c) ? cv[base + lane] : make_int2(0, 0);
    int cl = cvl.x;
    float vl = __int_as_float(cvl.y);
    int j = 0;
    for (; j + 8 <= c; j += 8) {
      int c0 = rl(cl, j), c1 = rl(cl, j + 1), c2 = rl(cl, j + 2), c3 = rl(cl, j + 3);
      int c4 = rl(cl, j + 4), c5 = rl(cl, j + 5), c6 = rl(cl, j + 6), c7 = rl(cl, j + 7);
      float v0 = rlf(vl, j), v1 = rlf(vl, j + 1), v2 = rlf(vl, j + 2), v3 = rlf(vl, j + 3);
      float v4 = rlf(vl, j + 4), v5 = rlf(vl, j + 5), v6 = rlf(vl, j + 6), v7 = rlf(vl, j + 7);
      float r0 = bf2f(srcbf[(c0 << 6) + lane]);
      float r1 = bf2f(srcbf[(c1 << 6) + lane]);
      float r2 = bf2f(srcbf[(c2 << 6) + lane]);
      float r3 = bf2f(srcbf[(c3 << 6) + lane]);
      float r4 = bf2f(srcbf[(c4 << 6) + lane]);
      float r5 = bf2f(srcbf[(c5 << 6) + lane]);
      float r6 = bf2f(srcbf[(c6 << 6) + lane]);
      float r7 = bf2f(srcbf[(c7 << 6) + lane]);
      a0 = fmaf(r0, v0, a0); a1 = fmaf(r1, v1, a1);
      a2 = fmaf(r2, v2, a2); a3 = fmaf(r3, v3, a3);
      a0 = fmaf(r4, v4, a0); a1 = fmaf(r5, v5, a1);
      a2 = fmaf(r6, v6, a2); a3 = fmaf(r7, v7, a3);
    }
    for (; j < c; ++j) {
      int cj = rl(cl, j);
      float vj = rlf(vl, j);
      a0 = fmaf(bf2f(srcbf[(cj << 6) + lane]), vj, a0);
    }
  }
  float acc = (a0 + a1) + (a2 + a3);
  float ua = acc * mix + acc;
  float nrm = sqrtf(waveReduceSum(ua * ua));
  float val = ua / fmaxf(nrm, 1e-12f);
  size_t o = (size_t)usr * 64 + lane;
  if (nxt) nxt[o] = val;
  outp[o] = addb[o] + val;
  if (sc4out) {
    // fused hop-2 factor scores: sc4b[usr] = val @ latent^T
    float s0 = waveReduceSum(val * latl[lane]);
    float s1 = waveReduceSum(val * latl[64 + lane]);
    float s2 = waveReduceSum(val * latl[128 + lane]);
    float s3 = waveReduceSum(val * latl[192 + lane]);
    if (lane == 0) sc4out[usr] = make_float4(s0, s1, s2, s3);
  }
}

// KG aggregation inner (readlane broadcasts, 4 acc chains)
__device__ __forceinline__ float kg_agg64(int deg, int lane, int pk, float mk,
                                          const ushort_t* __restrict__ srcbf,
                                          const float* __restrict__ wl) {
  float a0 = 0.f, a1 = 0.f, a2 = 0.f, a3 = 0.f;
  int j = 0;
  for (; j + 4 <= deg; j += 4) {
    int p0 = rl(pk, j), p1 = rl(pk, j + 1), p2 = rl(pk, j + 2), p3 = rl(pk, j + 3);
    float k0 = rlf(mk, j), k1 = rlf(mk, j + 1), k2 = rlf(mk, j + 2), k3 = rlf(mk, j + 3);
    float r0 = bf2f(srcbf[((p0 & 0xFFFFF) << 6) + lane]);
    float r1 = bf2f(srcbf[((p1 & 0xFFFFF) << 6) + lane]);
    float r2 = bf2f(srcbf[((p2 & 0xFFFFF) << 6) + lane]);
    float r3 = bf2f(srcbf[((p3 & 0xFFFFF) << 6) + lane]);
    a0 = fmaf(r0 * wl[(((p0 >> 20) & 15) << 6) + lane], k0, a0);
    a1 = fmaf(r1 * wl[(((p1 >> 20) & 15) << 6) + lane], k1, a1);
    a2 = fmaf(r2 * wl[(((p2 >> 20) & 15) << 6) + lane], k2, a2);
    a3 = fmaf(r3 * wl[(((p3 >> 20) & 15) << 6) + lane], k3, a3);
  }
  for (; j < deg; ++j) {
    int pj = rl(pk, j);
    float kj = rlf(mk, j);
    a0 = fmaf(bf2f(srcbf[((pj & 0xFFFFF) << 6) + lane]) * wl[(((pj >> 20) & 15) << 6) + lane], kj, a0);
  }
  return (a0 + a1) + (a2 + a3);
}

// ---------------- D1: mask + fused KG hop-1  |  UI hop-1 (+sc4b) ----------------
__global__ void k_mask_kg_ui(const float* __restrict__ ent0,
                             const ushort_t* __restrict__ ent0bf,
                             const int* __restrict__ hptr, const int* __restrict__ packed,
                             const float* __restrict__ rel2t,
                             float* __restrict__ mask_s, const float* __restrict__ weight,
                             float* __restrict__ out_ent, ushort_t* __restrict__ ent1bf,
                             const float4* __restrict__ sc4,
                             float* __restrict__ out_usr,
                             float* __restrict__ usr1, const int* __restrict__ uptr,
                             const int2* __restrict__ cv,
                             const float* __restrict__ user_emb, const float* __restrict__ dw,
                             const float* __restrict__ latent, float4* __restrict__ sc4b) {
  int lane = threadIdx.x & 63, wid = threadIdx.x >> 6;
  if (blockIdx.x < KG_BLOCKS) {
    __shared__ __align__(16) float sh_eh[4][64];
    __shared__ float wl[576];
    for (int i = threadIdx.x; i < 576; i += 256) wl[i] = weight[i];
    int ent = blockIdx.x * 4 + wid;  // always < N_ENT
    int s = hptr[ent], e = hptr[ent + 1];
    float eh = ent0[(size_t)ent * 64 + lane];
    sh_eh[wid][lane] = eh;
    __syncthreads();
    size_t o = (size_t)ent * 64 + lane;
    int deg = e - s;
    if (deg == 0) {
      ent1bf[o] = f2bf(0.f);
      out_ent[o] = eh;
      return;
    }
    if (deg <= 64) {
      // ---- hot path ----
      int pk = (lane < deg) ? packed[s + lane] : 0;
      int tb = (pk >> 20) & 15;
      float r2sel = rel2t[ent * 9 + ((lane < deg) ? tb : 0)];
      // ---- 8-lane-per-edge dot ----
      int part = lane & 7;
      const float4* ehq = (const float4*)(sh_eh[wid] + (part << 3));
      float4 ef0 = ehq[0], ef1 = ehq[1];
      float myDot = 0.f;
      int nch = (deg + 7) >> 3;
      for (int c2 = 0; c2 < nch; ++c2) {
        int pkj = __shfl(pk, (c2 << 3) + (lane >> 3));
        const uint4* row = (const uint4*)(ent0bf + ((pkj & 0xFFFFF) << 6)) + part;
        uint4 b = *row;
        float s0 = bf2f(b.x & 0xFFFFu) * ef0.x;
        float s1 = bf2f(b.y & 0xFFFFu) * ef0.z;
        float s2 = bf2f(b.z & 0xFFFFu) * ef1.x;
        float s3 = bf2f(b.w & 0xFFFFu) * ef1.z;
        s0 = fmaf(bf2f(b.x >> 16), ef0.y, s0);
        s1 = fmaf(bf2f(b.y >> 16), ef0.w, s1);
        s2 = fmaf(bf2f(b.z >> 16), ef1.y, s2);
        s3 = fmaf(bf2f(b.w >> 16), ef1.w, s3);
        float sv = (s0 + s1) + (s2 + s3);
        sv += __shfl_xor(sv, 1);
        sv += __shfl_xor(sv, 2);
        sv += __shfl_xor(sv, 4);
        float got = __shfl(sv, part << 3);
        myDot = ((lane >> 3) == c2) ? got : myDot;
      }
      float trip = (lane < deg) ? myDot + r2sel : -INFINITY;
      float m2 = waveReduceMax(trip);
      float ex = (lane < deg) ? expf(trip - m2) : 0.f;
      float den2 = waveReduceSum(ex) + 1e-16f;
      float mk = ex / den2;
      if (lane < deg) mask_s[s + lane] = mk;
      // ---- fused KG hop-1 aggregation ----
      float acc = kg_agg64(deg, lane, pk, mk, ent0bf, wl);
      float agg = acc / (float)deg;
      float nrm = sqrtf(waveReduceSum(agg * agg));
      float val = agg / fmaxf(nrm, 1e-12f);
      ent1bf[o] = f2bf(val);
      out_ent[o] = eh + val;
    } else {
      // ---- generic multi-chunk path ----
      float m2l = -INFINITY;
      for (int base = s; base < e; base += 64) {
        int c = min(64, e - base);
        int pk = (lane < c) ? packed[base + lane] : 0;
        int tb = (pk >> 20) & 15;
        float r2 = rel2t[ent * 9 + ((lane < c) ? tb : 0)];
        int tl = pk & 0xFFFFF;
        const uint4* row = (const uint4*)(ent0bf + (tl << 6));
        const float* ehp = sh_eh[wid];
        float d = 0.f;
#pragma unroll
        for (int q = 0; q < 8; ++q) {
          uint4 a = row[q];
          d += bf2f(a.x & 0xFFFF) * ehp[q * 8 + 0] + bf2f(a.x >> 16) * ehp[q * 8 + 1];
          d += bf2f(a.y & 0xFFFF) * ehp[q * 8 + 2] + bf2f(a.y >> 16) * ehp[q * 8 + 3];
          d += bf2f(a.z & 0xFFFF) * ehp[q * 8 + 4] + bf2f(a.z >> 16) * ehp[q * 8 + 5];
          d += bf2f(a.w & 0xFFFF) * ehp[q * 8 + 6] + bf2f(a.w >> 16) * ehp[q * 8 + 7];
        }
        float trip = d + r2;
        if (lane < c) {
          mask_s[base + lane] = trip;
          m2l = fmaxf(m2l, trip);
        }
      }
      float m2 = waveReduceMax(m2l);
      float denl = 0.f;
      for (int base = s; base < e; base += 64) {
        int c = min(64, e - base);
        denl += (lane < c) ? expf(mask_s[base + lane] - m2) : 0.f;
      }
      float den2 = waveReduceSum(denl) + 1e-16f;
      float acc = 0.f;
      for (int base = s; base < e; base += 64) {
        int c = min(64, e - base);
        int pk = (lane < c) ? packed[base + lane] : 0;
        float mk = 0.f;
        if (lane < c) {
          mk = expf(mask_s[base + lane] - m2) / den2;
          mask_s[base + lane] = mk;
        }
        acc += kg_agg64(c, lane, pk, mk, ent0bf, wl);
      }
      float agg = acc / (float)deg;
      float nrm = sqrtf(waveReduceSum(agg * agg));
      float val = agg / fmaxf(nrm, 1e-12f);
      ent1bf[o] = f2bf(val);
      out_ent[o] = eh + val;
    }
  } else {
    __shared__ float dwl[256];
    __shared__ float latl[256];
    if (threadIdx.x < 256) {
      dwl[threadIdx.x] = dw[threadIdx.x];
      latl[threadIdx.x] = latent[threadIdx.x];
    }
    __syncthreads();
    int usr = (blockIdx.x - KG_BLOCKS) * 4 + wid;  // always < N_USR
    ui_body(usr, lane, ent0bf, sc4, user_emb, out_usr, usr1,
            uptr, cv, dwl, latl, sc4b);
  }
}

// ---------------- D2: KG hop-2 + UI hop-2 ----------------
__global__ void k_hop2(const ushort_t* __restrict__ srcbf,
                       float* __restrict__ out_ent,
                       const int* __restrict__ hptr, const int* __restrict__ packed,
                       const float* __restrict__ mask_s, const float* __restrict__ weight,
                       const float* __restrict__ usr1, float* __restrict__ out_usr,
                       const int* __restrict__ uptr, const int2* __restrict__ cv,
                       const float4* __restrict__ sc4,
                       const float* __restrict__ dw) {
  int lane = threadIdx.x & 63, wid = threadIdx.x >> 6;
  if (blockIdx.x < KG_BLOCKS) {
    __shared__ float wl[576];
    for (int i = threadIdx.x; i < 576; i += 256) wl[i] = weight[i];
    __syncthreads();
    int ent = blockIdx.x * 4 + wid;
    int s = hptr[ent], e = hptr[ent + 1];
    float acc = 0.f;
    for (int base = s; base < e; base += 64) {
      int c = min(64, e - base);
      int pk = (lane < c) ? packed[base + lane] : 0;
      float mk = (lane < c) ? mask_s[base + lane] : 0.f;
      acc += kg_agg64(c, lane, pk, mk, srcbf, wl);
    }
    float n = (float)(e - s);
    float agg = acc / fmaxf(n, 1.0f);
    float nrm = sqrtf(waveReduceSum(agg * agg));
    float val = agg / fmaxf(nrm, 1e-12f);
    size_t o = (size_t)ent * 64 + lane;
    out_ent[o] = out_ent[o] + val;
  } else {
    __shared__ float dwl[256];
    if (threadIdx.x < 256) dwl[threadIdx.x] = dw[threadIdx.x];
    __syncthreads();
    int usr = (blockIdx.x - KG_BLOCKS) * 4 + wid;
    ui_body(usr, lane, srcbf, sc4, out_usr, out_usr, nullptr,
            uptr, cv, dwl, nullptr, nullptr);
  }
}

extern "C" void kernel_launch(void* const* d_in, const int* in_sizes, int n_in,
                              void* d_out, int out_size, void* d_ws, size_t ws_size,
                              hipStream_t stream) {
  const float* user_emb = (const float*)d_in[0];
  const float* entity_emb = (const float*)d_in[1];
  const float* latent = (const float*)d_in[2];
  const float* weight = (const float*)d_in[3];
  const float* disen = (const float*)d_in[4];
  const float* kgW = (const float*)d_in[5];
  const float* ui_vals = (const float*)d_in[6];
  const int* edge_index = (const int*)d_in[7];
  const int* edge_type = (const int*)d_in[8];
  const int* ui_rows = (const int*)d_in[9];
  const int* ui_cols = (const int*)d_in[10];
  const int* head = edge_index;
  const int* tail = edge_index + N_EDGE;

  char* ws = (char*)d_ws;
  size_t o = 0;
  auto alloc = [&](size_t bytes) -> char* {
    char* p = ws + o;
    o += (bytes + 255) & ~(size_t)255;
    return p;
  };
  int* head_ptr = (int*)alloc((N_ENT + 1) * 4);
  int* head_cur = (int*)alloc((size_t)N_ENT * 4);
  int* ui_ptr = (int*)alloc((N_USR + 1) * 4);
  int* ui_cur = (int*)alloc((size_t)N_USR * 4);
  int* bsum_h = (int*)alloc(256 * 4);
  int* bsum_u = (int*)alloc(256 * 4);
  int* packed = (int*)alloc((size_t)N_EDGE * 4);
  int2* cv = (int2*)alloc((size_t)N_EDGE * 8);
  float* mask_s = (float*)alloc((size_t)N_EDGE * 4);
  ushort_t* ent0bf = (ushort_t*)alloc((size_t)N_ENT * 64 * 2);
  ushort_t* ent1bf = (ushort_t*)alloc((size_t)N_ENT * 64 * 2);
  float* usr1 = (float*)alloc((size_t)N_USR * 64 * 4);
  int* cnt9 = (int*)alloc((size_t)N_ENT * 9 * 4);
  float* rel2t = (float*)alloc((size_t)N_ENT * 9 * 4);
  float4* sc4a = (float4*)alloc((size_t)N_USR * 16);
  float4* sc4b = (float4*)alloc((size_t)N_USR * 16);
  float* V = (float*)alloc(9 * 64 * 4);
  float* wsq = (float*)alloc(16 * 4);
  float* dw = (float*)alloc(4 * 64 * 4);
  if (o > ws_size) return;

  float* out_ent = (float*)d_out;
  float* out_usr = out_ent + (size_t)N_ENT * 64;
  float* out_cor = out_ent + (size_t)N_ENT * 64 + (size_t)N_USR * 64;

  hipMemsetAsync(ui_cur, 0, (size_t)N_USR * 4, stream);
  hipMemsetAsync(cnt9, 0, (size_t)N_ENT * 9 * 4, stream);

  // K1: bf16 convert + count + prep + sc(user)
  k_pre<<<TB_BLOCKS + CNT_BLOCKS + 1 + SC_BLOCKS, 256, 0, stream>>>(
      entity_emb, ent0bf, head, ui_rows, edge_type, ui_cur, cnt9,
      weight, kgW, disen, V, wsq, dw, out_cor, user_emb, latent, sc4a);

  int nbh = (N_ENT + 1023) / 1024, nbu = (N_USR + 1023) / 1024;
  // K2: fused scan-reduce
  k_scanred<<<nbh + nbu, 256, 0, stream>>>(cnt9, ui_cur, bsum_h, bsum_u, nbh);
  // K3: block-sum exclusive scans
  k_scan_tops<<<1, 64, 0, stream>>>(bsum_h, nbh, bsum_u, nbu, head_ptr, N_ENT, ui_ptr, N_USR, N_EDGE);
  // K4: fused scan-final
  k_scanfin<<<nbh + nbu, 256, 0, stream>>>(cnt9, bsum_h, bsum_u,
                                           head_ptr, head_cur, ui_ptr, ui_cur, nbh);
  // K5: build + rel2
  k_build_rel2<<<BUILD_BLOCKS + REL2_BLOCKS, 256, 0, stream>>>(
      head, tail, edge_type, ui_rows, ui_cols, ui_vals,
      head_cur, ui_cur, packed, cv, ent0bf, V, wsq, cnt9, rel2t);

  // D1: mask + fused KG hop-1 + UI hop-1 (+ sc4b epilogue)
  k_mask_kg_ui<<<KG_BLOCKS + UI_BLOCKS, 256, 0, stream>>>(
      entity_emb, ent0bf, head_ptr, packed, rel2t, mask_s, weight,
      out_ent, ent1bf, sc4a, out_usr, usr1, ui_ptr, cv, user_emb, dw, latent, sc4b);

  // D2: KG hop-2 + UI hop-2
  k_hop2<<<KG_BLOCKS + UI_BLOCKS, 256, 0, stream>>>(
      ent1bf, out_ent, head_ptr, packed, mask_s, weight,
      usr1, out_usr, ui_ptr, cv, sc4b, dw);
}